// Round 3
// baseline (31166.785 us; speedup 1.0000x reference)
//
#include <hip/hip_runtime.h>

#define DEV __device__ __forceinline__

constexpr int T_SEQ = 1024;
constexpr int DMODEL = 512;
constexpr int NSYM = 1024;
constexpr int NPAT = 512;

// ---------------- epilogue modes ----------------
enum { E_BIAS = 0, E_GUMBEL = 1, E_POS = 2, E_RES = 3, E_GELU = 4, E_VQ = 5 };

// ---------------- fp32 GEMM v2 ------------------------------------------------
// C[M,N] = A[M,K] * op(B) + epilogue.  NNLAY=0: B is [N,K]. NNLAY=1: B is [K,N].
// BM=64, BN=128, BK=32, 256 threads (4 waves, each 32x64, 4x8 micro/lane).
// Double-buffered LDS (one barrier/iter), register prefetch, XCD-aware swizzle.
template <int NNLAY, int EPI>
__global__ __launch_bounds__(256, 2) void gemm2(
    const float* __restrict__ A, const float* __restrict__ Bm,
    const float* __restrict__ bias, const float* __restrict__ res,
    float* __restrict__ C, int M, int N, int K, int resMask,
    const int* __restrict__ ep, const int* __restrict__ tot, int gx) {
  constexpr int BM = 64, BN = 128, BK = 32;
  __shared__ __align__(16) float As[2][BK][BM + 4];
  __shared__ __align__(16) float Bs[2][BK][BN + 4];

  // ---- bijective XCD swizzle (m204): cluster consecutive logical blocks
  // (which share an A panel, x-fastest) onto one XCD for L2 reuse.
  const int nwg = gridDim.x;
  const int orig = blockIdx.x;
  const int q = nwg >> 3, r = nwg & 7;
  const int xcd = orig & 7, slot = orig >> 3;
  const int wg = (xcd < r ? xcd * (q + 1) : r * (q + 1) + (xcd - r) * q) + slot;
  const int by = wg / gx, bx = wg % gx;
  const int bm = by * BM, bn = bx * BN;

  const int tid = threadIdx.x;
  const int w = tid >> 6, lane = tid & 63;
  const int wy = w >> 1, wx = w & 1;       // 2x2 wave grid
  const int ly = lane >> 3, lx = lane & 7; // 8x8 lane grid
  const int row0 = wy * 32 + ly * 4;       // 4 rows per lane
  const int col0 = wx * 64 + lx * 8;       // 8 cols per lane

  // staging indices (coalesced float4 along K / along N)
  const int ar = (tid) >> 3;               // base A row for e=tid
  const int ac4 = (tid & 7) << 2;

  float4 pa[2], pb[4];

  // ---- LOAD tile t into registers ----
  auto LOAD = [&](int k0) {
#pragma unroll
    for (int ii = 0; ii < 2; ++ii) {
      int e = tid + ii * 256;
      int rr = e >> 3, c4 = (e & 7) << 2;
      pa[ii] = *(const float4*)(A + (size_t)(bm + rr) * K + k0 + c4);
    }
    if constexpr (NNLAY == 0) {
#pragma unroll
      for (int ii = 0; ii < 4; ++ii) {
        int e = tid + ii * 256;
        int rr = e >> 3, c4 = (e & 7) << 2;
        pb[ii] = *(const float4*)(Bm + (size_t)(bn + rr) * K + k0 + c4);
      }
    } else {
#pragma unroll
      for (int ii = 0; ii < 4; ++ii) {
        int e = tid + ii * 256;
        int rr = e >> 5, c4 = (e & 31) << 2;
        pb[ii] = *(const float4*)(Bm + (size_t)(k0 + rr) * N + bn + c4);
      }
    }
  };

  // ---- STORE registers into LDS buffer buf ----
  auto STORE = [&](int buf) {
#pragma unroll
    for (int ii = 0; ii < 2; ++ii) {
      int e = tid + ii * 256;
      int rr = e >> 3, c4 = (e & 7) << 2;
      As[buf][c4 + 0][rr] = pa[ii].x;
      As[buf][c4 + 1][rr] = pa[ii].y;
      As[buf][c4 + 2][rr] = pa[ii].z;
      As[buf][c4 + 3][rr] = pa[ii].w;
    }
    if constexpr (NNLAY == 0) {
#pragma unroll
      for (int ii = 0; ii < 4; ++ii) {
        int e = tid + ii * 256;
        int rr = e >> 3, c4 = (e & 7) << 2;
        Bs[buf][c4 + 0][rr] = pb[ii].x;
        Bs[buf][c4 + 1][rr] = pb[ii].y;
        Bs[buf][c4 + 2][rr] = pb[ii].z;
        Bs[buf][c4 + 3][rr] = pb[ii].w;
      }
    } else {
#pragma unroll
      for (int ii = 0; ii < 4; ++ii) {
        int e = tid + ii * 256;
        int rr = e >> 5, c4 = (e & 31) << 2;
        *(float4*)&Bs[buf][rr][c4] = pb[ii];
      }
    }
  };

  float acc[4][8];
#pragma unroll
  for (int i = 0; i < 4; ++i)
#pragma unroll
    for (int j = 0; j < 8; ++j) acc[i][j] = 0.0f;

  const int nt = K / BK;
  LOAD(0);
  STORE(0);
  __syncthreads();
  int cur = 0;
  for (int t = 0; t < nt; ++t) {
    if (t + 1 < nt) LOAD((t + 1) * BK);
#pragma unroll
    for (int k = 0; k < BK; ++k) {
      float a[4], b[8];
      *(float4*)&a[0] = *(const float4*)&As[cur][k][row0];
      *(float4*)&b[0] = *(const float4*)&Bs[cur][k][col0];
      *(float4*)&b[4] = *(const float4*)&Bs[cur][k][col0 + 4];
#pragma unroll
      for (int i = 0; i < 4; ++i)
#pragma unroll
        for (int j = 0; j < 8; ++j) acc[i][j] = fmaf(a[i], b[j], acc[i][j]);
    }
    if (t + 1 < nt) {
      STORE(cur ^ 1);
      __syncthreads();
    }
    cur ^= 1;
  }

  // ---- epilogue ----
  const int ncol = bn + col0;
  float bb[8];
  if constexpr (EPI == E_BIAS || EPI == E_RES || EPI == E_GELU) {
    *(float4*)&bb[0] = *(const float4*)(bias + ncol);
    *(float4*)&bb[4] = *(const float4*)(bias + ncol + 4);
  }
  float invt = 1.0f;
  if constexpr (EPI == E_VQ) {
    float t = 1.0f - 0.5f * (float)ep[0] / (float)tot[0];
    invt = 1.0f / fmaxf(0.5f, t);
  }
#pragma unroll
  for (int i = 0; i < 4; ++i) {
    const int m = bm + row0 + i;
    float o[8];
#pragma unroll
    for (int j = 0; j < 8; ++j) o[j] = acc[i][j];
    if constexpr (EPI == E_BIAS) {
#pragma unroll
      for (int j = 0; j < 8; ++j) o[j] += bb[j];
    } else if constexpr (EPI == E_GUMBEL) {
      float g[8];
      *(float4*)&g[0] = *(const float4*)(res + (size_t)m * N + ncol);
      *(float4*)&g[4] = *(const float4*)(res + (size_t)m * N + ncol + 4);
#pragma unroll
      for (int j = 0; j < 8; ++j) o[j] = 4.0f * o[j] + 2.0f * g[j];
    } else if constexpr (EPI == E_POS) {
      float g[8];
      const size_t pr = (size_t)(m & resMask) * N + ncol;
      *(float4*)&g[0] = *(const float4*)(res + pr);
      *(float4*)&g[4] = *(const float4*)(res + pr + 4);
#pragma unroll
      for (int j = 0; j < 8; ++j) o[j] += g[j];
    } else if constexpr (EPI == E_RES) {
      float g[8];
      *(float4*)&g[0] = *(const float4*)(res + (size_t)m * N + ncol);
      *(float4*)&g[4] = *(const float4*)(res + (size_t)m * N + ncol + 4);
#pragma unroll
      for (int j = 0; j < 8; ++j) o[j] += bb[j] + g[j];
    } else if constexpr (EPI == E_GELU) {
#pragma unroll
      for (int j = 0; j < 8; ++j) {
        float t = o[j] + bb[j];
        o[j] = 0.5f * t * (1.0f + erff(t * 0.7071067811865476f));
      }
    } else if constexpr (EPI == E_VQ) {
#pragma unroll
      for (int j = 0; j < 8; ++j) o[j] *= invt;
    }
    *(float4*)(C + (size_t)m * N + ncol) = *(float4*)&o[0];
    *(float4*)(C + (size_t)m * N + ncol + 4) = *(float4*)&o[4];
  }
}

// ---------------- flash attention v2 -----------------------------------------
// 4 waves/block, each wave owns 32 q-rows; K/V 64x64 tiles shared in LDS.
DEV int SW(int x) { return ((x ^ (x >> 3)) & 7) << 2; }

__global__ __launch_bounds__(256) void flash_attn2(
    const float* __restrict__ qkv, float* __restrict__ outp) {
  __shared__ __align__(16) float QT[4][64][32];  // [wave][d][q ^ SW(d)]
  __shared__ __align__(16) float KT[64][64];     // [d][k ^ SW(d)]
  __shared__ __align__(16) float Vs[64][64];     // [kv][d ^ SW(kv)]
  const int tid = threadIdx.x;
  const int w = tid >> 6, lane = tid & 63;
  const int ly = lane >> 3, lx = lane & 7;
  const int qt = blockIdx.x;  // 0..7 (128 q-rows per block)
  const int bh = blockIdx.y;  // 0..63
  const int b = bh >> 3, hh = bh & 7;

  const int qbase = qt * 128 + w * 32;
  const int lr = lane >> 4;          // 0..3
  const int lc = (lane & 15) << 2;   // 0,4,..,60
  const size_t baseQ = ((size_t)(b * T_SEQ + qbase)) * 1536 + hh * 64;
#pragma unroll
  for (int i = 0; i < 8; ++i) {
    int r = lr + 4 * i;  // 0..31
    float4 v = *(const float4*)(qkv + baseQ + (size_t)r * 1536 + lc);
    QT[w][lc + 0][r ^ SW(lc + 0)] = v.x;
    QT[w][lc + 1][r ^ SW(lc + 1)] = v.y;
    QT[w][lc + 2][r ^ SW(lc + 2)] = v.z;
    QT[w][lc + 3][r ^ SW(lc + 3)] = v.w;
  }

  float o[4][8] = {};
  float mrun[4], lrun[4];
#pragma unroll
  for (int i = 0; i < 4; ++i) {
    mrun[i] = -__builtin_huge_valf();
    lrun[i] = 0.0f;
  }

  const int kr = tid >> 4;          // 0..15
  const int kc = (tid & 15) << 2;   // 0,4,..,60

  for (int kt = 0; kt < 16; ++kt) {
    __syncthreads();
    const size_t baseK =
        ((size_t)(b * T_SEQ + kt * 64)) * 1536 + 512 + hh * 64;
#pragma unroll
    for (int jj = 0; jj < 4; ++jj) {
      int r = kr + 16 * jj;  // 0..63
      float4 kv4 = *(const float4*)(qkv + baseK + (size_t)r * 1536 + kc);
      KT[kc + 0][r ^ SW(kc + 0)] = kv4.x;
      KT[kc + 1][r ^ SW(kc + 1)] = kv4.y;
      KT[kc + 2][r ^ SW(kc + 2)] = kv4.z;
      KT[kc + 3][r ^ SW(kc + 3)] = kv4.w;
      float4 vv4 = *(const float4*)(qkv + baseK + 512 + (size_t)r * 1536 + kc);
      *(float4*)&Vs[r][kc ^ SW(r)] = vv4;
    }
    __syncthreads();

    float s[4][8] = {};
#pragma unroll 4
    for (int d = 0; d < 64; ++d) {
      int sw = SW(d);
      float q[4], k[8];
      *(float4*)&q[0] = *(const float4*)&QT[w][d][(4 * ly) ^ sw];
      *(float4*)&k[0] = *(const float4*)&KT[d][(8 * lx) ^ sw];
      *(float4*)&k[4] = *(const float4*)&KT[d][(8 * lx + 4) ^ sw];
#pragma unroll
      for (int i = 0; i < 4; ++i)
#pragma unroll
        for (int j = 0; j < 8; ++j) s[i][j] = fmaf(q[i], k[j], s[i][j]);
    }

#pragma unroll
    for (int i = 0; i < 4; ++i) {
#pragma unroll
      for (int j = 0; j < 8; ++j) s[i][j] *= 0.125f;
      float rm = s[i][0];
#pragma unroll
      for (int j = 1; j < 8; ++j) rm = fmaxf(rm, s[i][j]);
      rm = fmaxf(rm, __shfl_xor(rm, 1));
      rm = fmaxf(rm, __shfl_xor(rm, 2));
      rm = fmaxf(rm, __shfl_xor(rm, 4));
      float mnew = fmaxf(mrun[i], rm);
      float alpha = expf(mrun[i] - mnew);
      float rs = 0.0f;
#pragma unroll
      for (int j = 0; j < 8; ++j) {
        float p = expf(s[i][j] - mnew);
        s[i][j] = p;
        rs += p;
      }
      rs += __shfl_xor(rs, 1);
      rs += __shfl_xor(rs, 2);
      rs += __shfl_xor(rs, 4);
      lrun[i] = lrun[i] * alpha + rs;
      mrun[i] = mnew;
#pragma unroll
      for (int j = 0; j < 8; ++j) o[i][j] *= alpha;
    }

#pragma unroll 4
    for (int c = 0; c < 64; ++c) {
      const int srcl = (ly << 3) | (c >> 3);
      float pb[4];
      pb[0] = __shfl(s[0][c & 7], srcl);
      pb[1] = __shfl(s[1][c & 7], srcl);
      pb[2] = __shfl(s[2][c & 7], srcl);
      pb[3] = __shfl(s[3][c & 7], srcl);
      int sw = SW(c);
      float vv[8];
      *(float4*)&vv[0] = *(const float4*)&Vs[c][(8 * lx) ^ sw];
      *(float4*)&vv[4] = *(const float4*)&Vs[c][(8 * lx + 4) ^ sw];
#pragma unroll
      for (int i = 0; i < 4; ++i)
#pragma unroll
        for (int j = 0; j < 8; ++j) o[i][j] = fmaf(pb[i], vv[j], o[i][j]);
    }
  }

  const size_t baseO = ((size_t)(b * T_SEQ + qbase)) * DMODEL + hh * 64;
#pragma unroll
  for (int i = 0; i < 4; ++i) {
    float inv = 1.0f / lrun[i];
    int r = 4 * ly + i;
    float4 w0 = make_float4(o[i][0] * inv, o[i][1] * inv, o[i][2] * inv,
                            o[i][3] * inv);
    float4 w1 = make_float4(o[i][4] * inv, o[i][5] * inv, o[i][6] * inv,
                            o[i][7] * inv);
    *(float4*)(outp + baseO + (size_t)r * DMODEL + 8 * lx) = w0;
    *(float4*)(outp + baseO + (size_t)r * DMODEL + 8 * lx + 4) = w1;
  }
}

// ---------------- row kernels (D=512, one wave per row, 4 rows/block) --------
DEV float wave_sum(float v) {
#pragma unroll
  for (int off = 1; off < 64; off <<= 1) v += __shfl_xor(v, off);
  return v;
}

template <int DOL2>
__global__ __launch_bounds__(256) void ln_kernel(const float* __restrict__ x,
                                                 const float* __restrict__ g,
                                                 const float* __restrict__ b,
                                                 float* __restrict__ y) {
  const int row = blockIdx.x * 4 + (threadIdx.x >> 6);
  const int lane = threadIdx.x & 63;
  const float* xr = x + (size_t)row * DMODEL;
  float v[8];
  *(float4*)&v[0] = *(const float4*)(xr + lane * 8);
  *(float4*)&v[4] = *(const float4*)(xr + lane * 8 + 4);
  float s = 0.0f;
#pragma unroll
  for (int j = 0; j < 8; ++j) s += v[j];
  s = wave_sum(s);
  float mean = s * (1.0f / 512.0f);
  float s2 = 0.0f;
#pragma unroll
  for (int j = 0; j < 8; ++j) {
    float d = v[j] - mean;
    s2 += d * d;
  }
  s2 = wave_sum(s2);
  float rstd = 1.0f / sqrtf(s2 * (1.0f / 512.0f) + 1e-5f);
  float gg[8], bv[8];
  *(float4*)&gg[0] = *(const float4*)(g + lane * 8);
  *(float4*)&gg[4] = *(const float4*)(g + lane * 8 + 4);
  *(float4*)&bv[0] = *(const float4*)(b + lane * 8);
  *(float4*)&bv[4] = *(const float4*)(b + lane * 8 + 4);
  float t[8];
#pragma unroll
  for (int j = 0; j < 8; ++j) t[j] = (v[j] - mean) * rstd * gg[j] + bv[j];
  if constexpr (DOL2) {
    float n2 = 0.0f;
#pragma unroll
    for (int j = 0; j < 8; ++j) n2 += t[j] * t[j];
    n2 = wave_sum(n2);
    float den = fmaxf(sqrtf(n2), 1e-12f);
#pragma unroll
    for (int j = 0; j < 8; ++j) t[j] /= den;
  }
  float* yr = y + (size_t)row * DMODEL;
  *(float4*)(yr + lane * 8) = *(float4*)&t[0];
  *(float4*)(yr + lane * 8 + 4) = *(float4*)&t[4];
}

__global__ __launch_bounds__(256) void l2_rows(const float* __restrict__ x,
                                               float* __restrict__ y) {
  const int row = blockIdx.x * 4 + (threadIdx.x >> 6);
  const int lane = threadIdx.x & 63;
  const float* xr = x + (size_t)row * DMODEL;
  float v[8];
  *(float4*)&v[0] = *(const float4*)(xr + lane * 8);
  *(float4*)&v[4] = *(const float4*)(xr + lane * 8 + 4);
  float n2 = 0.0f;
#pragma unroll
  for (int j = 0; j < 8; ++j) n2 += v[j] * v[j];
  n2 = wave_sum(n2);
  float den = fmaxf(sqrtf(n2), 1e-12f);
#pragma unroll
  for (int j = 0; j < 8; ++j) v[j] /= den;
  float* yr = y + (size_t)row * DMODEL;
  *(float4*)(yr + lane * 8) = *(float4*)&v[0];
  *(float4*)(yr + lane * 8 + 4) = *(float4*)&v[4];
}

// in-place softmax over rows of length 1024 (one block of 256 per row)
__global__ __launch_bounds__(256) void softmax_rows(float* __restrict__ p) {
  const int row = blockIdx.x;
  const int tid = threadIdx.x;
  float* pr = p + (size_t)row * NSYM;
  float4 v = *(const float4*)(pr + tid * 4);
  float m = fmaxf(fmaxf(v.x, v.y), fmaxf(v.z, v.w));
#pragma unroll
  for (int off = 1; off < 64; off <<= 1) m = fmaxf(m, __shfl_xor(m, off));
  __shared__ float red[4];
  const int wv = tid >> 6;
  if ((tid & 63) == 0) red[wv] = m;
  __syncthreads();
  m = fmaxf(fmaxf(red[0], red[1]), fmaxf(red[2], red[3]));
  float e0 = expf(v.x - m), e1 = expf(v.y - m), e2 = expf(v.z - m),
        e3 = expf(v.w - m);
  float s = e0 + e1 + e2 + e3;
#pragma unroll
  for (int off = 1; off < 64; off <<= 1) s += __shfl_xor(s, off);
  __syncthreads();
  if ((tid & 63) == 0) red[wv] = s;
  __syncthreads();
  s = red[0] + red[1] + red[2] + red[3];
  float4 w = make_float4(e0 / s, e1 / s, e2 / s, e3 / s);
  *(float4*)(pr + tid * 4) = w;
}

// argmax + one_hot + gather (one wave per row)
__global__ __launch_bounds__(256) void vq_finalize(
    const float* __restrict__ logits, const float* __restrict__ patterns,
    float* __restrict__ emb, float* __restrict__ assign,
    float* __restrict__ idxf) {
  const int row = blockIdx.x * 4 + (threadIdx.x >> 6);
  const int lane = threadIdx.x & 63;
  const float* lr = logits + (size_t)row * NPAT;
  float best = -__builtin_huge_valf();
  int bi = 0;
#pragma unroll
  for (int jj = 0; jj < 8; ++jj) {
    int j = lane + jj * 64;
    float v = lr[j];
    if (v > best) {
      best = v;
      bi = j;
    }
  }
#pragma unroll
  for (int off = 1; off < 64; off <<= 1) {
    float ob = __shfl_xor(best, off);
    int oi = __shfl_xor(bi, off);
    if (ob > best || (ob == best && oi < bi)) {
      best = ob;
      bi = oi;
    }
  }
  const float* pr = patterns + (size_t)bi * DMODEL;
#pragma unroll
  for (int g = 0; g < 2; ++g) {
    int c = lane * 8 + g * 4;
    float4 pv = *(const float4*)(pr + c);
    *(float4*)(emb + (size_t)row * DMODEL + c) = pv;
    float4 av;
    av.x = (c + 0 == bi) ? 1.0f : 0.0f;
    av.y = (c + 1 == bi) ? 1.0f : 0.0f;
    av.z = (c + 2 == bi) ? 1.0f : 0.0f;
    av.w = (c + 3 == bi) ? 1.0f : 0.0f;
    *(float4*)(assign + (size_t)row * NPAT + c) = av;
  }
  if (lane == 0) idxf[row] = (float)bi;
}

// ---------------- host launch ----------------
extern "C" void kernel_launch(void* const* d_in, const int* in_sizes, int n_in,
                              void* d_out, int out_size, void* d_ws,
                              size_t ws_size, hipStream_t stream) {
  (void)in_sizes;
  (void)n_in;
  (void)out_size;
  (void)ws_size;
  const float* x = (const float*)d_in[0];
  const float* gumbel = (const float*)d_in[1];
  const float* sym_w = (const float*)d_in[2];
  const float* sym_b = (const float*)d_in[3];
  const float* codebook = (const float*)d_in[4];
  const float* pos_enc = (const float*)d_in[5];
  const float* attn_in_w = (const float*)d_in[6];
  const float* attn_in_b = (const float*)d_in[7];
  const float* attn_out_w = (const float*)d_in[8];
  const float* attn_out_b = (const float*)d_in[9];
  const float* n1_g = (const float*)d_in[10];
  const float* n1_b = (const float*)d_in[11];
  const float* n2_g = (const float*)d_in[12];
  const float* n2_b = (const float*)d_in[13];
  const float* ffn_w1 = (const float*)d_in[14];
  const float* ffn_b1 = (const float*)d_in[15];
  const float* ffn_w2 = (const float*)d_in[16];
  const float* ffn_b2 = (const float*)d_in[17];
  const float* q_w = (const float*)d_in[18];
  const float* q_b = (const float*)d_in[19];
  const float* qln_g = (const float*)d_in[20];
  const float* qln_b = (const float*)d_in[21];
  const float* patterns = (const float*)d_in[22];
  const int* epoch = (const int*)d_in[23];
  const int* tot = (const int*)d_in[24];

  float* out = (float*)d_out;
  float* emb = out;                    // [8192,512]
  float* assign = out + 4194304;       // [8192,512]
  float* logits = out + 8388608;       // [8192,512]
  float* h = out + 12582912;           // [8192,512]
  float* idxf = out + 16777216;        // [8192]

  float* ws = (float*)d_ws;
  float* r1 = ws;                      // 16777216 floats: soft/qkv/mid
  float* hn = ws + 16777216;           // 4194304
  float* r3 = ws + 20971520;           // 4194304: hp/attno/q
  float* cbn = ws + 25165824;          // 524288
  float* patn = ws + 25690112;         // 262144

  // 1. hp = x @ sym_w^T + sym_b   [8192,512] K=1024
  gemm2<0, E_BIAS><<<512, 256, 0, stream>>>(x, sym_w, sym_b, nullptr, r3, 8192,
                                            512, 1024, 0, nullptr, nullptr, 4);
  // 2. cbn = l2norm(codebook)  [1024,512]
  l2_rows<<<256, 256, 0, stream>>>(codebook, cbn);
  // 3. hp <- l2norm(hp) in place
  l2_rows<<<2048, 256, 0, stream>>>(r3, r3);
  // 4. soft_pre = 4*(hp_n@cbn^T) + 2*gumbel   [8192,1024] K=512
  gemm2<0, E_GUMBEL><<<1024, 256, 0, stream>>>(
      r3, cbn, nullptr, gumbel, r1, 8192, 1024, 512, 0, nullptr, nullptr, 8);
  // 5. softmax rows
  softmax_rows<<<8192, 256, 0, stream>>>(r1);
  // 6. h = soft @ codebook + pos_enc   [8192,512] K=1024 (NN)
  gemm2<1, E_POS><<<512, 256, 0, stream>>>(r1, codebook, nullptr, pos_enc, h,
                                           8192, 512, 1024, 1023, nullptr,
                                           nullptr, 4);

  for (int l = 0; l < 4; ++l) {
    const float* inw = attn_in_w + (size_t)l * 1536 * 512;
    const float* inb = attn_in_b + (size_t)l * 1536;
    const float* outw = attn_out_w + (size_t)l * 512 * 512;
    const float* outb = attn_out_b + (size_t)l * 512;
    const float* w1 = ffn_w1 + (size_t)l * 2048 * 512;
    const float* b1 = ffn_b1 + (size_t)l * 2048;
    const float* w2 = ffn_w2 + (size_t)l * 512 * 2048;
    const float* b2 = ffn_b2 + (size_t)l * 512;

    ln_kernel<0><<<2048, 256, 0, stream>>>(h, n1_g + l * 512, n1_b + l * 512,
                                           hn);
    gemm2<0, E_BIAS><<<1536, 256, 0, stream>>>(
        hn, inw, inb, nullptr, r1, 8192, 1536, 512, 0, nullptr, nullptr, 12);
    flash_attn2<<<dim3(8, 64), 256, 0, stream>>>(r1, r3);
    gemm2<0, E_RES><<<512, 256, 0, stream>>>(r3, outw, outb, h, h, 8192, 512,
                                             512, 0, nullptr, nullptr, 4);
    ln_kernel<0><<<2048, 256, 0, stream>>>(h, n2_g + l * 512, n2_b + l * 512,
                                           hn);
    gemm2<0, E_GELU><<<2048, 256, 0, stream>>>(
        hn, w1, b1, nullptr, r1, 8192, 2048, 512, 0, nullptr, nullptr, 16);
    gemm2<0, E_RES><<<512, 256, 0, stream>>>(r1, w2, b2, h, h, 8192, 512, 2048,
                                             0, nullptr, nullptr, 4);
  }

  // VQ head
  gemm2<0, E_BIAS><<<512, 256, 0, stream>>>(h, q_w, q_b, nullptr, r3, 8192, 512,
                                            512, 0, nullptr, nullptr, 4);
  ln_kernel<1><<<2048, 256, 0, stream>>>(r3, qln_g, qln_b, r3);
  l2_rows<<<128, 256, 0, stream>>>(patterns, patn);
  gemm2<0, E_VQ><<<512, 256, 0, stream>>>(r3, patn, nullptr, nullptr, logits,
                                          8192, 512, 512, 0, epoch, tot, 4);
  vq_finalize<<<2048, 256, 0, stream>>>(logits, patterns, emb, assign, idxf);
}

// Round 4
// 9358.164 us; speedup vs baseline: 3.3304x; 3.3304x over previous
//
#include <hip/hip_runtime.h>

#define DEV __device__ __forceinline__

constexpr int T_SEQ = 1024;
constexpr int DMODEL = 512;
constexpr int NSYM = 1024;
constexpr int NPAT = 512;

// ---------------- epilogue modes ----------------
enum { E_BIAS = 0, E_GUMBEL = 1, E_POS = 2, E_RES = 3, E_GELU = 4, E_VQ = 5 };

// ---------------- fp32 GEMM v3 ------------------------------------------------
// C[M,N] = A[M,K] * op(B) + epilogue.  NNLAY=0: B is [N,K]. NNLAY=1: B is [K,N].
// BM=64, BN=128, BK=32, 256 threads (2x2 waves, 4x8 micro-tile per lane).
// Double-buffered LDS, one barrier/iter. Prefetch registers are NAMED float4
// scalars inlined via macros (no lambdas / no register arrays -> no scratch).
template <int NNLAY, int EPI>
__global__ __launch_bounds__(256, 2) void gemm3(
    const float* __restrict__ A, const float* __restrict__ Bm,
    const float* __restrict__ bias, const float* __restrict__ res,
    float* __restrict__ C, int M, int N, int K, int resMask,
    const int* __restrict__ ep, const int* __restrict__ tot, int gx) {
  constexpr int BM = 64, BN = 128, BK = 32;
  __shared__ __align__(16) float As[2][BK][BM + 4];
  __shared__ __align__(16) float Bs[2][BK][BN + 4];
  (void)M;

  // bijective XCD swizzle (grids here are multiples of 8): consecutive logical
  // blocks (sharing an A panel, x-fastest) land on one XCD for L2 reuse.
  const int nwg = gridDim.x;
  const int orig = blockIdx.x;
  const int q = nwg >> 3;
  const int xcd = orig & 7, slot = orig >> 3;
  const int wg = xcd * q + slot;
  const int by = wg / gx, bx = wg % gx;
  const int bm = by * BM, bn = bx * BN;

  const int tid = threadIdx.x;
  const int w = tid >> 6, lane = tid & 63;
  const int wy = w >> 1, wx = w & 1;        // 2x2 wave grid
  const int ly = lane >> 3, lx = lane & 7;  // 8x8 lane grid
  const int row0 = wy * 32 + ly * 4;        // 4 rows per lane
  const int col0 = wx * 64 + lx * 8;        // 8 cols per lane

  const int arow = tid >> 3, ac4 = (tid & 7) << 2;  // A stage: rows arow,+32
  const int brK = tid >> 5, bcN = (tid & 31) << 2;  // B NN stage

#define G3_LOAD(k0)                                                       \
  {                                                                       \
    const float* Ap = A + (size_t)(bm + arow) * K + (k0) + ac4;           \
    pa0 = *(const float4*)Ap;                                             \
    pa1 = *(const float4*)(Ap + (size_t)32 * K);                          \
    if constexpr (NNLAY == 0) {                                           \
      const float* Bp = Bm + (size_t)(bn + arow) * K + (k0) + ac4;        \
      pb0 = *(const float4*)Bp;                                           \
      pb1 = *(const float4*)(Bp + (size_t)32 * K);                        \
      pb2 = *(const float4*)(Bp + (size_t)64 * K);                        \
      pb3 = *(const float4*)(Bp + (size_t)96 * K);                        \
    } else {                                                              \
      const float* Bp = Bm + (size_t)((k0) + brK) * N + bn + bcN;         \
      pb0 = *(const float4*)Bp;                                           \
      pb1 = *(const float4*)(Bp + (size_t)8 * N);                         \
      pb2 = *(const float4*)(Bp + (size_t)16 * N);                        \
      pb3 = *(const float4*)(Bp + (size_t)24 * N);                        \
    }                                                                     \
  }

#define G3_STORE(buf)                                                     \
  {                                                                       \
    As[buf][ac4 + 0][arow] = pa0.x;                                       \
    As[buf][ac4 + 1][arow] = pa0.y;                                       \
    As[buf][ac4 + 2][arow] = pa0.z;                                       \
    As[buf][ac4 + 3][arow] = pa0.w;                                       \
    As[buf][ac4 + 0][arow + 32] = pa1.x;                                  \
    As[buf][ac4 + 1][arow + 32] = pa1.y;                                  \
    As[buf][ac4 + 2][arow + 32] = pa1.z;                                  \
    As[buf][ac4 + 3][arow + 32] = pa1.w;                                  \
    if constexpr (NNLAY == 0) {                                           \
      Bs[buf][ac4 + 0][arow] = pb0.x;                                     \
      Bs[buf][ac4 + 1][arow] = pb0.y;                                     \
      Bs[buf][ac4 + 2][arow] = pb0.z;                                     \
      Bs[buf][ac4 + 3][arow] = pb0.w;                                     \
      Bs[buf][ac4 + 0][arow + 32] = pb1.x;                                \
      Bs[buf][ac4 + 1][arow + 32] = pb1.y;                                \
      Bs[buf][ac4 + 2][arow + 32] = pb1.z;                                \
      Bs[buf][ac4 + 3][arow + 32] = pb1.w;                                \
      Bs[buf][ac4 + 0][arow + 64] = pb2.x;                                \
      Bs[buf][ac4 + 1][arow + 64] = pb2.y;                                \
      Bs[buf][ac4 + 2][arow + 64] = pb2.z;                                \
      Bs[buf][ac4 + 3][arow + 64] = pb2.w;                                \
      Bs[buf][ac4 + 0][arow + 96] = pb3.x;                                \
      Bs[buf][ac4 + 1][arow + 96] = pb3.y;                                \
      Bs[buf][ac4 + 2][arow + 96] = pb3.z;                                \
      Bs[buf][ac4 + 3][arow + 96] = pb3.w;                                \
    } else {                                                              \
      *(float4*)&Bs[buf][brK][bcN] = pb0;                                 \
      *(float4*)&Bs[buf][brK + 8][bcN] = pb1;                             \
      *(float4*)&Bs[buf][brK + 16][bcN] = pb2;                            \
      *(float4*)&Bs[buf][brK + 24][bcN] = pb3;                            \
    }                                                                     \
  }

#define G3_COMPUTE(buf)                                                   \
  _Pragma("unroll") for (int k = 0; k < BK; ++k) {                        \
    const float4 a0 = *(const float4*)&As[buf][k][row0];                  \
    const float4 b0 = *(const float4*)&Bs[buf][k][col0];                  \
    const float4 b1 = *(const float4*)&Bs[buf][k][col0 + 4];              \
    acc[0][0] = fmaf(a0.x, b0.x, acc[0][0]);                              \
    acc[0][1] = fmaf(a0.x, b0.y, acc[0][1]);                              \
    acc[0][2] = fmaf(a0.x, b0.z, acc[0][2]);                              \
    acc[0][3] = fmaf(a0.x, b0.w, acc[0][3]);                              \
    acc[0][4] = fmaf(a0.x, b1.x, acc[0][4]);                              \
    acc[0][5] = fmaf(a0.x, b1.y, acc[0][5]);                              \
    acc[0][6] = fmaf(a0.x, b1.z, acc[0][6]);                              \
    acc[0][7] = fmaf(a0.x, b1.w, acc[0][7]);                              \
    acc[1][0] = fmaf(a0.y, b0.x, acc[1][0]);                              \
    acc[1][1] = fmaf(a0.y, b0.y, acc[1][1]);                              \
    acc[1][2] = fmaf(a0.y, b0.z, acc[1][2]);                              \
    acc[1][3] = fmaf(a0.y, b0.w, acc[1][3]);                              \
    acc[1][4] = fmaf(a0.y, b1.x, acc[1][4]);                              \
    acc[1][5] = fmaf(a0.y, b1.y, acc[1][5]);                              \
    acc[1][6] = fmaf(a0.y, b1.z, acc[1][6]);                              \
    acc[1][7] = fmaf(a0.y, b1.w, acc[1][7]);                              \
    acc[2][0] = fmaf(a0.z, b0.x, acc[2][0]);                              \
    acc[2][1] = fmaf(a0.z, b0.y, acc[2][1]);                              \
    acc[2][2] = fmaf(a0.z, b0.z, acc[2][2]);                              \
    acc[2][3] = fmaf(a0.z, b0.w, acc[2][3]);                              \
    acc[2][4] = fmaf(a0.z, b1.x, acc[2][4]);                              \
    acc[2][5] = fmaf(a0.z, b1.y, acc[2][5]);                              \
    acc[2][6] = fmaf(a0.z, b1.z, acc[2][6]);                              \
    acc[2][7] = fmaf(a0.z, b1.w, acc[2][7]);                              \
    acc[3][0] = fmaf(a0.w, b0.x, acc[3][0]);                              \
    acc[3][1] = fmaf(a0.w, b0.y, acc[3][1]);                              \
    acc[3][2] = fmaf(a0.w, b0.z, acc[3][2]);                              \
    acc[3][3] = fmaf(a0.w, b0.w, acc[3][3]);                              \
    acc[3][4] = fmaf(a0.w, b1.x, acc[3][4]);                              \
    acc[3][5] = fmaf(a0.w, b1.y, acc[3][5]);                              \
    acc[3][6] = fmaf(a0.w, b1.z, acc[3][6]);                              \
    acc[3][7] = fmaf(a0.w, b1.w, acc[3][7]);                              \
  }

  float4 pa0, pa1, pb0, pb1, pb2, pb3;
  float acc[4][8];
#pragma unroll
  for (int i = 0; i < 4; ++i)
#pragma unroll
    for (int j = 0; j < 8; ++j) acc[i][j] = 0.0f;

  const int nt = K / BK;
  G3_LOAD(0);
  G3_STORE(0);
  __syncthreads();
  for (int t = 0; t < nt - 1; ++t) {
    const int cur = t & 1;
    G3_LOAD((t + 1) * BK);
    G3_COMPUTE(cur);
    G3_STORE(cur ^ 1);
    __syncthreads();
  }
  G3_COMPUTE((nt - 1) & 1);

#undef G3_LOAD
#undef G3_STORE
#undef G3_COMPUTE

  // ---- epilogue ----
  const int ncol = bn + col0;
  float bb[8];
  if constexpr (EPI == E_BIAS || EPI == E_RES || EPI == E_GELU) {
    *(float4*)&bb[0] = *(const float4*)(bias + ncol);
    *(float4*)&bb[4] = *(const float4*)(bias + ncol + 4);
  }
  float invt = 1.0f;
  if constexpr (EPI == E_VQ) {
    float t = 1.0f - 0.5f * (float)ep[0] / (float)tot[0];
    invt = 1.0f / fmaxf(0.5f, t);
  }
#pragma unroll
  for (int i = 0; i < 4; ++i) {
    const int m = bm + row0 + i;
    float o[8];
#pragma unroll
    for (int j = 0; j < 8; ++j) o[j] = acc[i][j];
    if constexpr (EPI == E_BIAS) {
#pragma unroll
      for (int j = 0; j < 8; ++j) o[j] += bb[j];
    } else if constexpr (EPI == E_GUMBEL) {
      float g[8];
      *(float4*)&g[0] = *(const float4*)(res + (size_t)m * N + ncol);
      *(float4*)&g[4] = *(const float4*)(res + (size_t)m * N + ncol + 4);
#pragma unroll
      for (int j = 0; j < 8; ++j) o[j] = 4.0f * o[j] + 2.0f * g[j];
    } else if constexpr (EPI == E_POS) {
      float g[8];
      const size_t pr = (size_t)(m & resMask) * N + ncol;
      *(float4*)&g[0] = *(const float4*)(res + pr);
      *(float4*)&g[4] = *(const float4*)(res + pr + 4);
#pragma unroll
      for (int j = 0; j < 8; ++j) o[j] += g[j];
    } else if constexpr (EPI == E_RES) {
      float g[8];
      *(float4*)&g[0] = *(const float4*)(res + (size_t)m * N + ncol);
      *(float4*)&g[4] = *(const float4*)(res + (size_t)m * N + ncol + 4);
#pragma unroll
      for (int j = 0; j < 8; ++j) o[j] += bb[j] + g[j];
    } else if constexpr (EPI == E_GELU) {
#pragma unroll
      for (int j = 0; j < 8; ++j) {
        float t = o[j] + bb[j];
        o[j] = 0.5f * t * (1.0f + erff(t * 0.7071067811865476f));
      }
    } else if constexpr (EPI == E_VQ) {
#pragma unroll
      for (int j = 0; j < 8; ++j) o[j] *= invt;
    }
    *(float4*)(C + (size_t)m * N + ncol) = *(float4*)&o[0];
    *(float4*)(C + (size_t)m * N + ncol + 4) = *(float4*)&o[4];
  }
}

// ---------------- flash attention v2 -----------------------------------------
// 4 waves/block, each wave owns 32 q-rows; K/V 64x64 tiles shared in LDS.
DEV int SW(int x) { return ((x ^ (x >> 3)) & 7) << 2; }

__global__ __launch_bounds__(256) void flash_attn2(
    const float* __restrict__ qkv, float* __restrict__ outp) {
  __shared__ __align__(16) float QT[4][64][32];  // [wave][d][q ^ SW(d)]
  __shared__ __align__(16) float KT[64][64];     // [d][k ^ SW(d)]
  __shared__ __align__(16) float Vs[64][64];     // [kv][d ^ SW(kv)]
  const int tid = threadIdx.x;
  const int w = tid >> 6, lane = tid & 63;
  const int ly = lane >> 3, lx = lane & 7;
  const int qt = blockIdx.x;  // 0..7 (128 q-rows per block)
  const int bh = blockIdx.y;  // 0..63
  const int b = bh >> 3, hh = bh & 7;

  const int qbase = qt * 128 + w * 32;
  const int lr = lane >> 4;          // 0..3
  const int lc = (lane & 15) << 2;   // 0,4,..,60
  const size_t baseQ = ((size_t)(b * T_SEQ + qbase)) * 1536 + hh * 64;
#pragma unroll
  for (int i = 0; i < 8; ++i) {
    int r = lr + 4 * i;  // 0..31
    float4 v = *(const float4*)(qkv + baseQ + (size_t)r * 1536 + lc);
    QT[w][lc + 0][r ^ SW(lc + 0)] = v.x;
    QT[w][lc + 1][r ^ SW(lc + 1)] = v.y;
    QT[w][lc + 2][r ^ SW(lc + 2)] = v.z;
    QT[w][lc + 3][r ^ SW(lc + 3)] = v.w;
  }

  float o[4][8] = {};
  float mrun[4], lrun[4];
#pragma unroll
  for (int i = 0; i < 4; ++i) {
    mrun[i] = -__builtin_huge_valf();
    lrun[i] = 0.0f;
  }

  const int kr = tid >> 4;          // 0..15
  const int kc = (tid & 15) << 2;   // 0,4,..,60

  for (int kt = 0; kt < 16; ++kt) {
    __syncthreads();
    const size_t baseK =
        ((size_t)(b * T_SEQ + kt * 64)) * 1536 + 512 + hh * 64;
#pragma unroll
    for (int jj = 0; jj < 4; ++jj) {
      int r = kr + 16 * jj;  // 0..63
      float4 kv4 = *(const float4*)(qkv + baseK + (size_t)r * 1536 + kc);
      KT[kc + 0][r ^ SW(kc + 0)] = kv4.x;
      KT[kc + 1][r ^ SW(kc + 1)] = kv4.y;
      KT[kc + 2][r ^ SW(kc + 2)] = kv4.z;
      KT[kc + 3][r ^ SW(kc + 3)] = kv4.w;
      float4 vv4 = *(const float4*)(qkv + baseK + 512 + (size_t)r * 1536 + kc);
      *(float4*)&Vs[r][kc ^ SW(r)] = vv4;
    }
    __syncthreads();

    float s[4][8] = {};
#pragma unroll 4
    for (int d = 0; d < 64; ++d) {
      int sw = SW(d);
      float q[4], k[8];
      *(float4*)&q[0] = *(const float4*)&QT[w][d][(4 * ly) ^ sw];
      *(float4*)&k[0] = *(const float4*)&KT[d][(8 * lx) ^ sw];
      *(float4*)&k[4] = *(const float4*)&KT[d][(8 * lx + 4) ^ sw];
#pragma unroll
      for (int i = 0; i < 4; ++i)
#pragma unroll
        for (int j = 0; j < 8; ++j) s[i][j] = fmaf(q[i], k[j], s[i][j]);
    }

#pragma unroll
    for (int i = 0; i < 4; ++i) {
#pragma unroll
      for (int j = 0; j < 8; ++j) s[i][j] *= 0.125f;
      float rm = s[i][0];
#pragma unroll
      for (int j = 1; j < 8; ++j) rm = fmaxf(rm, s[i][j]);
      rm = fmaxf(rm, __shfl_xor(rm, 1));
      rm = fmaxf(rm, __shfl_xor(rm, 2));
      rm = fmaxf(rm, __shfl_xor(rm, 4));
      float mnew = fmaxf(mrun[i], rm);
      float alpha = expf(mrun[i] - mnew);
      float rs = 0.0f;
#pragma unroll
      for (int j = 0; j < 8; ++j) {
        float p = expf(s[i][j] - mnew);
        s[i][j] = p;
        rs += p;
      }
      rs += __shfl_xor(rs, 1);
      rs += __shfl_xor(rs, 2);
      rs += __shfl_xor(rs, 4);
      lrun[i] = lrun[i] * alpha + rs;
      mrun[i] = mnew;
#pragma unroll
      for (int j = 0; j < 8; ++j) o[i][j] *= alpha;
    }

#pragma unroll 4
    for (int c = 0; c < 64; ++c) {
      const int srcl = (ly << 3) | (c >> 3);
      float pb[4];
      pb[0] = __shfl(s[0][c & 7], srcl);
      pb[1] = __shfl(s[1][c & 7], srcl);
      pb[2] = __shfl(s[2][c & 7], srcl);
      pb[3] = __shfl(s[3][c & 7], srcl);
      int sw = SW(c);
      float vv[8];
      *(float4*)&vv[0] = *(const float4*)&Vs[c][(8 * lx) ^ sw];
      *(float4*)&vv[4] = *(const float4*)&Vs[c][(8 * lx + 4) ^ sw];
#pragma unroll
      for (int i = 0; i < 4; ++i)
#pragma unroll
        for (int j = 0; j < 8; ++j) o[i][j] = fmaf(pb[i], vv[j], o[i][j]);
    }
  }

  const size_t baseO = ((size_t)(b * T_SEQ + qbase)) * DMODEL + hh * 64;
#pragma unroll
  for (int i = 0; i < 4; ++i) {
    float inv = 1.0f / lrun[i];
    int r = 4 * ly + i;
    float4 w0 = make_float4(o[i][0] * inv, o[i][1] * inv, o[i][2] * inv,
                            o[i][3] * inv);
    float4 w1 = make_float4(o[i][4] * inv, o[i][5] * inv, o[i][6] * inv,
                            o[i][7] * inv);
    *(float4*)(outp + baseO + (size_t)r * DMODEL + 8 * lx) = w0;
    *(float4*)(outp + baseO + (size_t)r * DMODEL + 8 * lx + 4) = w1;
  }
}

// ---------------- row kernels (D=512, one wave per row, 4 rows/block) --------
DEV float wave_sum(float v) {
#pragma unroll
  for (int off = 1; off < 64; off <<= 1) v += __shfl_xor(v, off);
  return v;
}

template <int DOL2>
__global__ __launch_bounds__(256) void ln_kernel(const float* __restrict__ x,
                                                 const float* __restrict__ g,
                                                 const float* __restrict__ b,
                                                 float* __restrict__ y) {
  const int row = blockIdx.x * 4 + (threadIdx.x >> 6);
  const int lane = threadIdx.x & 63;
  const float* xr = x + (size_t)row * DMODEL;
  float v[8];
  *(float4*)&v[0] = *(const float4*)(xr + lane * 8);
  *(float4*)&v[4] = *(const float4*)(xr + lane * 8 + 4);
  float s = 0.0f;
#pragma unroll
  for (int j = 0; j < 8; ++j) s += v[j];
  s = wave_sum(s);
  float mean = s * (1.0f / 512.0f);
  float s2 = 0.0f;
#pragma unroll
  for (int j = 0; j < 8; ++j) {
    float d = v[j] - mean;
    s2 += d * d;
  }
  s2 = wave_sum(s2);
  float rstd = 1.0f / sqrtf(s2 * (1.0f / 512.0f) + 1e-5f);
  float gg[8], bv[8];
  *(float4*)&gg[0] = *(const float4*)(g + lane * 8);
  *(float4*)&gg[4] = *(const float4*)(g + lane * 8 + 4);
  *(float4*)&bv[0] = *(const float4*)(b + lane * 8);
  *(float4*)&bv[4] = *(const float4*)(b + lane * 8 + 4);
  float t[8];
#pragma unroll
  for (int j = 0; j < 8; ++j) t[j] = (v[j] - mean) * rstd * gg[j] + bv[j];
  if constexpr (DOL2) {
    float n2 = 0.0f;
#pragma unroll
    for (int j = 0; j < 8; ++j) n2 += t[j] * t[j];
    n2 = wave_sum(n2);
    float den = fmaxf(sqrtf(n2), 1e-12f);
#pragma unroll
    for (int j = 0; j < 8; ++j) t[j] /= den;
  }
  float* yr = y + (size_t)row * DMODEL;
  *(float4*)(yr + lane * 8) = *(float4*)&t[0];
  *(float4*)(yr + lane * 8 + 4) = *(float4*)&t[4];
}

__global__ __launch_bounds__(256) void l2_rows(const float* __restrict__ x,
                                               float* __restrict__ y) {
  const int row = blockIdx.x * 4 + (threadIdx.x >> 6);
  const int lane = threadIdx.x & 63;
  const float* xr = x + (size_t)row * DMODEL;
  float v[8];
  *(float4*)&v[0] = *(const float4*)(xr + lane * 8);
  *(float4*)&v[4] = *(const float4*)(xr + lane * 8 + 4);
  float n2 = 0.0f;
#pragma unroll
  for (int j = 0; j < 8; ++j) n2 += v[j] * v[j];
  n2 = wave_sum(n2);
  float den = fmaxf(sqrtf(n2), 1e-12f);
#pragma unroll
  for (int j = 0; j < 8; ++j) v[j] /= den;
  float* yr = y + (size_t)row * DMODEL;
  *(float4*)(yr + lane * 8) = *(float4*)&v[0];
  *(float4*)(yr + lane * 8 + 4) = *(float4*)&v[4];
}

// in-place softmax over rows of length 1024 (one block of 256 per row)
__global__ __launch_bounds__(256) void softmax_rows(float* __restrict__ p) {
  const int row = blockIdx.x;
  const int tid = threadIdx.x;
  float* pr = p + (size_t)row * NSYM;
  float4 v = *(const float4*)(pr + tid * 4);
  float m = fmaxf(fmaxf(v.x, v.y), fmaxf(v.z, v.w));
#pragma unroll
  for (int off = 1; off < 64; off <<= 1) m = fmaxf(m, __shfl_xor(m, off));
  __shared__ float red[4];
  const int wv = tid >> 6;
  if ((tid & 63) == 0) red[wv] = m;
  __syncthreads();
  m = fmaxf(fmaxf(red[0], red[1]), fmaxf(red[2], red[3]));
  float e0 = expf(v.x - m), e1 = expf(v.y - m), e2 = expf(v.z - m),
        e3 = expf(v.w - m);
  float s = e0 + e1 + e2 + e3;
#pragma unroll
  for (int off = 1; off < 64; off <<= 1) s += __shfl_xor(s, off);
  __syncthreads();
  if ((tid & 63) == 0) red[wv] = s;
  __syncthreads();
  s = red[0] + red[1] + red[2] + red[3];
  float4 w = make_float4(e0 / s, e1 / s, e2 / s, e3 / s);
  *(float4*)(pr + tid * 4) = w;
}

// argmax + one_hot + gather (one wave per row)
__global__ __launch_bounds__(256) void vq_finalize(
    const float* __restrict__ logits, const float* __restrict__ patterns,
    float* __restrict__ emb, float* __restrict__ assign,
    float* __restrict__ idxf) {
  const int row = blockIdx.x * 4 + (threadIdx.x >> 6);
  const int lane = threadIdx.x & 63;
  const float* lr = logits + (size_t)row * NPAT;
  float best = -__builtin_huge_valf();
  int bi = 0;
#pragma unroll
  for (int jj = 0; jj < 8; ++jj) {
    int j = lane + jj * 64;
    float v = lr[j];
    if (v > best) {
      best = v;
      bi = j;
    }
  }
#pragma unroll
  for (int off = 1; off < 64; off <<= 1) {
    float ob = __shfl_xor(best, off);
    int oi = __shfl_xor(bi, off);
    if (ob > best || (ob == best && oi < bi)) {
      best = ob;
      bi = oi;
    }
  }
  const float* pr = patterns + (size_t)bi * DMODEL;
#pragma unroll
  for (int g = 0; g < 2; ++g) {
    int c = lane * 8 + g * 4;
    float4 pv = *(const float4*)(pr + c);
    *(float4*)(emb + (size_t)row * DMODEL + c) = pv;
    float4 av;
    av.x = (c + 0 == bi) ? 1.0f : 0.0f;
    av.y = (c + 1 == bi) ? 1.0f : 0.0f;
    av.z = (c + 2 == bi) ? 1.0f : 0.0f;
    av.w = (c + 3 == bi) ? 1.0f : 0.0f;
    *(float4*)(assign + (size_t)row * NPAT + c) = av;
  }
  if (lane == 0) idxf[row] = (float)bi;
}

// ---------------- host launch ----------------
extern "C" void kernel_launch(void* const* d_in, const int* in_sizes, int n_in,
                              void* d_out, int out_size, void* d_ws,
                              size_t ws_size, hipStream_t stream) {
  (void)in_sizes;
  (void)n_in;
  (void)out_size;
  (void)ws_size;
  const float* x = (const float*)d_in[0];
  const float* gumbel = (const float*)d_in[1];
  const float* sym_w = (const float*)d_in[2];
  const float* sym_b = (const float*)d_in[3];
  const float* codebook = (const float*)d_in[4];
  const float* pos_enc = (const float*)d_in[5];
  const float* attn_in_w = (const float*)d_in[6];
  const float* attn_in_b = (const float*)d_in[7];
  const float* attn_out_w = (const float*)d_in[8];
  const float* attn_out_b = (const float*)d_in[9];
  const float* n1_g = (const float*)d_in[10];
  const float* n1_b = (const float*)d_in[11];
  const float* n2_g = (const float*)d_in[12];
  const float* n2_b = (const float*)d_in[13];
  const float* ffn_w1 = (const float*)d_in[14];
  const float* ffn_b1 = (const float*)d_in[15];
  const float* ffn_w2 = (const float*)d_in[16];
  const float* ffn_b2 = (const float*)d_in[17];
  const float* q_w = (const float*)d_in[18];
  const float* q_b = (const float*)d_in[19];
  const float* qln_g = (const float*)d_in[20];
  const float* qln_b = (const float*)d_in[21];
  const float* patterns = (const float*)d_in[22];
  const int* epoch = (const int*)d_in[23];
  const int* tot = (const int*)d_in[24];

  float* out = (float*)d_out;
  float* emb = out;                    // [8192,512]
  float* assign = out + 4194304;       // [8192,512]
  float* logits = out + 8388608;       // [8192,512]
  float* h = out + 12582912;           // [8192,512]
  float* idxf = out + 16777216;        // [8192]

  float* ws = (float*)d_ws;
  float* r1 = ws;                      // 16777216 floats: soft/qkv/mid
  float* hn = ws + 16777216;           // 4194304
  float* r3 = ws + 20971520;           // 4194304: hp/attno/q
  float* cbn = ws + 25165824;          // 524288
  float* patn = ws + 25690112;         // 262144

  // 1. hp = x @ sym_w^T + sym_b   [8192,512] K=1024
  gemm3<0, E_BIAS><<<512, 256, 0, stream>>>(x, sym_w, sym_b, nullptr, r3, 8192,
                                            512, 1024, 0, nullptr, nullptr, 4);
  // 2. cbn = l2norm(codebook)  [1024,512]
  l2_rows<<<256, 256, 0, stream>>>(codebook, cbn);
  // 3. hp <- l2norm(hp) in place
  l2_rows<<<2048, 256, 0, stream>>>(r3, r3);
  // 4. soft_pre = 4*(hp_n@cbn^T) + 2*gumbel   [8192,1024] K=512
  gemm3<0, E_GUMBEL><<<1024, 256, 0, stream>>>(
      r3, cbn, nullptr, gumbel, r1, 8192, 1024, 512, 0, nullptr, nullptr, 8);
  // 5. softmax rows
  softmax_rows<<<8192, 256, 0, stream>>>(r1);
  // 6. h = soft @ codebook + pos_enc   [8192,512] K=1024 (NN)
  gemm3<1, E_POS><<<512, 256, 0, stream>>>(r1, codebook, nullptr, pos_enc, h,
                                           8192, 512, 1024, 1023, nullptr,
                                           nullptr, 4);

  for (int l = 0; l < 4; ++l) {
    const float* inw = attn_in_w + (size_t)l * 1536 * 512;
    const float* inb = attn_in_b + (size_t)l * 1536;
    const float* outw = attn_out_w + (size_t)l * 512 * 512;
    const float* outb = attn_out_b + (size_t)l * 512;
    const float* w1 = ffn_w1 + (size_t)l * 2048 * 512;
    const float* b1 = ffn_b1 + (size_t)l * 2048;
    const float* w2 = ffn_w2 + (size_t)l * 512 * 2048;
    const float* b2 = ffn_b2 + (size_t)l * 512;

    ln_kernel<0><<<2048, 256, 0, stream>>>(h, n1_g + l * 512, n1_b + l * 512,
                                           hn);
    gemm3<0, E_BIAS><<<1536, 256, 0, stream>>>(
        hn, inw, inb, nullptr, r1, 8192, 1536, 512, 0, nullptr, nullptr, 12);
    flash_attn2<<<dim3(8, 64), 256, 0, stream>>>(r1, r3);
    gemm3<0, E_RES><<<512, 256, 0, stream>>>(r3, outw, outb, h, h, 8192, 512,
                                             512, 0, nullptr, nullptr, 4);
    ln_kernel<0><<<2048, 256, 0, stream>>>(h, n2_g + l * 512, n2_b + l * 512,
                                           hn);
    gemm3<0, E_GELU><<<2048, 256, 0, stream>>>(
        hn, w1, b1, nullptr, r1, 8192, 2048, 512, 0, nullptr, nullptr, 16);
    gemm3<0, E_RES><<<512, 256, 0, stream>>>(r1, w2, b2, h, h, 8192, 512, 2048,
                                             0, nullptr, nullptr, 4);
  }

  // VQ head
  gemm3<0, E_BIAS><<<512, 256, 0, stream>>>(h, q_w, q_b, nullptr, r3, 8192, 512,
                                            512, 0, nullptr, nullptr, 4);
  ln_kernel<1><<<2048, 256, 0, stream>>>(r3, qln_g, qln_b, r3);
  l2_rows<<<128, 256, 0, stream>>>(patterns, patn);
  gemm3<0, E_VQ><<<512, 256, 0, stream>>>(r3, patn, nullptr, nullptr, logits,
                                          8192, 512, 512, 0, epoch, tot, 4);
  vq_finalize<<<2048, 256, 0, stream>>>(logits, patterns, emb, assign, idxf);
}

// Round 5
// 4503.725 us; speedup vs baseline: 6.9202x; 2.0779x over previous
//
#include <hip/hip_runtime.h>

#define DEV __device__ __forceinline__

constexpr int T_SEQ = 1024;
constexpr int DMODEL = 512;
constexpr int NSYM = 1024;
constexpr int NPAT = 512;

// ---------------- epilogue modes ----------------
enum { E_BIAS = 0, E_GUMBEL = 1, E_POS = 2, E_RES = 3, E_GELU = 4, E_VQ = 5 };

// ---------------- generic fp32 GEMM (R2-proven structure) ---------------------
// C[M,N] = A[M,K] * op(B) + epilogue.  NNLAY=0: B is [N,K] (NT). NNLAY=1: [K,N].
// Single-buffered LDS, BK=16, direct staged loads (proven: no scratch traffic).
// WR = rows per wave (64 -> 8x8 micro, 32 -> 4x8 micro; more waves/CU).
template <int BM, int BN, int WR, int NNLAY, int EPI>
__global__ __launch_bounds__((BM / WR) * (BN / 64) * 64) void gemm_f32(
    const float* __restrict__ A, const float* __restrict__ Bm,
    const float* __restrict__ bias, const float* __restrict__ res,
    float* __restrict__ C, int M, int N, int K, int resMask,
    const int* __restrict__ ep, const int* __restrict__ tot) {
  constexpr int BK = 16;
  constexpr int WN = BN / 64;
  constexpr int NW = (BM / WR) * WN;
  constexpr int NT = NW * 64;
  constexpr int RM = WR / 8;  // rows per lane
  __shared__ __align__(16) float As[BK][BM + 4];
  __shared__ __align__(16) float Bs[BK][BN + 4];
  const int tid = threadIdx.x;
  const int w = tid >> 6, lane = tid & 63;
  const int wy = w / WN, wx = w % WN;
  const int ly = lane >> 3, lx = lane & 7;
  const int bm = blockIdx.y * BM;
  const int bn = blockIdx.x * BN;
  const int rbase = wy * WR + ly * RM;

  float acc[RM][8];
#pragma unroll
  for (int i = 0; i < RM; ++i)
#pragma unroll
    for (int j = 0; j < 8; ++j) acc[i][j] = 0.0f;

  for (int k0 = 0; k0 < K; k0 += BK) {
#pragma unroll
    for (int i = 0; i < (BM * BK / 4) / NT; ++i) {
      int idx = tid + i * NT;
      int r = idx >> 2, c4 = (idx & 3) << 2;
      const float4 v = *(const float4*)(A + (size_t)(bm + r) * K + k0 + c4);
      As[c4 + 0][r] = v.x;
      As[c4 + 1][r] = v.y;
      As[c4 + 2][r] = v.z;
      As[c4 + 3][r] = v.w;
    }
    if constexpr (NNLAY == 0) {
#pragma unroll
      for (int i = 0; i < (BN * BK / 4) / NT; ++i) {
        int idx = tid + i * NT;
        int r = idx >> 2, c4 = (idx & 3) << 2;
        const float4 v = *(const float4*)(Bm + (size_t)(bn + r) * K + k0 + c4);
        Bs[c4 + 0][r] = v.x;
        Bs[c4 + 1][r] = v.y;
        Bs[c4 + 2][r] = v.z;
        Bs[c4 + 3][r] = v.w;
      }
    } else {
#pragma unroll
      for (int i = 0; i < (BN * BK / 4) / NT; ++i) {
        int idx = tid + i * NT;
        int r = idx / (BN / 4), c4 = (idx % (BN / 4)) * 4;
        *(float4*)&Bs[r][c4] =
            *(const float4*)(Bm + (size_t)(k0 + r) * N + bn + c4);
      }
    }
    __syncthreads();
#pragma unroll
    for (int k = 0; k < BK; ++k) {
      float a[RM], b[8];
#pragma unroll
      for (int r4 = 0; r4 < RM; r4 += 4)
        *(float4*)&a[r4] = *(const float4*)&As[k][rbase + r4];
      *(float4*)&b[0] = *(const float4*)&Bs[k][wx * 64 + lx * 8];
      *(float4*)&b[4] = *(const float4*)&Bs[k][wx * 64 + lx * 8 + 4];
#pragma unroll
      for (int i = 0; i < RM; ++i)
#pragma unroll
        for (int j = 0; j < 8; ++j) acc[i][j] = fmaf(a[i], b[j], acc[i][j]);
    }
    __syncthreads();
  }

  // ---- epilogue ----
  const int ncol = bn + wx * 64 + lx * 8;
  float bb[8];
  if constexpr (EPI == E_BIAS || EPI == E_RES || EPI == E_GELU) {
    *(float4*)&bb[0] = *(const float4*)(bias + ncol);
    *(float4*)&bb[4] = *(const float4*)(bias + ncol + 4);
  }
  float invt = 1.0f;
  if constexpr (EPI == E_VQ) {
    float t = 1.0f - 0.5f * (float)ep[0] / (float)tot[0];
    invt = 1.0f / fmaxf(0.5f, t);
  }
#pragma unroll
  for (int i = 0; i < RM; ++i) {
    const int m = bm + rbase + i;
    float o[8];
#pragma unroll
    for (int j = 0; j < 8; ++j) o[j] = acc[i][j];
    if constexpr (EPI == E_BIAS) {
#pragma unroll
      for (int j = 0; j < 8; ++j) o[j] += bb[j];
    } else if constexpr (EPI == E_GUMBEL) {
      float g[8];
      *(float4*)&g[0] = *(const float4*)(res + (size_t)m * N + ncol);
      *(float4*)&g[4] = *(const float4*)(res + (size_t)m * N + ncol + 4);
#pragma unroll
      for (int j = 0; j < 8; ++j) o[j] = 4.0f * o[j] + 2.0f * g[j];
    } else if constexpr (EPI == E_POS) {
      float g[8];
      const size_t pr = (size_t)(m & resMask) * N + ncol;
      *(float4*)&g[0] = *(const float4*)(res + pr);
      *(float4*)&g[4] = *(const float4*)(res + pr + 4);
#pragma unroll
      for (int j = 0; j < 8; ++j) o[j] += g[j];
    } else if constexpr (EPI == E_RES) {
      float g[8];
      *(float4*)&g[0] = *(const float4*)(res + (size_t)m * N + ncol);
      *(float4*)&g[4] = *(const float4*)(res + (size_t)m * N + ncol + 4);
#pragma unroll
      for (int j = 0; j < 8; ++j) o[j] += bb[j] + g[j];
    } else if constexpr (EPI == E_GELU) {
#pragma unroll
      for (int j = 0; j < 8; ++j) {
        float t = o[j] + bb[j];
        o[j] = 0.5f * t * (1.0f + erff(t * 0.7071067811865476f));
      }
    } else if constexpr (EPI == E_VQ) {
#pragma unroll
      for (int j = 0; j < 8; ++j) o[j] *= invt;
    }
    *(float4*)(C + (size_t)m * N + ncol) = *(float4*)&o[0];
    *(float4*)(C + (size_t)m * N + ncol + 4) = *(float4*)&o[4];
  }
}

// ---------------- flash attention v2 (R2-proven) ------------------------------
DEV int SW(int x) { return ((x ^ (x >> 3)) & 7) << 2; }

__global__ __launch_bounds__(256) void flash_attn2(
    const float* __restrict__ qkv, float* __restrict__ outp) {
  __shared__ __align__(16) float QT[4][64][32];  // [wave][d][q ^ SW(d)]
  __shared__ __align__(16) float KT[64][64];     // [d][k ^ SW(d)]
  __shared__ __align__(16) float Vs[64][64];     // [kv][d ^ SW(kv)]
  const int tid = threadIdx.x;
  const int w = tid >> 6, lane = tid & 63;
  const int ly = lane >> 3, lx = lane & 7;
  const int qt = blockIdx.x;  // 0..7 (128 q-rows per block)
  const int bh = blockIdx.y;  // 0..63
  const int b = bh >> 3, hh = bh & 7;

  const int qbase = qt * 128 + w * 32;
  const int lr = lane >> 4;          // 0..3
  const int lc = (lane & 15) << 2;   // 0,4,..,60
  const size_t baseQ = ((size_t)(b * T_SEQ + qbase)) * 1536 + hh * 64;
#pragma unroll
  for (int i = 0; i < 8; ++i) {
    int r = lr + 4 * i;  // 0..31
    float4 v = *(const float4*)(qkv + baseQ + (size_t)r * 1536 + lc);
    QT[w][lc + 0][r ^ SW(lc + 0)] = v.x;
    QT[w][lc + 1][r ^ SW(lc + 1)] = v.y;
    QT[w][lc + 2][r ^ SW(lc + 2)] = v.z;
    QT[w][lc + 3][r ^ SW(lc + 3)] = v.w;
  }

  float o[4][8] = {};
  float mrun[4], lrun[4];
#pragma unroll
  for (int i = 0; i < 4; ++i) {
    mrun[i] = -__builtin_huge_valf();
    lrun[i] = 0.0f;
  }

  const int kr = tid >> 4;          // 0..15
  const int kc = (tid & 15) << 2;   // 0,4,..,60

  for (int kt = 0; kt < 16; ++kt) {
    __syncthreads();
    const size_t baseK =
        ((size_t)(b * T_SEQ + kt * 64)) * 1536 + 512 + hh * 64;
#pragma unroll
    for (int jj = 0; jj < 4; ++jj) {
      int r = kr + 16 * jj;  // 0..63
      float4 kv4 = *(const float4*)(qkv + baseK + (size_t)r * 1536 + kc);
      KT[kc + 0][r ^ SW(kc + 0)] = kv4.x;
      KT[kc + 1][r ^ SW(kc + 1)] = kv4.y;
      KT[kc + 2][r ^ SW(kc + 2)] = kv4.z;
      KT[kc + 3][r ^ SW(kc + 3)] = kv4.w;
      float4 vv4 = *(const float4*)(qkv + baseK + 512 + (size_t)r * 1536 + kc);
      *(float4*)&Vs[r][kc ^ SW(r)] = vv4;
    }
    __syncthreads();

    float s[4][8] = {};
#pragma unroll 4
    for (int d = 0; d < 64; ++d) {
      int sw = SW(d);
      float q[4], k[8];
      *(float4*)&q[0] = *(const float4*)&QT[w][d][(4 * ly) ^ sw];
      *(float4*)&k[0] = *(const float4*)&KT[d][(8 * lx) ^ sw];
      *(float4*)&k[4] = *(const float4*)&KT[d][(8 * lx + 4) ^ sw];
#pragma unroll
      for (int i = 0; i < 4; ++i)
#pragma unroll
        for (int j = 0; j < 8; ++j) s[i][j] = fmaf(q[i], k[j], s[i][j]);
    }

#pragma unroll
    for (int i = 0; i < 4; ++i) {
#pragma unroll
      for (int j = 0; j < 8; ++j) s[i][j] *= 0.125f;
      float rm = s[i][0];
#pragma unroll
      for (int j = 1; j < 8; ++j) rm = fmaxf(rm, s[i][j]);
      rm = fmaxf(rm, __shfl_xor(rm, 1));
      rm = fmaxf(rm, __shfl_xor(rm, 2));
      rm = fmaxf(rm, __shfl_xor(rm, 4));
      float mnew = fmaxf(mrun[i], rm);
      float alpha = expf(mrun[i] - mnew);
      float rs = 0.0f;
#pragma unroll
      for (int j = 0; j < 8; ++j) {
        float p = expf(s[i][j] - mnew);
        s[i][j] = p;
        rs += p;
      }
      rs += __shfl_xor(rs, 1);
      rs += __shfl_xor(rs, 2);
      rs += __shfl_xor(rs, 4);
      lrun[i] = lrun[i] * alpha + rs;
      mrun[i] = mnew;
#pragma unroll
      for (int j = 0; j < 8; ++j) o[i][j] *= alpha;
    }

#pragma unroll 4
    for (int c = 0; c < 64; ++c) {
      const int srcl = (ly << 3) | (c >> 3);
      float pb[4];
      pb[0] = __shfl(s[0][c & 7], srcl);
      pb[1] = __shfl(s[1][c & 7], srcl);
      pb[2] = __shfl(s[2][c & 7], srcl);
      pb[3] = __shfl(s[3][c & 7], srcl);
      int sw = SW(c);
      float vv[8];
      *(float4*)&vv[0] = *(const float4*)&Vs[c][(8 * lx) ^ sw];
      *(float4*)&vv[4] = *(const float4*)&Vs[c][(8 * lx + 4) ^ sw];
#pragma unroll
      for (int i = 0; i < 4; ++i)
#pragma unroll
        for (int j = 0; j < 8; ++j) o[i][j] = fmaf(pb[i], vv[j], o[i][j]);
    }
  }

  const size_t baseO = ((size_t)(b * T_SEQ + qbase)) * DMODEL + hh * 64;
#pragma unroll
  for (int i = 0; i < 4; ++i) {
    float inv = 1.0f / lrun[i];
    int r = 4 * ly + i;
    float4 w0 = make_float4(o[i][0] * inv, o[i][1] * inv, o[i][2] * inv,
                            o[i][3] * inv);
    float4 w1 = make_float4(o[i][4] * inv, o[i][5] * inv, o[i][6] * inv,
                            o[i][7] * inv);
    *(float4*)(outp + baseO + (size_t)r * DMODEL + 8 * lx) = w0;
    *(float4*)(outp + baseO + (size_t)r * DMODEL + 8 * lx + 4) = w1;
  }
}

// ---------------- row kernels (D=512, one wave per row, 4 rows/block) --------
DEV float wave_sum(float v) {
#pragma unroll
  for (int off = 1; off < 64; off <<= 1) v += __shfl_xor(v, off);
  return v;
}

template <int DOL2>
__global__ __launch_bounds__(256) void ln_kernel(const float* __restrict__ x,
                                                 const float* __restrict__ g,
                                                 const float* __restrict__ b,
                                                 float* __restrict__ y) {
  const int row = blockIdx.x * 4 + (threadIdx.x >> 6);
  const int lane = threadIdx.x & 63;
  const float* xr = x + (size_t)row * DMODEL;
  float v[8];
  *(float4*)&v[0] = *(const float4*)(xr + lane * 8);
  *(float4*)&v[4] = *(const float4*)(xr + lane * 8 + 4);
  float s = 0.0f;
#pragma unroll
  for (int j = 0; j < 8; ++j) s += v[j];
  s = wave_sum(s);
  float mean = s * (1.0f / 512.0f);
  float s2 = 0.0f;
#pragma unroll
  for (int j = 0; j < 8; ++j) {
    float d = v[j] - mean;
    s2 += d * d;
  }
  s2 = wave_sum(s2);
  float rstd = 1.0f / sqrtf(s2 * (1.0f / 512.0f) + 1e-5f);
  float gg[8], bv[8];
  *(float4*)&gg[0] = *(const float4*)(g + lane * 8);
  *(float4*)&gg[4] = *(const float4*)(g + lane * 8 + 4);
  *(float4*)&bv[0] = *(const float4*)(b + lane * 8);
  *(float4*)&bv[4] = *(const float4*)(b + lane * 8 + 4);
  float t[8];
#pragma unroll
  for (int j = 0; j < 8; ++j) t[j] = (v[j] - mean) * rstd * gg[j] + bv[j];
  if constexpr (DOL2) {
    float n2 = 0.0f;
#pragma unroll
    for (int j = 0; j < 8; ++j) n2 += t[j] * t[j];
    n2 = wave_sum(n2);
    float den = fmaxf(sqrtf(n2), 1e-12f);
#pragma unroll
    for (int j = 0; j < 8; ++j) t[j] /= den;
  }
  float* yr = y + (size_t)row * DMODEL;
  *(float4*)(yr + lane * 8) = *(float4*)&t[0];
  *(float4*)(yr + lane * 8 + 4) = *(float4*)&t[4];
}

__global__ __launch_bounds__(256) void l2_rows(const float* __restrict__ x,
                                               float* __restrict__ y) {
  const int row = blockIdx.x * 4 + (threadIdx.x >> 6);
  const int lane = threadIdx.x & 63;
  const float* xr = x + (size_t)row * DMODEL;
  float v[8];
  *(float4*)&v[0] = *(const float4*)(xr + lane * 8);
  *(float4*)&v[4] = *(const float4*)(xr + lane * 8 + 4);
  float n2 = 0.0f;
#pragma unroll
  for (int j = 0; j < 8; ++j) n2 += v[j] * v[j];
  n2 = wave_sum(n2);
  float den = fmaxf(sqrtf(n2), 1e-12f);
#pragma unroll
  for (int j = 0; j < 8; ++j) v[j] /= den;
  float* yr = y + (size_t)row * DMODEL;
  *(float4*)(yr + lane * 8) = *(float4*)&v[0];
  *(float4*)(yr + lane * 8 + 4) = *(float4*)&v[4];
}

// in-place softmax over rows of length 1024 (one block of 256 per row)
__global__ __launch_bounds__(256) void softmax_rows(float* __restrict__ p) {
  const int row = blockIdx.x;
  const int tid = threadIdx.x;
  float* pr = p + (size_t)row * NSYM;
  float4 v = *(const float4*)(pr + tid * 4);
  float m = fmaxf(fmaxf(v.x, v.y), fmaxf(v.z, v.w));
#pragma unroll
  for (int off = 1; off < 64; off <<= 1) m = fmaxf(m, __shfl_xor(m, off));
  __shared__ float red[4];
  const int wv = tid >> 6;
  if ((tid & 63) == 0) red[wv] = m;
  __syncthreads();
  m = fmaxf(fmaxf(red[0], red[1]), fmaxf(red[2], red[3]));
  float e0 = expf(v.x - m), e1 = expf(v.y - m), e2 = expf(v.z - m),
        e3 = expf(v.w - m);
  float s = e0 + e1 + e2 + e3;
#pragma unroll
  for (int off = 1; off < 64; off <<= 1) s += __shfl_xor(s, off);
  __syncthreads();
  if ((tid & 63) == 0) red[wv] = s;
  __syncthreads();
  s = red[0] + red[1] + red[2] + red[3];
  float4 w = make_float4(e0 / s, e1 / s, e2 / s, e3 / s);
  *(float4*)(pr + tid * 4) = w;
}

// argmax + one_hot + gather (one wave per row)
__global__ __launch_bounds__(256) void vq_finalize(
    const float* __restrict__ logits, const float* __restrict__ patterns,
    float* __restrict__ emb, float* __restrict__ assign,
    float* __restrict__ idxf) {
  const int row = blockIdx.x * 4 + (threadIdx.x >> 6);
  const int lane = threadIdx.x & 63;
  const float* lr = logits + (size_t)row * NPAT;
  float best = -__builtin_huge_valf();
  int bi = 0;
#pragma unroll
  for (int jj = 0; jj < 8; ++jj) {
    int j = lane + jj * 64;
    float v = lr[j];
    if (v > best) {
      best = v;
      bi = j;
    }
  }
#pragma unroll
  for (int off = 1; off < 64; off <<= 1) {
    float ob = __shfl_xor(best, off);
    int oi = __shfl_xor(bi, off);
    if (ob > best || (ob == best && oi < bi)) {
      best = ob;
      bi = oi;
    }
  }
  const float* pr = patterns + (size_t)bi * DMODEL;
#pragma unroll
  for (int g = 0; g < 2; ++g) {
    int c = lane * 8 + g * 4;
    float4 pv = *(const float4*)(pr + c);
    *(float4*)(emb + (size_t)row * DMODEL + c) = pv;
    float4 av;
    av.x = (c + 0 == bi) ? 1.0f : 0.0f;
    av.y = (c + 1 == bi) ? 1.0f : 0.0f;
    av.z = (c + 2 == bi) ? 1.0f : 0.0f;
    av.w = (c + 3 == bi) ? 1.0f : 0.0f;
    *(float4*)(assign + (size_t)row * NPAT + c) = av;
  }
  if (lane == 0) idxf[row] = (float)bi;
}

// ---------------- host launch ----------------
extern "C" void kernel_launch(void* const* d_in, const int* in_sizes, int n_in,
                              void* d_out, int out_size, void* d_ws,
                              size_t ws_size, hipStream_t stream) {
  (void)in_sizes;
  (void)n_in;
  (void)out_size;
  (void)ws_size;
  const float* x = (const float*)d_in[0];
  const float* gumbel = (const float*)d_in[1];
  const float* sym_w = (const float*)d_in[2];
  const float* sym_b = (const float*)d_in[3];
  const float* codebook = (const float*)d_in[4];
  const float* pos_enc = (const float*)d_in[5];
  const float* attn_in_w = (const float*)d_in[6];
  const float* attn_in_b = (const float*)d_in[7];
  const float* attn_out_w = (const float*)d_in[8];
  const float* attn_out_b = (const float*)d_in[9];
  const float* n1_g = (const float*)d_in[10];
  const float* n1_b = (const float*)d_in[11];
  const float* n2_g = (const float*)d_in[12];
  const float* n2_b = (const float*)d_in[13];
  const float* ffn_w1 = (const float*)d_in[14];
  const float* ffn_b1 = (const float*)d_in[15];
  const float* ffn_w2 = (const float*)d_in[16];
  const float* ffn_b2 = (const float*)d_in[17];
  const float* q_w = (const float*)d_in[18];
  const float* q_b = (const float*)d_in[19];
  const float* qln_g = (const float*)d_in[20];
  const float* qln_b = (const float*)d_in[21];
  const float* patterns = (const float*)d_in[22];
  const int* epoch = (const int*)d_in[23];
  const int* tot = (const int*)d_in[24];

  float* out = (float*)d_out;
  float* emb = out;                    // [8192,512]
  float* assign = out + 4194304;       // [8192,512]
  float* logits = out + 8388608;       // [8192,512]
  float* h = out + 12582912;           // [8192,512]
  float* idxf = out + 16777216;        // [8192]

  float* ws = (float*)d_ws;
  float* r1 = ws;                      // 16777216 floats: soft/qkv/mid
  float* hn = ws + 16777216;           // 4194304
  float* r3 = ws + 20971520;           // 4194304: hp/attno/q
  float* cbn = ws + 25165824;          // 524288
  float* patn = ws + 25690112;         // 262144

  // 1. hp = x @ sym_w^T + sym_b   [8192,512] K=1024
  gemm_f32<64, 128, 32, 0, E_BIAS><<<dim3(4, 128), 256, 0, stream>>>(
      x, sym_w, sym_b, nullptr, r3, 8192, 512, 1024, 0, nullptr, nullptr);
  // 2. cbn = l2norm(codebook)  [1024,512]
  l2_rows<<<256, 256, 0, stream>>>(codebook, cbn);
  // 3. hp <- l2norm(hp) in place
  l2_rows<<<2048, 256, 0, stream>>>(r3, r3);
  // 4. soft_pre = 4*(hp_n@cbn^T) + 2*gumbel   [8192,1024] K=512
  gemm_f32<128, 128, 64, 0, E_GUMBEL><<<dim3(8, 64), 256, 0, stream>>>(
      r3, cbn, nullptr, gumbel, r1, 8192, 1024, 512, 0, nullptr, nullptr);
  // 5. softmax rows
  softmax_rows<<<8192, 256, 0, stream>>>(r1);
  // 6. h = soft @ codebook + pos_enc   [8192,512] K=1024 (NN)
  gemm_f32<64, 128, 32, 1, E_POS><<<dim3(4, 128), 256, 0, stream>>>(
      r1, codebook, nullptr, pos_enc, h, 8192, 512, 1024, 1023, nullptr,
      nullptr);

  for (int l = 0; l < 4; ++l) {
    const float* inw = attn_in_w + (size_t)l * 1536 * 512;
    const float* inb = attn_in_b + (size_t)l * 1536;
    const float* outw = attn_out_w + (size_t)l * 512 * 512;
    const float* outb = attn_out_b + (size_t)l * 512;
    const float* w1 = ffn_w1 + (size_t)l * 2048 * 512;
    const float* b1 = ffn_b1 + (size_t)l * 2048;
    const float* w2 = ffn_w2 + (size_t)l * 512 * 2048;
    const float* b2 = ffn_b2 + (size_t)l * 512;

    ln_kernel<0><<<2048, 256, 0, stream>>>(h, n1_g + l * 512, n1_b + l * 512,
                                           hn);
    gemm_f32<128, 128, 64, 0, E_BIAS><<<dim3(12, 64), 256, 0, stream>>>(
        hn, inw, inb, nullptr, r1, 8192, 1536, 512, 0, nullptr, nullptr);
    flash_attn2<<<dim3(8, 64), 256, 0, stream>>>(r1, r3);
    gemm_f32<64, 128, 32, 0, E_RES><<<dim3(4, 128), 256, 0, stream>>>(
        r3, outw, outb, h, h, 8192, 512, 512, 0, nullptr, nullptr);
    ln_kernel<0><<<2048, 256, 0, stream>>>(h, n2_g + l * 512, n2_b + l * 512,
                                           hn);
    gemm_f32<128, 128, 64, 0, E_GELU><<<dim3(16, 64), 256, 0, stream>>>(
        hn, w1, b1, nullptr, r1, 8192, 2048, 512, 0, nullptr, nullptr);
    gemm_f32<64, 128, 32, 0, E_RES><<<dim3(4, 128), 256, 0, stream>>>(
        r1, w2, b2, h, h, 8192, 512, 2048, 0, nullptr, nullptr);
  }

  // VQ head
  gemm_f32<64, 128, 32, 0, E_BIAS><<<dim3(4, 128), 256, 0, stream>>>(
      h, q_w, q_b, nullptr, r3, 8192, 512, 512, 0, nullptr, nullptr);
  ln_kernel<1><<<2048, 256, 0, stream>>>(r3, qln_g, qln_b, r3);
  l2_rows<<<128, 256, 0, stream>>>(patterns, patn);
  gemm_f32<64, 128, 32, 0, E_VQ><<<dim3(4, 128), 256, 0, stream>>>(
      r3, patn, nullptr, nullptr, logits, 8192, 512, 512, 0, epoch, tot);
  vq_finalize<<<2048, 256, 0, stream>>>(logits, patterns, emb, assign, idxf);
}

// Round 6
// 3236.674 us; speedup vs baseline: 9.6293x; 1.3915x over previous
//
#include <hip/hip_runtime.h>

#define DEV __device__ __forceinline__

typedef unsigned short u16;
typedef unsigned int u32;
typedef __attribute__((ext_vector_type(8))) short bf8_t;   // 8 bf16 (4 VGPR)
typedef __attribute__((ext_vector_type(4))) float f4_t;

constexpr int T_SEQ = 1024;
constexpr int DMODEL = 512;
constexpr int NPAT = 512;

// ---------------- epilogue modes ----------------
enum {
  E_BIAS = 0,
  E_VQ = 5,
  E_RES = 6,
  E_ACC = 7,
  E_POS = 8,
  E_GUM3 = 9,
  E_GELU3 = 10
};

// ---------------- bf16 triple-split helpers ----------------
DEV u16 f2bf(float x) {
  u32 u = __float_as_uint(x);
  u32 r = u + 0x7FFFu + ((u >> 16) & 1u);
  return (u16)(r >> 16);
}
DEV float bf2f(u16 h) { return __uint_as_float((u32)h << 16); }
DEV void split3(float x, u16& h, u16& m, u16& l) {
  h = f2bf(x);
  float r1 = x - bf2f(h);
  m = f2bf(r1);
  float r2 = r1 - bf2f(m);
  l = f2bf(r2);
}

// ---------------- MFMA GEMM, triple-bf16 split (fp32-accurate) ---------------
// C[M,N] = A[M,K]*B[N,K]^T via 6 bf16 products (hh,hm,mh,hl,mm,lh).
// A,B given as 3 bf16 planes each, row-major [rows][ld]. BN=128, BK=32,
// 4 waves (2x2), each wave computes (BM/2)x64 as (BM/32)x4 16x16 tiles.
template <int BM, int EPI>
__global__ __launch_bounds__(256, 2) void gemm_mf(
    const u16* __restrict__ Ah, const u16* __restrict__ Am,
    const u16* __restrict__ Al, const u16* __restrict__ Bh,
    const u16* __restrict__ Bm, const u16* __restrict__ Bl,
    const float* __restrict__ bias, const float* __restrict__ res,
    float* __restrict__ Cf, u16* __restrict__ Ch, u16* __restrict__ Cm,
    u16* __restrict__ Cl, int N, int KK, int lda, int ldb) {
  constexpr int MT = BM / 32;  // m-tiles per wave
  __shared__ __align__(16) u16 AsH[BM][4][8], AsM[BM][4][8], AsL[BM][4][8];
  __shared__ __align__(16) u16 BsH[128][4][8], BsM[128][4][8], BsL[128][4][8];
  const int tid = threadIdx.x;
  const int w = tid >> 6, lane = tid & 63;
  const int wy = w >> 1, wx = w & 1;
  const int lr = lane & 15, lg = lane >> 4;
  const int bm = blockIdx.y * BM, bn = blockIdx.x * 128;

  f4_t acc[MT][4];
#pragma unroll
  for (int mt = 0; mt < MT; ++mt)
#pragma unroll
    for (int nt = 0; nt < 4; ++nt) acc[mt][nt] = (f4_t){0.f, 0.f, 0.f, 0.f};

  for (int k0 = 0; k0 < KK; k0 += 32) {
    if (k0) __syncthreads();
    // stage A planes (BM*4 packets of 8 bf16)
#pragma unroll
    for (int u = 0; u < BM / 64; ++u) {
      int p = tid + u * 256;
      int row = p >> 2, kp = p & 3;
      int slot = kp ^ ((row >> 1) & 3);
      size_t g = (size_t)(bm + row) * lda + k0 + kp * 8;
      *(uint4*)&AsH[row][slot][0] = *(const uint4*)&Ah[g];
      *(uint4*)&AsM[row][slot][0] = *(const uint4*)&Am[g];
      *(uint4*)&AsL[row][slot][0] = *(const uint4*)&Al[g];
    }
    // stage B planes (512 packets)
#pragma unroll
    for (int u = 0; u < 2; ++u) {
      int p = tid + u * 256;
      int col = p >> 2, kp = p & 3;
      int slot = kp ^ ((col >> 1) & 3);
      size_t g = (size_t)(bn + col) * ldb + k0 + kp * 8;
      *(uint4*)&BsH[col][slot][0] = *(const uint4*)&Bh[g];
      *(uint4*)&BsM[col][slot][0] = *(const uint4*)&Bm[g];
      *(uint4*)&BsL[col][slot][0] = *(const uint4*)&Bl[g];
    }
    __syncthreads();

    bf8_t fah[MT], fam[MT], fal[MT], fbh[4], fbm[4], fbl[4];
#pragma unroll
    for (int mt = 0; mt < MT; ++mt) {
      int row = wy * (BM / 2) + mt * 16 + lr;
      int slot = lg ^ ((row >> 1) & 3);
      fah[mt] = *(const bf8_t*)&AsH[row][slot][0];
      fam[mt] = *(const bf8_t*)&AsM[row][slot][0];
      fal[mt] = *(const bf8_t*)&AsL[row][slot][0];
    }
#pragma unroll
    for (int nt = 0; nt < 4; ++nt) {
      int col = wx * 64 + nt * 16 + lr;
      int slot = lg ^ ((col >> 1) & 3);
      fbh[nt] = *(const bf8_t*)&BsH[col][slot][0];
      fbm[nt] = *(const bf8_t*)&BsM[col][slot][0];
      fbl[nt] = *(const bf8_t*)&BsL[col][slot][0];
    }
#pragma unroll
    for (int mt = 0; mt < MT; ++mt)
#pragma unroll
      for (int nt = 0; nt < 4; ++nt) {
        acc[mt][nt] = __builtin_amdgcn_mfma_f32_16x16x32_bf16(
            fah[mt], fbh[nt], acc[mt][nt], 0, 0, 0);
        acc[mt][nt] = __builtin_amdgcn_mfma_f32_16x16x32_bf16(
            fah[mt], fbm[nt], acc[mt][nt], 0, 0, 0);
        acc[mt][nt] = __builtin_amdgcn_mfma_f32_16x16x32_bf16(
            fam[mt], fbh[nt], acc[mt][nt], 0, 0, 0);
        acc[mt][nt] = __builtin_amdgcn_mfma_f32_16x16x32_bf16(
            fah[mt], fbl[nt], acc[mt][nt], 0, 0, 0);
        acc[mt][nt] = __builtin_amdgcn_mfma_f32_16x16x32_bf16(
            fam[mt], fbm[nt], acc[mt][nt], 0, 0, 0);
        acc[mt][nt] = __builtin_amdgcn_mfma_f32_16x16x32_bf16(
            fal[mt], fbh[nt], acc[mt][nt], 0, 0, 0);
      }
  }

  // ---- epilogue (C frag: col = lane&15, row = 4*(lane>>4)+i) ----
  float bv[4];
  if constexpr (EPI == E_BIAS || EPI == E_RES || EPI == E_GELU3) {
#pragma unroll
    for (int nt = 0; nt < 4; ++nt) bv[nt] = bias[bn + wx * 64 + nt * 16 + lr];
  }
#pragma unroll
  for (int mt = 0; mt < MT; ++mt)
#pragma unroll
    for (int nt = 0; nt < 4; ++nt) {
      const int c = bn + wx * 64 + nt * 16 + lr;
#pragma unroll
      for (int i = 0; i < 4; ++i) {
        const int m = bm + wy * (BM / 2) + mt * 16 + 4 * lg + i;
        const size_t idx = (size_t)m * N + c;
        float v = acc[mt][nt][i];
        if constexpr (EPI == E_BIAS) {
          Cf[idx] = v + bv[nt];
        } else if constexpr (EPI == E_RES) {
          Cf[idx] = v + bv[nt] + res[idx];
        } else if constexpr (EPI == E_ACC) {
          Cf[idx] += v;
        } else if constexpr (EPI == E_POS) {
          Cf[idx] = v + res[(size_t)(m & 1023) * N + c];
        } else if constexpr (EPI == E_GUM3) {
          float t = 4.0f * v + 2.0f * res[idx];
          u16 h2, m2, l2;
          split3(t, h2, m2, l2);
          Ch[idx] = h2;
          Cm[idx] = m2;
          Cl[idx] = l2;
        } else if constexpr (EPI == E_GELU3) {
          float t = v + bv[nt];
          float g = 0.5f * t * (1.0f + erff(t * 0.7071067811865476f));
          u16 h2, m2, l2;
          split3(g, h2, m2, l2);
          Ch[idx] = h2;
          Cm[idx] = m2;
          Cl[idx] = l2;
        }
      }
    }
}

// ---------------- fp32 vector GEMM (R5-proven; VQ-head precision anchor) -----
template <int BM, int BN, int WR, int EPI>
__global__ __launch_bounds__((BM / WR) * (BN / 64) * 64) void gemm_f32(
    const float* __restrict__ A, const float* __restrict__ Bmat,
    const float* __restrict__ bias, float* __restrict__ C, int M, int N, int K,
    const int* __restrict__ ep, const int* __restrict__ tot) {
  constexpr int BK = 16;
  constexpr int WN = BN / 64;
  constexpr int NW = (BM / WR) * WN;
  constexpr int NT = NW * 64;
  constexpr int RM = WR / 8;
  __shared__ __align__(16) float As[BK][BM + 4];
  __shared__ __align__(16) float Bs[BK][BN + 4];
  const int tid = threadIdx.x;
  const int w = tid >> 6, lane = tid & 63;
  const int wy = w / WN, wx = w % WN;
  const int ly = lane >> 3, lx = lane & 7;
  const int bm = blockIdx.y * BM;
  const int bn = blockIdx.x * BN;
  const int rbase = wy * WR + ly * RM;

  float acc[RM][8];
#pragma unroll
  for (int i = 0; i < RM; ++i)
#pragma unroll
    for (int j = 0; j < 8; ++j) acc[i][j] = 0.0f;

  for (int k0 = 0; k0 < K; k0 += BK) {
#pragma unroll
    for (int i = 0; i < (BM * BK / 4) / NT; ++i) {
      int idx = tid + i * NT;
      int r = idx >> 2, c4 = (idx & 3) << 2;
      const float4 v = *(const float4*)(A + (size_t)(bm + r) * K + k0 + c4);
      As[c4 + 0][r] = v.x;
      As[c4 + 1][r] = v.y;
      As[c4 + 2][r] = v.z;
      As[c4 + 3][r] = v.w;
    }
#pragma unroll
    for (int i = 0; i < (BN * BK / 4) / NT; ++i) {
      int idx = tid + i * NT;
      int r = idx >> 2, c4 = (idx & 3) << 2;
      const float4 v = *(const float4*)(Bmat + (size_t)(bn + r) * K + k0 + c4);
      Bs[c4 + 0][r] = v.x;
      Bs[c4 + 1][r] = v.y;
      Bs[c4 + 2][r] = v.z;
      Bs[c4 + 3][r] = v.w;
    }
    __syncthreads();
#pragma unroll
    for (int k = 0; k < BK; ++k) {
      float a[RM], b[8];
#pragma unroll
      for (int r4 = 0; r4 < RM; r4 += 4)
        *(float4*)&a[r4] = *(const float4*)&As[k][rbase + r4];
      *(float4*)&b[0] = *(const float4*)&Bs[k][wx * 64 + lx * 8];
      *(float4*)&b[4] = *(const float4*)&Bs[k][wx * 64 + lx * 8 + 4];
#pragma unroll
      for (int i = 0; i < RM; ++i)
#pragma unroll
        for (int j = 0; j < 8; ++j) acc[i][j] = fmaf(a[i], b[j], acc[i][j]);
    }
    __syncthreads();
  }

  const int ncol = bn + wx * 64 + lx * 8;
  float bb[8];
  if constexpr (EPI == E_BIAS) {
    *(float4*)&bb[0] = *(const float4*)(bias + ncol);
    *(float4*)&bb[4] = *(const float4*)(bias + ncol + 4);
  }
  float invt = 1.0f;
  if constexpr (EPI == E_VQ) {
    float t = 1.0f - 0.5f * (float)ep[0] / (float)tot[0];
    invt = 1.0f / fmaxf(0.5f, t);
  }
#pragma unroll
  for (int i = 0; i < RM; ++i) {
    const int m = bm + rbase + i;
    float o[8];
#pragma unroll
    for (int j = 0; j < 8; ++j) o[j] = acc[i][j];
    if constexpr (EPI == E_BIAS) {
#pragma unroll
      for (int j = 0; j < 8; ++j) o[j] += bb[j];
    } else if constexpr (EPI == E_VQ) {
#pragma unroll
      for (int j = 0; j < 8; ++j) o[j] *= invt;
    }
    *(float4*)(C + (size_t)m * N + ncol) = *(float4*)&o[0];
    *(float4*)(C + (size_t)m * N + ncol + 4) = *(float4*)&o[4];
  }
}

// ---------------- flash attention (R5 core; epilogue -> 3 bf16 planes) -------
DEV int SW(int x) { return ((x ^ (x >> 3)) & 7) << 2; }

__global__ __launch_bounds__(256) void flash_attn2(
    const float* __restrict__ qkv, u16* __restrict__ Oh, u16* __restrict__ Om,
    u16* __restrict__ Ol) {
  __shared__ __align__(16) float QT[4][64][32];
  __shared__ __align__(16) float KT[64][64];
  __shared__ __align__(16) float Vs[64][64];
  const int tid = threadIdx.x;
  const int w = tid >> 6, lane = tid & 63;
  const int ly = lane >> 3, lx = lane & 7;
  const int qt = blockIdx.x;
  const int bh = blockIdx.y;
  const int b = bh >> 3, hh = bh & 7;

  const int qbase = qt * 128 + w * 32;
  const int lr4 = lane >> 4;
  const int lc = (lane & 15) << 2;
  const size_t baseQ = ((size_t)(b * T_SEQ + qbase)) * 1536 + hh * 64;
#pragma unroll
  for (int i = 0; i < 8; ++i) {
    int r = lr4 + 4 * i;
    float4 v = *(const float4*)(qkv + baseQ + (size_t)r * 1536 + lc);
    QT[w][lc + 0][r ^ SW(lc + 0)] = v.x;
    QT[w][lc + 1][r ^ SW(lc + 1)] = v.y;
    QT[w][lc + 2][r ^ SW(lc + 2)] = v.z;
    QT[w][lc + 3][r ^ SW(lc + 3)] = v.w;
  }

  float o[4][8] = {};
  float mrun[4], lrun[4];
#pragma unroll
  for (int i = 0; i < 4; ++i) {
    mrun[i] = -__builtin_huge_valf();
    lrun[i] = 0.0f;
  }

  const int kr = tid >> 4;
  const int kc = (tid & 15) << 2;

  for (int kt = 0; kt < 16; ++kt) {
    __syncthreads();
    const size_t baseK = ((size_t)(b * T_SEQ + kt * 64)) * 1536 + 512 + hh * 64;
#pragma unroll
    for (int jj = 0; jj < 4; ++jj) {
      int r = kr + 16 * jj;
      float4 kv4 = *(const float4*)(qkv + baseK + (size_t)r * 1536 + kc);
      KT[kc + 0][r ^ SW(kc + 0)] = kv4.x;
      KT[kc + 1][r ^ SW(kc + 1)] = kv4.y;
      KT[kc + 2][r ^ SW(kc + 2)] = kv4.z;
      KT[kc + 3][r ^ SW(kc + 3)] = kv4.w;
      float4 vv4 = *(const float4*)(qkv + baseK + 512 + (size_t)r * 1536 + kc);
      *(float4*)&Vs[r][kc ^ SW(r)] = vv4;
    }
    __syncthreads();

    float s[4][8] = {};
#pragma unroll 4
    for (int d = 0; d < 64; ++d) {
      int sw = SW(d);
      float q[4], k[8];
      *(float4*)&q[0] = *(const float4*)&QT[w][d][(4 * ly) ^ sw];
      *(float4*)&k[0] = *(const float4*)&KT[d][(8 * lx) ^ sw];
      *(float4*)&k[4] = *(const float4*)&KT[d][(8 * lx + 4) ^ sw];
#pragma unroll
      for (int i = 0; i < 4; ++i)
#pragma unroll
        for (int j = 0; j < 8; ++j) s[i][j] = fmaf(q[i], k[j], s[i][j]);
    }

#pragma unroll
    for (int i = 0; i < 4; ++i) {
#pragma unroll
      for (int j = 0; j < 8; ++j) s[i][j] *= 0.125f;
      float rm = s[i][0];
#pragma unroll
      for (int j = 1; j < 8; ++j) rm = fmaxf(rm, s[i][j]);
      rm = fmaxf(rm, __shfl_xor(rm, 1));
      rm = fmaxf(rm, __shfl_xor(rm, 2));
      rm = fmaxf(rm, __shfl_xor(rm, 4));
      float mnew = fmaxf(mrun[i], rm);
      float alpha = expf(mrun[i] - mnew);
      float rs = 0.0f;
#pragma unroll
      for (int j = 0; j < 8; ++j) {
        float p = expf(s[i][j] - mnew);
        s[i][j] = p;
        rs += p;
      }
      rs += __shfl_xor(rs, 1);
      rs += __shfl_xor(rs, 2);
      rs += __shfl_xor(rs, 4);
      lrun[i] = lrun[i] * alpha + rs;
      mrun[i] = mnew;
#pragma unroll
      for (int j = 0; j < 8; ++j) o[i][j] *= alpha;
    }

#pragma unroll 4
    for (int c = 0; c < 64; ++c) {
      const int srcl = (ly << 3) | (c >> 3);
      float pb[4];
      pb[0] = __shfl(s[0][c & 7], srcl);
      pb[1] = __shfl(s[1][c & 7], srcl);
      pb[2] = __shfl(s[2][c & 7], srcl);
      pb[3] = __shfl(s[3][c & 7], srcl);
      int sw = SW(c);
      float vv[8];
      *(float4*)&vv[0] = *(const float4*)&Vs[c][(8 * lx) ^ sw];
      *(float4*)&vv[4] = *(const float4*)&Vs[c][(8 * lx + 4) ^ sw];
#pragma unroll
      for (int i = 0; i < 4; ++i)
#pragma unroll
        for (int j = 0; j < 8; ++j) o[i][j] = fmaf(pb[i], vv[j], o[i][j]);
    }
  }

  const size_t baseO = ((size_t)(b * T_SEQ + qbase)) * DMODEL + hh * 64;
#pragma unroll
  for (int i = 0; i < 4; ++i) {
    float inv = 1.0f / lrun[i];
    int r = 4 * ly + i;
    u16 vh[8], vm[8], vl[8];
#pragma unroll
    for (int j = 0; j < 8; ++j) split3(o[i][j] * inv, vh[j], vm[j], vl[j]);
    size_t ob = baseO + (size_t)r * DMODEL + 8 * lx;
    *(ushort4*)&Oh[ob] = make_ushort4(vh[0], vh[1], vh[2], vh[3]);
    *(ushort4*)&Oh[ob + 4] = make_ushort4(vh[4], vh[5], vh[6], vh[7]);
    *(ushort4*)&Om[ob] = make_ushort4(vm[0], vm[1], vm[2], vm[3]);
    *(ushort4*)&Om[ob + 4] = make_ushort4(vm[4], vm[5], vm[6], vm[7]);
    *(ushort4*)&Ol[ob] = make_ushort4(vl[0], vl[1], vl[2], vl[3]);
    *(ushort4*)&Ol[ob + 4] = make_ushort4(vl[4], vl[5], vl[6], vl[7]);
  }
}

// ---------------- row kernels ----------------
DEV float wave_sum(float v) {
#pragma unroll
  for (int off = 1; off < 64; off <<= 1) v += __shfl_xor(v, off);
  return v;
}

DEV void store8_split3(u16* H, u16* M, u16* L, size_t base, const float* t) {
  u16 vh[8], vm[8], vl[8];
#pragma unroll
  for (int j = 0; j < 8; ++j) split3(t[j], vh[j], vm[j], vl[j]);
  *(ushort4*)&H[base] = make_ushort4(vh[0], vh[1], vh[2], vh[3]);
  *(ushort4*)&H[base + 4] = make_ushort4(vh[4], vh[5], vh[6], vh[7]);
  *(ushort4*)&M[base] = make_ushort4(vm[0], vm[1], vm[2], vm[3]);
  *(ushort4*)&M[base + 4] = make_ushort4(vm[4], vm[5], vm[6], vm[7]);
  *(ushort4*)&L[base] = make_ushort4(vl[0], vl[1], vl[2], vl[3]);
  *(ushort4*)&L[base + 4] = make_ushort4(vl[4], vl[5], vl[6], vl[7]);
}

// LN over D=512 -> 3 bf16 planes
__global__ __launch_bounds__(256) void ln_split3(const float* __restrict__ x,
                                                 const float* __restrict__ g,
                                                 const float* __restrict__ b,
                                                 u16* __restrict__ yh,
                                                 u16* __restrict__ ym,
                                                 u16* __restrict__ yl) {
  const int row = blockIdx.x * 4 + (threadIdx.x >> 6);
  const int lane = threadIdx.x & 63;
  const float* xr = x + (size_t)row * DMODEL;
  float v[8];
  *(float4*)&v[0] = *(const float4*)(xr + lane * 8);
  *(float4*)&v[4] = *(const float4*)(xr + lane * 8 + 4);
  float s = 0.0f;
#pragma unroll
  for (int j = 0; j < 8; ++j) s += v[j];
  s = wave_sum(s);
  float mean = s * (1.0f / 512.0f);
  float s2 = 0.0f;
#pragma unroll
  for (int j = 0; j < 8; ++j) {
    float d = v[j] - mean;
    s2 += d * d;
  }
  s2 = wave_sum(s2);
  float rstd = 1.0f / sqrtf(s2 * (1.0f / 512.0f) + 1e-5f);
  float gg[8], bv[8];
  *(float4*)&gg[0] = *(const float4*)(g + lane * 8);
  *(float4*)&gg[4] = *(const float4*)(g + lane * 8 + 4);
  *(float4*)&bv[0] = *(const float4*)(b + lane * 8);
  *(float4*)&bv[4] = *(const float4*)(b + lane * 8 + 4);
  float t[8];
#pragma unroll
  for (int j = 0; j < 8; ++j) t[j] = (v[j] - mean) * rstd * gg[j] + bv[j];
  store8_split3(yh, ym, yl, (size_t)row * DMODEL + lane * 8, t);
}

// LN + l2norm, fp32 in/out (VQ head)
__global__ __launch_bounds__(256) void ln_l2_f32(const float* __restrict__ x,
                                                 const float* __restrict__ g,
                                                 const float* __restrict__ b,
                                                 float* __restrict__ y) {
  const int row = blockIdx.x * 4 + (threadIdx.x >> 6);
  const int lane = threadIdx.x & 63;
  const float* xr = x + (size_t)row * DMODEL;
  float v[8];
  *(float4*)&v[0] = *(const float4*)(xr + lane * 8);
  *(float4*)&v[4] = *(const float4*)(xr + lane * 8 + 4);
  float s = 0.0f;
#pragma unroll
  for (int j = 0; j < 8; ++j) s += v[j];
  s = wave_sum(s);
  float mean = s * (1.0f / 512.0f);
  float s2 = 0.0f;
#pragma unroll
  for (int j = 0; j < 8; ++j) {
    float d = v[j] - mean;
    s2 += d * d;
  }
  s2 = wave_sum(s2);
  float rstd = 1.0f / sqrtf(s2 * (1.0f / 512.0f) + 1e-5f);
  float gg[8], bv[8];
  *(float4*)&gg[0] = *(const float4*)(g + lane * 8);
  *(float4*)&gg[4] = *(const float4*)(g + lane * 8 + 4);
  *(float4*)&bv[0] = *(const float4*)(b + lane * 8);
  *(float4*)&bv[4] = *(const float4*)(b + lane * 8 + 4);
  float t[8];
#pragma unroll
  for (int j = 0; j < 8; ++j) t[j] = (v[j] - mean) * rstd * gg[j] + bv[j];
  float n2 = 0.0f;
#pragma unroll
  for (int j = 0; j < 8; ++j) n2 += t[j] * t[j];
  n2 = wave_sum(n2);
  float den = fmaxf(sqrtf(n2), 1e-12f);
#pragma unroll
  for (int j = 0; j < 8; ++j) t[j] /= den;
  float* yr = y + (size_t)row * DMODEL;
  *(float4*)(yr + lane * 8) = *(float4*)&t[0];
  *(float4*)(yr + lane * 8 + 4) = *(float4*)&t[4];
}

// l2norm rows (D=512) -> 3 bf16 planes
__global__ __launch_bounds__(256) void l2_split3(const float* __restrict__ x,
                                                 u16* __restrict__ yh,
                                                 u16* __restrict__ ym,
                                                 u16* __restrict__ yl) {
  const int row = blockIdx.x * 4 + (threadIdx.x >> 6);
  const int lane = threadIdx.x & 63;
  const float* xr = x + (size_t)row * DMODEL;
  float v[8];
  *(float4*)&v[0] = *(const float4*)(xr + lane * 8);
  *(float4*)&v[4] = *(const float4*)(xr + lane * 8 + 4);
  float n2 = 0.0f;
#pragma unroll
  for (int j = 0; j < 8; ++j) n2 += v[j] * v[j];
  n2 = wave_sum(n2);
  float den = fmaxf(sqrtf(n2), 1e-12f);
#pragma unroll
  for (int j = 0; j < 8; ++j) v[j] /= den;
  store8_split3(yh, ym, yl, (size_t)row * DMODEL + lane * 8, v);
}

// l2norm rows fp32 out (patterns)
__global__ __launch_bounds__(256) void l2_f32(const float* __restrict__ x,
                                              float* __restrict__ y) {
  const int row = blockIdx.x * 4 + (threadIdx.x >> 6);
  const int lane = threadIdx.x & 63;
  const float* xr = x + (size_t)row * DMODEL;
  float v[8];
  *(float4*)&v[0] = *(const float4*)(xr + lane * 8);
  *(float4*)&v[4] = *(const float4*)(xr + lane * 8 + 4);
  float n2 = 0.0f;
#pragma unroll
  for (int j = 0; j < 8; ++j) n2 += v[j] * v[j];
  n2 = wave_sum(n2);
  float den = fmaxf(sqrtf(n2), 1e-12f);
#pragma unroll
  for (int j = 0; j < 8; ++j) v[j] /= den;
  float* yr = y + (size_t)row * DMODEL;
  *(float4*)(yr + lane * 8) = *(float4*)&v[0];
  *(float4*)(yr + lane * 8 + 4) = *(float4*)&v[4];
}

// softmax over rows of 1024, in-place on 3 bf16 planes
__global__ __launch_bounds__(256) void softmax3(u16* __restrict__ H,
                                                u16* __restrict__ M,
                                                u16* __restrict__ L) {
  const int row = blockIdx.x;
  const int tid = threadIdx.x;
  const size_t base = (size_t)row * 1024 + tid * 4;
  ushort4 qh = *(const ushort4*)&H[base];
  ushort4 qm = *(const ushort4*)&M[base];
  ushort4 ql = *(const ushort4*)&L[base];
  float v0 = bf2f(qh.x) + bf2f(qm.x) + bf2f(ql.x);
  float v1 = bf2f(qh.y) + bf2f(qm.y) + bf2f(ql.y);
  float v2 = bf2f(qh.z) + bf2f(qm.z) + bf2f(ql.z);
  float v3 = bf2f(qh.w) + bf2f(qm.w) + bf2f(ql.w);
  float mx = fmaxf(fmaxf(v0, v1), fmaxf(v2, v3));
#pragma unroll
  for (int off = 1; off < 64; off <<= 1) mx = fmaxf(mx, __shfl_xor(mx, off));
  __shared__ float red[4];
  const int wv = tid >> 6;
  if ((tid & 63) == 0) red[wv] = mx;
  __syncthreads();
  mx = fmaxf(fmaxf(red[0], red[1]), fmaxf(red[2], red[3]));
  float e0 = expf(v0 - mx), e1 = expf(v1 - mx), e2 = expf(v2 - mx),
        e3 = expf(v3 - mx);
  float s = e0 + e1 + e2 + e3;
#pragma unroll
  for (int off = 1; off < 64; off <<= 1) s += __shfl_xor(s, off);
  __syncthreads();
  if ((tid & 63) == 0) red[wv] = s;
  __syncthreads();
  s = red[0] + red[1] + red[2] + red[3];
  float inv = 1.0f / s;
  u16 ah[4], am[4], al[4];
  split3(e0 * inv, ah[0], am[0], al[0]);
  split3(e1 * inv, ah[1], am[1], al[1]);
  split3(e2 * inv, ah[2], am[2], al[2]);
  split3(e3 * inv, ah[3], am[3], al[3]);
  *(ushort4*)&H[base] = make_ushort4(ah[0], ah[1], ah[2], ah[3]);
  *(ushort4*)&M[base] = make_ushort4(am[0], am[1], am[2], am[3]);
  *(ushort4*)&L[base] = make_ushort4(al[0], al[1], al[2], al[3]);
}

// generic fp32 -> 3 bf16 planes splitter (n4 = n/4)
__global__ __launch_bounds__(256) void split3_k(const float* __restrict__ src,
                                                u16* __restrict__ H,
                                                u16* __restrict__ M,
                                                u16* __restrict__ L, int n4) {
  for (int e = blockIdx.x * 256 + threadIdx.x; e < n4;
       e += gridDim.x * 256) {
    float4 v = *(const float4*)(src + (size_t)e * 4);
    u16 ah[4], am[4], al[4];
    split3(v.x, ah[0], am[0], al[0]);
    split3(v.y, ah[1], am[1], al[1]);
    split3(v.z, ah[2], am[2], al[2]);
    split3(v.w, ah[3], am[3], al[3]);
    *(ushort4*)&H[(size_t)e * 4] = make_ushort4(ah[0], ah[1], ah[2], ah[3]);
    *(ushort4*)&M[(size_t)e * 4] = make_ushort4(am[0], am[1], am[2], am[3]);
    *(ushort4*)&L[(size_t)e * 4] = make_ushort4(al[0], al[1], al[2], al[3]);
  }
}

// transpose codebook [1024][512] -> cbT [512][1024], split into 3 planes
__global__ __launch_bounds__(256) void tsplit_cb(const float* __restrict__ cb,
                                                 u16* __restrict__ th,
                                                 u16* __restrict__ tm,
                                                 u16* __restrict__ tl) {
  const int c = blockIdx.x;   // 0..511
  const int t = threadIdx.x;  // 0..255, rows 4t..4t+3
  u16 ah[4], am[4], al[4];
#pragma unroll
  for (int j = 0; j < 4; ++j) {
    float v = cb[(size_t)(4 * t + j) * 512 + c];
    split3(v, ah[j], am[j], al[j]);
  }
  const size_t base = (size_t)c * 1024 + 4 * t;
  *(ushort4*)&th[base] = make_ushort4(ah[0], ah[1], ah[2], ah[3]);
  *(ushort4*)&tm[base] = make_ushort4(am[0], am[1], am[2], am[3]);
  *(ushort4*)&tl[base] = make_ushort4(al[0], al[1], al[2], al[3]);
}

// argmax + one_hot + gather
__global__ __launch_bounds__(256) void vq_finalize(
    const float* __restrict__ logits, const float* __restrict__ patterns,
    float* __restrict__ emb, float* __restrict__ assign,
    float* __restrict__ idxf) {
  const int row = blockIdx.x * 4 + (threadIdx.x >> 6);
  const int lane = threadIdx.x & 63;
  const float* lr = logits + (size_t)row * NPAT;
  float best = -__builtin_huge_valf();
  int bi = 0;
#pragma unroll
  for (int jj = 0; jj < 8; ++jj) {
    int j = lane + jj * 64;
    float v = lr[j];
    if (v > best) {
      best = v;
      bi = j;
    }
  }
#pragma unroll
  for (int off = 1; off < 64; off <<= 1) {
    float ob = __shfl_xor(best, off);
    int oi = __shfl_xor(bi, off);
    if (ob > best || (ob == best && oi < bi)) {
      best = ob;
      bi = oi;
    }
  }
  const float* pr = patterns + (size_t)bi * DMODEL;
#pragma unroll
  for (int g = 0; g < 2; ++g) {
    int c = lane * 8 + g * 4;
    float4 pv = *(const float4*)(pr + c);
    *(float4*)(emb + (size_t)row * DMODEL + c) = pv;
    float4 av;
    av.x = (c + 0 == bi) ? 1.0f : 0.0f;
    av.y = (c + 1 == bi) ? 1.0f : 0.0f;
    av.z = (c + 2 == bi) ? 1.0f : 0.0f;
    av.w = (c + 3 == bi) ? 1.0f : 0.0f;
    *(float4*)(assign + (size_t)row * NPAT + c) = av;
  }
  if (lane == 0) idxf[row] = (float)bi;
}

// ---------------- host launch ----------------
extern "C" void kernel_launch(void* const* d_in, const int* in_sizes, int n_in,
                              void* d_out, int out_size, void* d_ws,
                              size_t ws_size, hipStream_t stream) {
  (void)in_sizes;
  (void)n_in;
  (void)out_size;
  (void)ws_size;
  const float* x = (const float*)d_in[0];
  const float* gumbel = (const float*)d_in[1];
  const float* sym_w = (const float*)d_in[2];
  const float* sym_b = (const float*)d_in[3];
  const float* codebook = (const float*)d_in[4];
  const float* pos_enc = (const float*)d_in[5];
  const float* attn_in_w = (const float*)d_in[6];
  const float* attn_in_b = (const float*)d_in[7];
  const float* attn_out_w = (const float*)d_in[8];
  const float* attn_out_b = (const float*)d_in[9];
  const float* n1_g = (const float*)d_in[10];
  const float* n1_b = (const float*)d_in[11];
  const float* n2_g = (const float*)d_in[12];
  const float* n2_b = (const float*)d_in[13];
  const float* ffn_w1 = (const float*)d_in[14];
  const float* ffn_b1 = (const float*)d_in[15];
  const float* ffn_w2 = (const float*)d_in[16];
  const float* ffn_b2 = (const float*)d_in[17];
  const float* q_w = (const float*)d_in[18];
  const float* q_b = (const float*)d_in[19];
  const float* qln_g = (const float*)d_in[20];
  const float* qln_b = (const float*)d_in[21];
  const float* patterns = (const float*)d_in[22];
  const int* epoch = (const int*)d_in[23];
  const int* tot = (const int*)d_in[24];

  float* out = (float*)d_out;
  float* emb = out;               // [8192,512]
  float* assign = out + 4194304;  // [8192,512]
  float* logits = out + 8388608;  // [8192,512]
  float* h = out + 12582912;      // [8192,512]
  float* idxf = out + 16777216;   // [8192]

  float* ws_f = (float*)d_ws;
  // R1 @0 (12.58M floats): x/soft/mid planes OR qkv fp32
  u16* r1u = (u16*)ws_f;
  float* r1f = ws_f;
  u16 *pH = r1u, *pM = r1u + 8388608, *pL = r1u + 16777216;
  // HA @12.58M (6.29M floats): hp_n / hn / attn planes (time-shared)
  u16* haU = (u16*)(ws_f + 12582912);
  u16 *hnH = haU, *hnM = haU + 4194304, *hnL = haU + 8388608;
  // R3 @18.87M (4.19M floats): hp / q fp32
  float* r3f = ws_f + 18874368;
  // CB @23.07M: cbn planes + cbT planes
  u16* cbU = (u16*)(ws_f + 23068672);
  u16 *cbnH = cbU, *cbnM = cbU + 524288, *cbnL = cbU + 1048576;
  u16 *cbTH = cbU + 1572864, *cbTM = cbU + 2097152, *cbTL = cbU + 2621440;
  // PATN @24.64M
  float* patn = ws_f + 24641536;
  // WBUF @24.90M (two slots of 1.57M floats each)
  u16* wU1 = (u16*)(ws_f + 24903680);
  u16* wU2 = (u16*)(ws_f + 26476544);

  // ---- symbolization ----
  split3_k<<<2048, 256, 0, stream>>>(x, pH, pM, pL, 2097152);
  split3_k<<<512, 256, 0, stream>>>(sym_w, wU1, wU1 + 524288, wU1 + 1048576,
                                    131072);
  gemm_mf<64, E_BIAS><<<dim3(4, 128), 256, 0, stream>>>(
      pH, pM, pL, wU1, wU1 + 524288, wU1 + 1048576, sym_b, nullptr, r3f,
      nullptr, nullptr, nullptr, 512, 1024, 1024, 1024);
  l2_split3<<<256, 256, 0, stream>>>(codebook, cbnH, cbnM, cbnL);
  l2_split3<<<2048, 256, 0, stream>>>(r3f, hnH, hnM, hnL);
  gemm_mf<64, E_GUM3><<<dim3(8, 128), 256, 0, stream>>>(
      hnH, hnM, hnL, cbnH, cbnM, cbnL, nullptr, gumbel, nullptr, pH, pM, pL,
      1024, 512, 512, 512);
  softmax3<<<8192, 256, 0, stream>>>(pH, pM, pL);
  tsplit_cb<<<512, 256, 0, stream>>>(codebook, cbTH, cbTM, cbTL);
  gemm_mf<64, E_POS><<<dim3(4, 128), 256, 0, stream>>>(
      pH, pM, pL, cbTH, cbTM, cbTL, nullptr, pos_enc, h, nullptr, nullptr,
      nullptr, 512, 1024, 1024, 1024);

  // ---- transformer layers ----
  for (int l = 0; l < 4; ++l) {
    const float* inw = attn_in_w + (size_t)l * 1536 * 512;
    const float* inb = attn_in_b + (size_t)l * 1536;
    const float* outw = attn_out_w + (size_t)l * 512 * 512;
    const float* outb = attn_out_b + (size_t)l * 512;
    const float* w1 = ffn_w1 + (size_t)l * 2048 * 512;
    const float* b1 = ffn_b1 + (size_t)l * 2048;
    const float* w2 = ffn_w2 + (size_t)l * 512 * 2048;
    const float* b2 = ffn_b2 + (size_t)l * 512;

    ln_split3<<<2048, 256, 0, stream>>>(h, n1_g + l * 512, n1_b + l * 512,
                                        hnH, hnM, hnL);
    split3_k<<<1024, 256, 0, stream>>>(inw, wU1, wU1 + 786432, wU1 + 1572864,
                                       196608);
    gemm_mf<128, E_BIAS><<<dim3(12, 64), 256, 0, stream>>>(
        hnH, hnM, hnL, wU1, wU1 + 786432, wU1 + 1572864, inb, nullptr, r1f,
        nullptr, nullptr, nullptr, 1536, 512, 512, 512);
    flash_attn2<<<dim3(8, 64), 256, 0, stream>>>(r1f, hnH, hnM, hnL);
    split3_k<<<256, 256, 0, stream>>>(outw, wU1, wU1 + 262144, wU1 + 524288,
                                      65536);
    gemm_mf<64, E_RES><<<dim3(4, 128), 256, 0, stream>>>(
        hnH, hnM, hnL, wU1, wU1 + 262144, wU1 + 524288, outb, h, h, nullptr,
        nullptr, nullptr, 512, 512, 512, 512);
    ln_split3<<<2048, 256, 0, stream>>>(h, n2_g + l * 512, n2_b + l * 512,
                                        hnH, hnM, hnL);
    split3_k<<<1024, 256, 0, stream>>>(w1, wU1, wU1 + 1048576, wU1 + 2097152,
                                       262144);
    split3_k<<<1024, 256, 0, stream>>>(w2, wU2, wU2 + 1048576, wU2 + 2097152,
                                       262144);
    // FFN in two N/K chunks so mid planes fit R1
    for (int c = 0; c < 2; ++c) {
      gemm_mf<128, E_GELU3><<<dim3(8, 64), 256, 0, stream>>>(
          hnH, hnM, hnL, wU1 + c * 524288, wU1 + 1048576 + c * 524288,
          wU1 + 2097152 + c * 524288, b1 + c * 1024, nullptr, nullptr, pH, pM,
          pL, 1024, 512, 512, 512);
      if (c == 0) {
        gemm_mf<64, E_RES><<<dim3(4, 128), 256, 0, stream>>>(
            pH, pM, pL, wU2 + 0, wU2 + 1048576, wU2 + 2097152, b2, h, h,
            nullptr, nullptr, nullptr, 512, 1024, 1024, 2048);
      } else {
        gemm_mf<64, E_ACC><<<dim3(4, 128), 256, 0, stream>>>(
            pH, pM, pL, wU2 + 1024, wU2 + 1048576 + 1024, wU2 + 2097152 + 1024,
            nullptr, nullptr, h, nullptr, nullptr, nullptr, 512, 1024, 1024,
            2048);
      }
    }
  }

  // ---- VQ head (fp32-vector precision anchor) ----
  gemm_f32<64, 128, 32, E_BIAS><<<dim3(4, 128), 256, 0, stream>>>(
      h, q_w, q_b, r3f, 8192, 512, 512, nullptr, nullptr);
  ln_l2_f32<<<2048, 256, 0, stream>>>(r3f, qln_g, qln_b, r3f);
  l2_f32<<<128, 256, 0, stream>>>(patterns, patn);
  gemm_f32<64, 128, 32, E_VQ><<<dim3(4, 128), 256, 0, stream>>>(
      r3f, patn, nullptr, logits, 8192, 512, 512, epoch, tot);
  vq_finalize<<<2048, 256, 0, stream>>>(logits, patterns, emb, assign, idxf);
}

// Round 7
// 2919.753 us; speedup vs baseline: 10.6745x; 1.1085x over previous
//
#include <hip/hip_runtime.h>

#define DEV __device__ __forceinline__

typedef unsigned short u16;
typedef unsigned int u32;
typedef __attribute__((ext_vector_type(8))) short bf8_t;   // 8 bf16 (4 VGPR)
typedef __attribute__((ext_vector_type(4))) float f4_t;

constexpr int T_SEQ = 1024;
constexpr int DMODEL = 512;
constexpr int NPAT = 512;

// ---------------- epilogue modes ----------------
enum {
  E_BIAS = 0,
  E_VQ = 5,
  E_RES = 6,
  E_ACC = 7,
  E_POS = 8,
  E_GUM3 = 9,
  E_GELU3 = 10,
  E_QKV3 = 11
};

// ---------------- bf16 triple-split helpers ----------------
DEV u16 f2bf(float x) {
  u32 u = __float_as_uint(x);
  u32 r = u + 0x7FFFu + ((u >> 16) & 1u);
  return (u16)(r >> 16);
}
DEV float bf2f(u16 h) { return __uint_as_float((u32)h << 16); }
DEV void split3(float x, u16& h, u16& m, u16& l) {
  h = f2bf(x);
  float r1 = x - bf2f(h);
  m = f2bf(r1);
  float r2 = r1 - bf2f(m);
  l = f2bf(r2);
}

DEV f4_t mf16(bf8_t a, bf8_t b, f4_t c) {
  return __builtin_amdgcn_mfma_f32_16x16x32_bf16(a, b, c, 0, 0, 0);
}
// 6-product triple-split accumulate (err ~2^-24)
DEV f4_t prod6(bf8_t ah, bf8_t am, bf8_t al, bf8_t bh, bf8_t bm, bf8_t bl,
               f4_t c) {
  c = mf16(ah, bh, c);
  c = mf16(ah, bm, c);
  c = mf16(am, bh, c);
  c = mf16(ah, bl, c);
  c = mf16(am, bm, c);
  c = mf16(al, bh, c);
  return c;
}

// ---------------- MFMA GEMM, triple-bf16 split (fp32-accurate) ---------------
// C[M,N] = A[M,K]*B[N,K]^T via 6 bf16 products. Verified R6.
template <int BM, int EPI>
__global__ __launch_bounds__(256, 2) void gemm_mf(
    const u16* __restrict__ Ah, const u16* __restrict__ Am,
    const u16* __restrict__ Al, const u16* __restrict__ Bh,
    const u16* __restrict__ Bm, const u16* __restrict__ Bl,
    const float* __restrict__ bias, const float* __restrict__ res,
    float* __restrict__ Cf, u16* __restrict__ Ch, u16* __restrict__ Cm,
    u16* __restrict__ Cl, int N, int KK, int lda, int ldb) {
  constexpr int MT = BM / 32;  // m-tiles per wave
  __shared__ __align__(16) u16 AsH[BM][4][8], AsM[BM][4][8], AsL[BM][4][8];
  __shared__ __align__(16) u16 BsH[128][4][8], BsM[128][4][8], BsL[128][4][8];
  const int tid = threadIdx.x;
  const int w = tid >> 6, lane = tid & 63;
  const int wy = w >> 1, wx = w & 1;
  const int lr = lane & 15, lg = lane >> 4;
  const int bm = blockIdx.y * BM, bn = blockIdx.x * 128;

  f4_t acc[MT][4];
#pragma unroll
  for (int mt = 0; mt < MT; ++mt)
#pragma unroll
    for (int nt = 0; nt < 4; ++nt) acc[mt][nt] = (f4_t){0.f, 0.f, 0.f, 0.f};

  for (int k0 = 0; k0 < KK; k0 += 32) {
    if (k0) __syncthreads();
#pragma unroll
    for (int u = 0; u < BM / 64; ++u) {
      int p = tid + u * 256;
      int row = p >> 2, kp = p & 3;
      int slot = kp ^ ((row >> 1) & 3);
      size_t g = (size_t)(bm + row) * lda + k0 + kp * 8;
      *(uint4*)&AsH[row][slot][0] = *(const uint4*)&Ah[g];
      *(uint4*)&AsM[row][slot][0] = *(const uint4*)&Am[g];
      *(uint4*)&AsL[row][slot][0] = *(const uint4*)&Al[g];
    }
#pragma unroll
    for (int u = 0; u < 2; ++u) {
      int p = tid + u * 256;
      int col = p >> 2, kp = p & 3;
      int slot = kp ^ ((col >> 1) & 3);
      size_t g = (size_t)(bn + col) * ldb + k0 + kp * 8;
      *(uint4*)&BsH[col][slot][0] = *(const uint4*)&Bh[g];
      *(uint4*)&BsM[col][slot][0] = *(const uint4*)&Bm[g];
      *(uint4*)&BsL[col][slot][0] = *(const uint4*)&Bl[g];
    }
    __syncthreads();

    bf8_t fah[MT], fam[MT], fal[MT], fbh[4], fbm[4], fbl[4];
#pragma unroll
    for (int mt = 0; mt < MT; ++mt) {
      int row = wy * (BM / 2) + mt * 16 + lr;
      int slot = lg ^ ((row >> 1) & 3);
      fah[mt] = *(const bf8_t*)&AsH[row][slot][0];
      fam[mt] = *(const bf8_t*)&AsM[row][slot][0];
      fal[mt] = *(const bf8_t*)&AsL[row][slot][0];
    }
#pragma unroll
    for (int nt = 0; nt < 4; ++nt) {
      int col = wx * 64 + nt * 16 + lr;
      int slot = lg ^ ((col >> 1) & 3);
      fbh[nt] = *(const bf8_t*)&BsH[col][slot][0];
      fbm[nt] = *(const bf8_t*)&BsM[col][slot][0];
      fbl[nt] = *(const bf8_t*)&BsL[col][slot][0];
    }
#pragma unroll
    for (int mt = 0; mt < MT; ++mt)
#pragma unroll
      for (int nt = 0; nt < 4; ++nt)
        acc[mt][nt] = prod6(fah[mt], fam[mt], fal[mt], fbh[nt], fbm[nt],
                            fbl[nt], acc[mt][nt]);
  }

  // ---- epilogue (C frag: col = lane&15, row = 4*(lane>>4)+i) ----
  float bv[4];
  if constexpr (EPI == E_BIAS || EPI == E_RES || EPI == E_GELU3 ||
                EPI == E_QKV3) {
#pragma unroll
    for (int nt = 0; nt < 4; ++nt) bv[nt] = bias[bn + wx * 64 + nt * 16 + lr];
  }
#pragma unroll
  for (int mt = 0; mt < MT; ++mt)
#pragma unroll
    for (int nt = 0; nt < 4; ++nt) {
      const int c = bn + wx * 64 + nt * 16 + lr;
#pragma unroll
      for (int i = 0; i < 4; ++i) {
        const int m = bm + wy * (BM / 2) + mt * 16 + 4 * lg + i;
        const size_t idx = (size_t)m * N + c;
        float v = acc[mt][nt][i];
        if constexpr (EPI == E_BIAS) {
          Cf[idx] = v + bv[nt];
        } else if constexpr (EPI == E_RES) {
          Cf[idx] = v + bv[nt] + res[idx];
        } else if constexpr (EPI == E_ACC) {
          Cf[idx] += v;
        } else if constexpr (EPI == E_POS) {
          Cf[idx] = v + res[(size_t)(m & 1023) * N + c];
        } else if constexpr (EPI == E_GUM3) {
          float t = 4.0f * v + 2.0f * res[idx];
          u16 h2, m2, l2;
          split3(t, h2, m2, l2);
          Ch[idx] = h2;
          Cm[idx] = m2;
          Cl[idx] = l2;
        } else if constexpr (EPI == E_GELU3) {
          float t = v + bv[nt];
          float g = 0.5f * t * (1.0f + erff(t * 0.7071067811865476f));
          u16 h2, m2, l2;
          split3(g, h2, m2, l2);
          Ch[idx] = h2;
          Cm[idx] = m2;
          Cl[idx] = l2;
        } else if constexpr (EPI == E_QKV3) {
          float t = v + bv[nt];
          u16 h2, m2, l2;
          split3(t, h2, m2, l2);
          size_t o;
          if (c < 512) {
            o = (size_t)m * 512 + c;                       // Q [B,T,512]
          } else if (c < 1024) {
            o = 4194304 + (size_t)m * 512 + (c - 512);     // K [B,T,512]
          } else {
            int cc = c - 1024, hh2 = cc >> 6, dd = cc & 63;
            int bb2 = m >> 10, tt = m & 1023;
            o = 8388608 +
                (((size_t)(bb2 * 8 + hh2) * 64 + dd) << 10) + tt;  // Vt
          }
          Ch[o] = h2;
          Cm[o] = m2;
          Cl[o] = l2;
        }
      }
    }
}

// ---------------- MFMA flash attention (triple-split, fp32-grade) ------------
// grid (16, 64): qt 0..15 (64 q-rows/block), bh = b*8+hh. 4 waves, each owns
// 16 q-rows. K rows-major [B,T,512]; V pre-transposed [B,8,64,T].
__global__ __launch_bounds__(256) void flash_mfma(
    const u16* __restrict__ QKVh, const u16* __restrict__ QKVm,
    const u16* __restrict__ QKVl, u16* __restrict__ Oh, u16* __restrict__ Om,
    u16* __restrict__ Ol) {
  __shared__ __align__(16) u16 Ks[3][64][8][8];
  __shared__ __align__(16) u16 Vs[3][64][8][8];
  __shared__ __align__(16) u16 Ps[3][64][8][8];
  const int tid = threadIdx.x;
  const int w = tid >> 6, lane = tid & 63;
  const int lr = lane & 15, lg = lane >> 4;
  const int qt = blockIdx.x, bh = blockIdx.y;
  const int b = bh >> 3, hh = bh & 7;

  const u16* Qh = QKVh;
  const u16* Qm = QKVm;
  const u16* Ql = QKVl;
  const u16* Kh = QKVh + 4194304;
  const u16* Km = QKVm + 4194304;
  const u16* Kl = QKVl + 4194304;
  const u16* Vh = QKVh + 8388608;
  const u16* Vm = QKVm + 8388608;
  const u16* Vl = QKVl + 8388608;

  // Q fragments (A-op: m = lr, k-packet = lg), hoisted for all kt
  bf8_t qf[2][3];
  {
    size_t g =
        ((size_t)(b * 1024 + qt * 64 + w * 16 + lr)) * 512 + hh * 64 + lg * 8;
    qf[0][0] = *(const bf8_t*)&Qh[g];
    qf[0][1] = *(const bf8_t*)&Qm[g];
    qf[0][2] = *(const bf8_t*)&Ql[g];
    qf[1][0] = *(const bf8_t*)&Qh[g + 32];
    qf[1][1] = *(const bf8_t*)&Qm[g + 32];
    qf[1][2] = *(const bf8_t*)&Ql[g + 32];
  }

  f4_t oacc[4];
#pragma unroll
  for (int nt = 0; nt < 4; ++nt) oacc[nt] = (f4_t){0.f, 0.f, 0.f, 0.f};
  float mrun[4], lrun[4];
#pragma unroll
  for (int i = 0; i < 4; ++i) {
    mrun[i] = -__builtin_huge_valf();
    lrun[i] = 0.0f;
  }

  for (int kt = 0; kt < 16; ++kt) {
    __syncthreads();
    // ---- stage K tile [64 tok][64 d] and Vt tile [64 d][64 tok] ----
#pragma unroll
    for (int u = 0; u < 2; ++u) {
      int p = tid + u * 256;
      int row = p >> 3, kp = p & 7;
      int slot = kp ^ (row & 7);
      size_t gk =
          ((size_t)(b * 1024 + kt * 64 + row)) * 512 + hh * 64 + kp * 8;
      *(uint4*)&Ks[0][row][slot][0] = *(const uint4*)&Kh[gk];
      *(uint4*)&Ks[1][row][slot][0] = *(const uint4*)&Km[gk];
      *(uint4*)&Ks[2][row][slot][0] = *(const uint4*)&Kl[gk];
      size_t gv = ((size_t)((b * 8 + hh) * 64 + row)) * 1024 + kt * 64 + kp * 8;
      *(uint4*)&Vs[0][row][slot][0] = *(const uint4*)&Vh[gv];
      *(uint4*)&Vs[1][row][slot][0] = *(const uint4*)&Vm[gv];
      *(uint4*)&Vs[2][row][slot][0] = *(const uint4*)&Vl[gv];
    }
    __syncthreads();

    // ---- S = Q K^T : 4 n-tiles x 2 k-slices x 6 products ----
    f4_t s[4];
#pragma unroll
    for (int nt = 0; nt < 4; ++nt) {
      s[nt] = (f4_t){0.f, 0.f, 0.f, 0.f};
      const int col = nt * 16 + lr;
#pragma unroll
      for (int ks = 0; ks < 2; ++ks) {
        int slot = (ks * 4 + lg) ^ (col & 7);
        bf8_t kh = *(const bf8_t*)&Ks[0][col][slot][0];
        bf8_t km = *(const bf8_t*)&Ks[1][col][slot][0];
        bf8_t kl = *(const bf8_t*)&Ks[2][col][slot][0];
        s[nt] = prod6(qf[ks][0], qf[ks][1], qf[ks][2], kh, km, kl, s[nt]);
      }
    }

    // ---- online softmax (row = 4*lg+i; reduce over lr via shfl) ----
#pragma unroll
    for (int i = 0; i < 4; ++i) {
      float rm = -__builtin_huge_valf();
#pragma unroll
      for (int nt = 0; nt < 4; ++nt) {
        s[nt][i] *= 0.125f;
        rm = fmaxf(rm, s[nt][i]);
      }
      rm = fmaxf(rm, __shfl_xor(rm, 1));
      rm = fmaxf(rm, __shfl_xor(rm, 2));
      rm = fmaxf(rm, __shfl_xor(rm, 4));
      rm = fmaxf(rm, __shfl_xor(rm, 8));
      float mnew = fmaxf(mrun[i], rm);
      float alpha = expf(mrun[i] - mnew);
      float rs = 0.0f;
#pragma unroll
      for (int nt = 0; nt < 4; ++nt) {
        float p = expf(s[nt][i] - mnew);
        s[nt][i] = p;
        rs += p;
      }
      rs += __shfl_xor(rs, 1);
      rs += __shfl_xor(rs, 2);
      rs += __shfl_xor(rs, 4);
      rs += __shfl_xor(rs, 8);
      lrun[i] = lrun[i] * alpha + rs;
      mrun[i] = mnew;
#pragma unroll
      for (int nt = 0; nt < 4; ++nt) oacc[nt][i] *= alpha;
    }

    // ---- P -> wave-private LDS slice (3 planes, swizzled) ----
#pragma unroll
    for (int nt = 0; nt < 4; ++nt)
#pragma unroll
      for (int i = 0; i < 4; ++i) {
        int qrow = w * 16 + 4 * lg + i;
        int kv = nt * 16 + lr;
        int kp = kv >> 3, j = kv & 7;
        int slot = kp ^ (qrow & 7);
        u16 h2, m2, l2;
        split3(s[nt][i], h2, m2, l2);
        Ps[0][qrow][slot][j] = h2;
        Ps[1][qrow][slot][j] = m2;
        Ps[2][qrow][slot][j] = l2;
      }

    // ---- O += P V (A = own P rows, B = Vt cols) ----
    bf8_t pf[2][3];
#pragma unroll
    for (int ks = 0; ks < 2; ++ks) {
      int row = w * 16 + lr;
      int slot = (ks * 4 + lg) ^ (row & 7);
      pf[ks][0] = *(const bf8_t*)&Ps[0][row][slot][0];
      pf[ks][1] = *(const bf8_t*)&Ps[1][row][slot][0];
      pf[ks][2] = *(const bf8_t*)&Ps[2][row][slot][0];
    }
#pragma unroll
    for (int ntd = 0; ntd < 4; ++ntd) {
      const int col = ntd * 16 + lr;
#pragma unroll
      for (int ks = 0; ks < 2; ++ks) {
        int slot = (ks * 4 + lg) ^ (col & 7);
        bf8_t vh = *(const bf8_t*)&Vs[0][col][slot][0];
        bf8_t vm = *(const bf8_t*)&Vs[1][col][slot][0];
        bf8_t vl = *(const bf8_t*)&Vs[2][col][slot][0];
        oacc[ntd] =
            prod6(pf[ks][0], pf[ks][1], pf[ks][2], vh, vm, vl, oacc[ntd]);
      }
    }
  }

  // ---- epilogue: normalize, split3, store planes [B,T,512] ----
#pragma unroll
  for (int i = 0; i < 4; ++i) {
    float inv = 1.0f / lrun[i];
    int t = qt * 64 + w * 16 + 4 * lg + i;
#pragma unroll
    for (int ntd = 0; ntd < 4; ++ntd) {
      int d = hh * 64 + ntd * 16 + lr;
      size_t idx = ((size_t)(b * 1024 + t)) * 512 + d;
      u16 h2, m2, l2;
      split3(oacc[ntd][i] * inv, h2, m2, l2);
      Oh[idx] = h2;
      Om[idx] = m2;
      Ol[idx] = l2;
    }
  }
}

// ---------------- fp32 vector GEMM (VQ-head precision anchor) ----------------
template <int BM, int BN, int WR, int EPI>
__global__ __launch_bounds__((BM / WR) * (BN / 64) * 64) void gemm_f32(
    const float* __restrict__ A, const float* __restrict__ Bmat,
    const float* __restrict__ bias, float* __restrict__ C, int M, int N, int K,
    const int* __restrict__ ep, const int* __restrict__ tot) {
  constexpr int BK = 16;
  constexpr int WN = BN / 64;
  constexpr int NW = (BM / WR) * WN;
  constexpr int NT = NW * 64;
  constexpr int RM = WR / 8;
  __shared__ __align__(16) float As[BK][BM + 4];
  __shared__ __align__(16) float Bs[BK][BN + 4];
  const int tid = threadIdx.x;
  const int w = tid >> 6, lane = tid & 63;
  const int wy = w / WN, wx = w % WN;
  const int ly = lane >> 3, lx = lane & 7;
  const int bm = blockIdx.y * BM;
  const int bn = blockIdx.x * BN;
  const int rbase = wy * WR + ly * RM;

  float acc[RM][8];
#pragma unroll
  for (int i = 0; i < RM; ++i)
#pragma unroll
    for (int j = 0; j < 8; ++j) acc[i][j] = 0.0f;

  for (int k0 = 0; k0 < K; k0 += BK) {
#pragma unroll
    for (int i = 0; i < (BM * BK / 4) / NT; ++i) {
      int idx = tid + i * NT;
      int r = idx >> 2, c4 = (idx & 3) << 2;
      const float4 v = *(const float4*)(A + (size_t)(bm + r) * K + k0 + c4);
      As[c4 + 0][r] = v.x;
      As[c4 + 1][r] = v.y;
      As[c4 + 2][r] = v.z;
      As[c4 + 3][r] = v.w;
    }
#pragma unroll
    for (int i = 0; i < (BN * BK / 4) / NT; ++i) {
      int idx = tid + i * NT;
      int r = idx >> 2, c4 = (idx & 3) << 2;
      const float4 v = *(const float4*)(Bmat + (size_t)(bn + r) * K + k0 + c4);
      Bs[c4 + 0][r] = v.x;
      Bs[c4 + 1][r] = v.y;
      Bs[c4 + 2][r] = v.z;
      Bs[c4 + 3][r] = v.w;
    }
    __syncthreads();
#pragma unroll
    for (int k = 0; k < BK; ++k) {
      float a[RM], b[8];
#pragma unroll
      for (int r4 = 0; r4 < RM; r4 += 4)
        *(float4*)&a[r4] = *(const float4*)&As[k][rbase + r4];
      *(float4*)&b[0] = *(const float4*)&Bs[k][wx * 64 + lx * 8];
      *(float4*)&b[4] = *(const float4*)&Bs[k][wx * 64 + lx * 8 + 4];
#pragma unroll
      for (int i = 0; i < RM; ++i)
#pragma unroll
        for (int j = 0; j < 8; ++j) acc[i][j] = fmaf(a[i], b[j], acc[i][j]);
    }
    __syncthreads();
  }

  const int ncol = bn + wx * 64 + lx * 8;
  float bb[8];
  if constexpr (EPI == E_BIAS) {
    *(float4*)&bb[0] = *(const float4*)(bias + ncol);
    *(float4*)&bb[4] = *(const float4*)(bias + ncol + 4);
  }
  float invt = 1.0f;
  if constexpr (EPI == E_VQ) {
    float t = 1.0f - 0.5f * (float)ep[0] / (float)tot[0];
    invt = 1.0f / fmaxf(0.5f, t);
  }
#pragma unroll
  for (int i = 0; i < RM; ++i) {
    const int m = bm + rbase + i;
    float o[8];
#pragma unroll
    for (int j = 0; j < 8; ++j) o[j] = acc[i][j];
    if constexpr (EPI == E_BIAS) {
#pragma unroll
      for (int j = 0; j < 8; ++j) o[j] += bb[j];
    } else if constexpr (EPI == E_VQ) {
#pragma unroll
      for (int j = 0; j < 8; ++j) o[j] *= invt;
    }
    *(float4*)(C + (size_t)m * N + ncol) = *(float4*)&o[0];
    *(float4*)(C + (size_t)m * N + ncol + 4) = *(float4*)&o[4];
  }
}

// ---------------- row kernels ----------------
DEV float wave_sum(float v) {
#pragma unroll
  for (int off = 1; off < 64; off <<= 1) v += __shfl_xor(v, off);
  return v;
}

DEV void store8_split3(u16* H, u16* M, u16* L, size_t base, const float* t) {
  u16 vh[8], vm[8], vl[8];
#pragma unroll
  for (int j = 0; j < 8; ++j) split3(t[j], vh[j], vm[j], vl[j]);
  *(ushort4*)&H[base] = make_ushort4(vh[0], vh[1], vh[2], vh[3]);
  *(ushort4*)&H[base + 4] = make_ushort4(vh[4], vh[5], vh[6], vh[7]);
  *(ushort4*)&M[base] = make_ushort4(vm[0], vm[1], vm[2], vm[3]);
  *(ushort4*)&M[base + 4] = make_ushort4(vm[4], vm[5], vm[6], vm[7]);
  *(ushort4*)&L[base] = make_ushort4(vl[0], vl[1], vl[2], vl[3]);
  *(ushort4*)&L[base + 4] = make_ushort4(vl[4], vl[5], vl[6], vl[7]);
}

__global__ __launch_bounds__(256) void ln_split3(const float* __restrict__ x,
                                                 const float* __restrict__ g,
                                                 const float* __restrict__ b,
                                                 u16* __restrict__ yh,
                                                 u16* __restrict__ ym,
                                                 u16* __restrict__ yl) {
  const int row = blockIdx.x * 4 + (threadIdx.x >> 6);
  const int lane = threadIdx.x & 63;
  const float* xr = x + (size_t)row * DMODEL;
  float v[8];
  *(float4*)&v[0] = *(const float4*)(xr + lane * 8);
  *(float4*)&v[4] = *(const float4*)(xr + lane * 8 + 4);
  float s = 0.0f;
#pragma unroll
  for (int j = 0; j < 8; ++j) s += v[j];
  s = wave_sum(s);
  float mean = s * (1.0f / 512.0f);
  float s2 = 0.0f;
#pragma unroll
  for (int j = 0; j < 8; ++j) {
    float d = v[j] - mean;
    s2 += d * d;
  }
  s2 = wave_sum(s2);
  float rstd = 1.0f / sqrtf(s2 * (1.0f / 512.0f) + 1e-5f);
  float gg[8], bv[8];
  *(float4*)&gg[0] = *(const float4*)(g + lane * 8);
  *(float4*)&gg[4] = *(const float4*)(g + lane * 8 + 4);
  *(float4*)&bv[0] = *(const float4*)(b + lane * 8);
  *(float4*)&bv[4] = *(const float4*)(b + lane * 8 + 4);
  float t[8];
#pragma unroll
  for (int j = 0; j < 8; ++j) t[j] = (v[j] - mean) * rstd * gg[j] + bv[j];
  store8_split3(yh, ym, yl, (size_t)row * DMODEL + lane * 8, t);
}

__global__ __launch_bounds__(256) void ln_l2_f32(const float* __restrict__ x,
                                                 const float* __restrict__ g,
                                                 const float* __restrict__ b,
                                                 float* __restrict__ y) {
  const int row = blockIdx.x * 4 + (threadIdx.x >> 6);
  const int lane = threadIdx.x & 63;
  const float* xr = x + (size_t)row * DMODEL;
  float v[8];
  *(float4*)&v[0] = *(const float4*)(xr + lane * 8);
  *(float4*)&v[4] = *(const float4*)(xr + lane * 8 + 4);
  float s = 0.0f;
#pragma unroll
  for (int j = 0; j < 8; ++j) s += v[j];
  s = wave_sum(s);
  float mean = s * (1.0f / 512.0f);
  float s2 = 0.0f;
#pragma unroll
  for (int j = 0; j < 8; ++j) {
    float d = v[j] - mean;
    s2 += d * d;
  }
  s2 = wave_sum(s2);
  float rstd = 1.0f / sqrtf(s2 * (1.0f / 512.0f) + 1e-5f);
  float gg[8], bv[8];
  *(float4*)&gg[0] = *(const float4*)(g + lane * 8);
  *(float4*)&gg[4] = *(const float4*)(g + lane * 8 + 4);
  *(float4*)&bv[0] = *(const float4*)(b + lane * 8);
  *(float4*)&bv[4] = *(const float4*)(b + lane * 8 + 4);
  float t[8];
#pragma unroll
  for (int j = 0; j < 8; ++j) t[j] = (v[j] - mean) * rstd * gg[j] + bv[j];
  float n2 = 0.0f;
#pragma unroll
  for (int j = 0; j < 8; ++j) n2 += t[j] * t[j];
  n2 = wave_sum(n2);
  float den = fmaxf(sqrtf(n2), 1e-12f);
#pragma unroll
  for (int j = 0; j < 8; ++j) t[j] /= den;
  float* yr = y + (size_t)row * DMODEL;
  *(float4*)(yr + lane * 8) = *(float4*)&t[0];
  *(float4*)(yr + lane * 8 + 4) = *(float4*)&t[4];
}

__global__ __launch_bounds__(256) void l2_split3(const float* __restrict__ x,
                                                 u16* __restrict__ yh,
                                                 u16* __restrict__ ym,
                                                 u16* __restrict__ yl) {
  const int row = blockIdx.x * 4 + (threadIdx.x >> 6);
  const int lane = threadIdx.x & 63;
  const float* xr = x + (size_t)row * DMODEL;
  float v[8];
  *(float4*)&v[0] = *(const float4*)(xr + lane * 8);
  *(float4*)&v[4] = *(const float4*)(xr + lane * 8 + 4);
  float n2 = 0.0f;
#pragma unroll
  for (int j = 0; j < 8; ++j) n2 += v[j] * v[j];
  n2 = wave_sum(n2);
  float den = fmaxf(sqrtf(n2), 1e-12f);
#pragma unroll
  for (int j = 0; j < 8; ++j) v[j] /= den;
  store8_split3(yh, ym, yl, (size_t)row * DMODEL + lane * 8, v);
}

__global__ __launch_bounds__(256) void l2_f32(const float* __restrict__ x,
                                              float* __restrict__ y) {
  const int row = blockIdx.x * 4 + (threadIdx.x >> 6);
  const int lane = threadIdx.x & 63;
  const float* xr = x + (size_t)row * DMODEL;
  float v[8];
  *(float4*)&v[0] = *(const float4*)(xr + lane * 8);
  *(float4*)&v[4] = *(const float4*)(xr + lane * 8 + 4);
  float n2 = 0.0f;
#pragma unroll
  for (int j = 0; j < 8; ++j) n2 += v[j] * v[j];
  n2 = wave_sum(n2);
  float den = fmaxf(sqrtf(n2), 1e-12f);
#pragma unroll
  for (int j = 0; j < 8; ++j) v[j] /= den;
  float* yr = y + (size_t)row * DMODEL;
  *(float4*)(yr + lane * 8) = *(float4*)&v[0];
  *(float4*)(yr + lane * 8 + 4) = *(float4*)&v[4];
}

__global__ __launch_bounds__(256) void softmax3(u16* __restrict__ H,
                                                u16* __restrict__ M,
                                                u16* __restrict__ L) {
  const int row = blockIdx.x;
  const int tid = threadIdx.x;
  const size_t base = (size_t)row * 1024 + tid * 4;
  ushort4 qh = *(const ushort4*)&H[base];
  ushort4 qm = *(const ushort4*)&M[base];
  ushort4 ql = *(const ushort4*)&L[base];
  float v0 = bf2f(qh.x) + bf2f(qm.x) + bf2f(ql.x);
  float v1 = bf2f(qh.y) + bf2f(qm.y) + bf2f(ql.y);
  float v2 = bf2f(qh.z) + bf2f(qm.z) + bf2f(ql.z);
  float v3 = bf2f(qh.w) + bf2f(qm.w) + bf2f(ql.w);
  float mx = fmaxf(fmaxf(v0, v1), fmaxf(v2, v3));
#pragma unroll
  for (int off = 1; off < 64; off <<= 1) mx = fmaxf(mx, __shfl_xor(mx, off));
  __shared__ float red[4];
  const int wv = tid >> 6;
  if ((tid & 63) == 0) red[wv] = mx;
  __syncthreads();
  mx = fmaxf(fmaxf(red[0], red[1]), fmaxf(red[2], red[3]));
  float e0 = expf(v0 - mx), e1 = expf(v1 - mx), e2 = expf(v2 - mx),
        e3 = expf(v3 - mx);
  float s = e0 + e1 + e2 + e3;
#pragma unroll
  for (int off = 1; off < 64; off <<= 1) s += __shfl_xor(s, off);
  __syncthreads();
  if ((tid & 63) == 0) red[wv] = s;
  __syncthreads();
  s = red[0] + red[1] + red[2] + red[3];
  float inv = 1.0f / s;
  u16 ah[4], am[4], al[4];
  split3(e0 * inv, ah[0], am[0], al[0]);
  split3(e1 * inv, ah[1], am[1], al[1]);
  split3(e2 * inv, ah[2], am[2], al[2]);
  split3(e3 * inv, ah[3], am[3], al[3]);
  *(ushort4*)&H[base] = make_ushort4(ah[0], ah[1], ah[2], ah[3]);
  *(ushort4*)&M[base] = make_ushort4(am[0], am[1], am[2], am[3]);
  *(ushort4*)&L[base] = make_ushort4(al[0], al[1], al[2], al[3]);
}

__global__ __launch_bounds__(256) void split3_k(const float* __restrict__ src,
                                                u16* __restrict__ H,
                                                u16* __restrict__ M,
                                                u16* __restrict__ L, int n4) {
  for (int e = blockIdx.x * 256 + threadIdx.x; e < n4; e += gridDim.x * 256) {
    float4 v = *(const float4*)(src + (size_t)e * 4);
    u16 ah[4], am[4], al[4];
    split3(v.x, ah[0], am[0], al[0]);
    split3(v.y, ah[1], am[1], al[1]);
    split3(v.z, ah[2], am[2], al[2]);
    split3(v.w, ah[3], am[3], al[3]);
    *(ushort4*)&H[(size_t)e * 4] = make_ushort4(ah[0], ah[1], ah[2], ah[3]);
    *(ushort4*)&M[(size_t)e * 4] = make_ushort4(am[0], am[1], am[2], am[3]);
    *(ushort4*)&L[(size_t)e * 4] = make_ushort4(al[0], al[1], al[2], al[3]);
  }
}

__global__ __launch_bounds__(256) void tsplit_cb(const float* __restrict__ cb,
                                                 u16* __restrict__ th,
                                                 u16* __restrict__ tm,
                                                 u16* __restrict__ tl) {
  const int c = blockIdx.x;
  const int t = threadIdx.x;
  u16 ah[4], am[4], al[4];
#pragma unroll
  for (int j = 0; j < 4; ++j) {
    float v = cb[(size_t)(4 * t + j) * 512 + c];
    split3(v, ah[j], am[j], al[j]);
  }
  const size_t base = (size_t)c * 1024 + 4 * t;
  *(ushort4*)&th[base] = make_ushort4(ah[0], ah[1], ah[2], ah[3]);
  *(ushort4*)&tm[base] = make_ushort4(am[0], am[1], am[2], am[3]);
  *(ushort4*)&tl[base] = make_ushort4(al[0], al[1], al[2], al[3]);
}

__global__ __launch_bounds__(256) void vq_finalize(
    const float* __restrict__ logits, const float* __restrict__ patterns,
    float* __restrict__ emb, float* __restrict__ assign,
    float* __restrict__ idxf) {
  const int row = blockIdx.x * 4 + (threadIdx.x >> 6);
  const int lane = threadIdx.x & 63;
  const float* lr = logits + (size_t)row * NPAT;
  float best = -__builtin_huge_valf();
  int bi = 0;
#pragma unroll
  for (int jj = 0; jj < 8; ++jj) {
    int j = lane + jj * 64;
    float v = lr[j];
    if (v > best) {
      best = v;
      bi = j;
    }
  }
#pragma unroll
  for (int off = 1; off < 64; off <<= 1) {
    float ob = __shfl_xor(best, off);
    int oi = __shfl_xor(bi, off);
    if (ob > best || (ob == best && oi < bi)) {
      best = ob;
      bi = oi;
    }
  }
  const float* pr = patterns + (size_t)bi * DMODEL;
#pragma unroll
  for (int g = 0; g < 2; ++g) {
    int c = lane * 8 + g * 4;
    float4 pv = *(const float4*)(pr + c);
    *(float4*)(emb + (size_t)row * DMODEL + c) = pv;
    float4 av;
    av.x = (c + 0 == bi) ? 1.0f : 0.0f;
    av.y = (c + 1 == bi) ? 1.0f : 0.0f;
    av.z = (c + 2 == bi) ? 1.0f : 0.0f;
    av.w = (c + 3 == bi) ? 1.0f : 0.0f;
    *(float4*)(assign + (size_t)row * NPAT + c) = av;
  }
  if (lane == 0) idxf[row] = (float)bi;
}

// ---------------- host launch ----------------
extern "C" void kernel_launch(void* const* d_in, const int* in_sizes, int n_in,
                              void* d_out, int out_size, void* d_ws,
                              size_t ws_size, hipStream_t stream) {
  (void)in_sizes;
  (void)n_in;
  (void)out_size;
  (void)ws_size;
  const float* x = (const float*)d_in[0];
  const float* gumbel = (const float*)d_in[1];
  const float* sym_w = (const float*)d_in[2];
  const float* sym_b = (const float*)d_in[3];
  const float* codebook = (const float*)d_in[4];
  const float* pos_enc = (const float*)d_in[5];
  const float* attn_in_w = (const float*)d_in[6];
  const float* attn_in_b = (const float*)d_in[7];
  const float* attn_out_w = (const float*)d_in[8];
  const float* attn_out_b = (const float*)d_in[9];
  const float* n1_g = (const float*)d_in[10];
  const float* n1_b = (const float*)d_in[11];
  const float* n2_g = (const float*)d_in[12];
  const float* n2_b = (const float*)d_in[13];
  const float* ffn_w1 = (const float*)d_in[14];
  const float* ffn_b1 = (const float*)d_in[15];
  const float* ffn_w2 = (const float*)d_in[16];
  const float* ffn_b2 = (const float*)d_in[17];
  const float* q_w = (const float*)d_in[18];
  const float* q_b = (const float*)d_in[19];
  const float* qln_g = (const float*)d_in[20];
  const float* qln_b = (const float*)d_in[21];
  const float* patterns = (const float*)d_in[22];
  const int* epoch = (const int*)d_in[23];
  const int* tot = (const int*)d_in[24];

  float* out = (float*)d_out;
  float* emb = out;               // [8192,512]
  float* assign = out + 4194304;  // [8192,512]
  float* logits = out + 8388608;  // [8192,512]
  float* h = out + 12582912;      // [8192,512]
  float* idxf = out + 16777216;   // [8192]

  float* ws_f = (float*)d_ws;
  // A region @0 (18.87M floats = 37.75M u16)
  u16* a16 = (u16*)ws_f;
  // B region @18.87M floats (6.29M floats = 12.58M u16)
  float* bF = ws_f + 18874368;
  u16* b16 = (u16*)bF;
  u16 *hnH = b16, *hnM = b16 + 4194304, *hnL = b16 + 8388608;
  // W region @25.17M floats (1.18M floats = 2.36M u16)
  float* wF = ws_f + 25165824;
  u16* w16 = (u16*)wF;

  // ---- symbolization ----
  // x planes: 3 x 8.39M u16 in A
  u16 *xH = a16, *xM = a16 + 8388608, *xL = a16 + 16777216;
  split3_k<<<2048, 256, 0, stream>>>(x, xH, xM, xL, 2097152);
  split3_k<<<512, 256, 0, stream>>>(sym_w, w16, w16 + 524288, w16 + 1048576,
                                    131072);
  gemm_mf<64, E_BIAS><<<dim3(4, 128), 256, 0, stream>>>(
      xH, xM, xL, w16, w16 + 524288, w16 + 1048576, sym_b, nullptr, bF,
      nullptr, nullptr, nullptr, 512, 1024, 1024, 1024);
  // cbn planes @ W (sym_w dead)
  l2_split3<<<256, 256, 0, stream>>>(codebook, w16, w16 + 524288,
                                     w16 + 1048576);
  // hp_n planes @ A[0..12.58M u16] (x planes dead)
  u16 *hpH = a16, *hpM = a16 + 4194304, *hpL = a16 + 8388608;
  l2_split3<<<2048, 256, 0, stream>>>(bF, hpH, hpM, hpL);
  // soft planes @ A[12.58M..37.75M u16]
  u16 *sH = a16 + 12582912, *sM = a16 + 20971520, *sL = a16 + 29360128;
  gemm_mf<64, E_GUM3><<<dim3(8, 128), 256, 0, stream>>>(
      hpH, hpM, hpL, w16, w16 + 524288, w16 + 1048576, nullptr, gumbel,
      nullptr, sH, sM, sL, 1024, 512, 512, 512);
  softmax3<<<8192, 256, 0, stream>>>(sH, sM, sL);
  tsplit_cb<<<512, 256, 0, stream>>>(codebook, w16, w16 + 524288,
                                     w16 + 1048576);
  gemm_mf<64, E_POS><<<dim3(4, 128), 256, 0, stream>>>(
      sH, sM, sL, w16, w16 + 524288, w16 + 1048576, nullptr, pos_enc, h,
      nullptr, nullptr, nullptr, 512, 1024, 1024, 1024);

  // ---- transformer layers ----
  // qkv planes: H @ a16, M @ +12.58M, L @ +25.17M (each 12.58M u16)
  u16 *qkvH = a16, *qkvM = a16 + 12582912, *qkvL = a16 + 25165824;
  // FFN weight planes inside A after qkv planes die
  u16* w1p = (u16*)(ws_f + 12582912);
  u16* w2p = (u16*)(ws_f + 14155776);
  // FFN mid planes @ A[0..25.17M u16]
  u16 *pH = a16, *pM = a16 + 8388608, *pL = a16 + 16777216;

  for (int l = 0; l < 4; ++l) {
    const float* inw = attn_in_w + (size_t)l * 1536 * 512;
    const float* inb = attn_in_b + (size_t)l * 1536;
    const float* outw = attn_out_w + (size_t)l * 512 * 512;
    const float* outb = attn_out_b + (size_t)l * 512;
    const float* w1 = ffn_w1 + (size_t)l * 2048 * 512;
    const float* b1 = ffn_b1 + (size_t)l * 2048;
    const float* w2 = ffn_w2 + (size_t)l * 512 * 2048;
    const float* b2 = ffn_b2 + (size_t)l * 512;

    ln_split3<<<2048, 256, 0, stream>>>(h, n1_g + l * 512, n1_b + l * 512,
                                        hnH, hnM, hnL);
    split3_k<<<1024, 256, 0, stream>>>(inw, w16, w16 + 786432, w16 + 1572864,
                                       196608);
    gemm_mf<128, E_QKV3><<<dim3(12, 64), 256, 0, stream>>>(
        hnH, hnM, hnL, w16, w16 + 786432, w16 + 1572864, inb, nullptr,
        nullptr, qkvH, qkvM, qkvL, 1536, 512, 512, 512);
    flash_mfma<<<dim3(16, 64), 256, 0, stream>>>(qkvH, qkvM, qkvL, hnH, hnM,
                                                 hnL);
    split3_k<<<256, 256, 0, stream>>>(outw, w16, w16 + 262144, w16 + 524288,
                                      65536);
    gemm_mf<64, E_RES><<<dim3(4, 128), 256, 0, stream>>>(
        hnH, hnM, hnL, w16, w16 + 262144, w16 + 524288, outb, h, h, nullptr,
        nullptr, nullptr, 512, 512, 512, 512);
    ln_split3<<<2048, 256, 0, stream>>>(h, n2_g + l * 512, n2_b + l * 512,
                                        hnH, hnM, hnL);
    split3_k<<<1024, 256, 0, stream>>>(w1, w1p, w1p + 1048576, w1p + 2097152,
                                       262144);
    split3_k<<<1024, 256, 0, stream>>>(w2, w2p, w2p + 1048576, w2p + 2097152,
                                       262144);
    for (int c = 0; c < 2; ++c) {
      gemm_mf<128, E_GELU3><<<dim3(8, 64), 256, 0, stream>>>(
          hnH, hnM, hnL, w1p + c * 524288, w1p + 1048576 + c * 524288,
          w1p + 2097152 + c * 524288, b1 + c * 1024, nullptr, nullptr, pH, pM,
          pL, 1024, 512, 512, 512);
      if (c == 0) {
        gemm_mf<64, E_RES><<<dim3(4, 128), 256, 0, stream>>>(
            pH, pM, pL, w2p + 0, w2p + 1048576, w2p + 2097152, b2, h, h,
            nullptr, nullptr, nullptr, 512, 1024, 1024, 2048);
      } else {
        gemm_mf<64, E_ACC><<<dim3(4, 128), 256, 0, stream>>>(
            pH, pM, pL, w2p + 1024, w2p + 1048576 + 1024, w2p + 2097152 + 1024,
            nullptr, nullptr, h, nullptr, nullptr, nullptr, 512, 1024, 1024,
            2048);
      }
    }
  }

  // ---- VQ head (fp32-vector precision anchor) ----
  gemm_f32<64, 128, 32, E_BIAS><<<dim3(4, 128), 256, 0, stream>>>(
      h, q_w, q_b, bF, 8192, 512, 512, nullptr, nullptr);
  ln_l2_f32<<<2048, 256, 0, stream>>>(bF, qln_g, qln_b, bF);
  l2_f32<<<128, 256, 0, stream>>>(patterns, wF);
  gemm_f32<64, 128, 32, E_VQ><<<dim3(4, 128), 256, 0, stream>>>(
      bF, wF, nullptr, logits, 8192, 512, 512, epoch, tot);
  vq_finalize<<<2048, 256, 0, stream>>>(logits, patterns, emb, assign, idxf);
}

// Round 8
// 2758.602 us; speedup vs baseline: 11.2980x; 1.0584x over previous
//
#include <hip/hip_runtime.h>

#define DEV __device__ __forceinline__

typedef unsigned short u16;
typedef unsigned int u32;
typedef __attribute__((ext_vector_type(8))) short bf8_t;   // 8 bf16 (4 VGPR)
typedef __attribute__((ext_vector_type(4))) float f4_t;

constexpr int T_SEQ = 1024;
constexpr int DMODEL = 512;
constexpr int NPAT = 512;

// ---------------- epilogue modes ----------------
enum {
  E_BIAS = 0,
  E_VQ = 5,
  E_RES = 6,
  E_ACC = 7,
  E_POS = 8,
  E_GUM3 = 9,
  E_GELU3 = 10,
  E_QKV3 = 11
};

// ---------------- bf16 triple-split helpers ----------------
DEV u16 f2bf(float x) {
  u32 u = __float_as_uint(x);
  u32 r = u + 0x7FFFu + ((u >> 16) & 1u);
  return (u16)(r >> 16);
}
DEV float bf2f(u16 h) { return __uint_as_float((u32)h << 16); }
DEV void split3(float x, u16& h, u16& m, u16& l) {
  h = f2bf(x);
  float r1 = x - bf2f(h);
  m = f2bf(r1);
  float r2 = r1 - bf2f(m);
  l = f2bf(r2);
}

DEV f4_t mf16(bf8_t a, bf8_t b, f4_t c) {
  return __builtin_amdgcn_mfma_f32_16x16x32_bf16(a, b, c, 0, 0, 0);
}
// 6-product triple-split accumulate (err ~2^-24)
DEV f4_t prod6(bf8_t ah, bf8_t am, bf8_t al, bf8_t bh, bf8_t bm, bf8_t bl,
               f4_t c) {
  c = mf16(ah, bh, c);
  c = mf16(ah, bm, c);
  c = mf16(am, bh, c);
  c = mf16(ah, bl, c);
  c = mf16(am, bm, c);
  c = mf16(al, bh, c);
  return c;
}

// async global->LDS, 16B per lane; LDS dest = base + lane*16 (wave-uniform base)
typedef const __attribute__((address_space(1))) unsigned char* gas_t;
typedef __attribute__((address_space(3))) unsigned char* las_t;
DEV void gload16(const u16* g, u16* l) {
  __builtin_amdgcn_global_load_lds((gas_t)(const void*)g, (las_t)(void*)l, 16,
                                   0, 0);
}

// ---------------- MFMA GEMM, triple-bf16 split (fp32-accurate) ---------------
// C[M,N] = A[M,K]*B[N,K]^T via 6 bf16 products. Verified R6/R7.
// Staging via global_load_lds (pre-swizzled source, linear LDS dest).
// 1-D grid + bijective XCD swizzle (consecutive logical blocks share A panel).
template <int BM, int EPI>
__global__ __launch_bounds__(256, 2) void gemm_mf(
    const u16* __restrict__ Ah, const u16* __restrict__ Am,
    const u16* __restrict__ Al, const u16* __restrict__ Bh,
    const u16* __restrict__ Bm, const u16* __restrict__ Bl,
    const float* __restrict__ bias, const float* __restrict__ res,
    float* __restrict__ Cf, u16* __restrict__ Ch, u16* __restrict__ Cm,
    u16* __restrict__ Cl, int N, int KK, int lda, int ldb, int gx) {
  constexpr int MT = BM / 32;  // m-tiles per wave
  __shared__ __align__(16) u16 AsH[BM][4][8], AsM[BM][4][8], AsL[BM][4][8];
  __shared__ __align__(16) u16 BsH[128][4][8], BsM[128][4][8], BsL[128][4][8];
  const int tid = threadIdx.x;
  const int w = tid >> 6, lane = tid & 63;
  const int wy = w >> 1, wx = w & 1;
  const int lr = lane & 15, lg = lane >> 4;

  // bijective XCD swizzle (all grids divisible by 8)
  const int nwg = gridDim.x;
  const int bid = blockIdx.x;
  const int qq = nwg >> 3;
  const int wg = (bid & 7) * qq + (bid >> 3);
  const int by = wg / gx, bx = wg % gx;
  const int bm = by * BM, bn = bx * 128;

  const int rowl = lane >> 2, slot4 = lane & 3;  // per-lane stage coords

  f4_t acc[MT][4];
#pragma unroll
  for (int mt = 0; mt < MT; ++mt)
#pragma unroll
    for (int nt = 0; nt < 4; ++nt) acc[mt][nt] = (f4_t){0.f, 0.f, 0.f, 0.f};

  for (int k0 = 0; k0 < KK; k0 += 32) {
    if (k0) __syncthreads();
    // ---- A planes: 3*(BM/16) 1KB chunks, round-robin over waves ----
#pragma unroll
    for (int it = 0; it < 3 * (BM / 16) / 4; ++it) {
      const int f = w + 4 * it;
      const int plane = f / (BM / 16);
      const int ch = f % (BM / 16);
      const int row = ch * 16 + rowl;
      const int kp = slot4 ^ ((row >> 1) & 3);
      const size_t g = (size_t)(bm + row) * lda + k0 + kp * 8;
      if (plane == 0)
        gload16(&Ah[g], &AsH[0][0][0] + ch * 512);
      else if (plane == 1)
        gload16(&Am[g], &AsM[0][0][0] + ch * 512);
      else
        gload16(&Al[g], &AsL[0][0][0] + ch * 512);
    }
    // ---- B planes: 24 chunks ----
#pragma unroll
    for (int it = 0; it < 6; ++it) {
      const int f = w + 4 * it;
      const int plane = f >> 3;
      const int ch = f & 7;
      const int row = ch * 16 + rowl;
      const int kp = slot4 ^ ((row >> 1) & 3);
      const size_t g = (size_t)(bn + row) * ldb + k0 + kp * 8;
      if (plane == 0)
        gload16(&Bh[g], &BsH[0][0][0] + ch * 512);
      else if (plane == 1)
        gload16(&Bm[g], &BsM[0][0][0] + ch * 512);
      else
        gload16(&Bl[g], &BsL[0][0][0] + ch * 512);
    }
    __syncthreads();

    bf8_t fah[MT], fam[MT], fal[MT], fbh[4], fbm[4], fbl[4];
#pragma unroll
    for (int mt = 0; mt < MT; ++mt) {
      int row = wy * (BM / 2) + mt * 16 + lr;
      int slot = lg ^ ((row >> 1) & 3);
      fah[mt] = *(const bf8_t*)&AsH[row][slot][0];
      fam[mt] = *(const bf8_t*)&AsM[row][slot][0];
      fal[mt] = *(const bf8_t*)&AsL[row][slot][0];
    }
#pragma unroll
    for (int nt = 0; nt < 4; ++nt) {
      int col = wx * 64 + nt * 16 + lr;
      int slot = lg ^ ((col >> 1) & 3);
      fbh[nt] = *(const bf8_t*)&BsH[col][slot][0];
      fbm[nt] = *(const bf8_t*)&BsM[col][slot][0];
      fbl[nt] = *(const bf8_t*)&BsL[col][slot][0];
    }
#pragma unroll
    for (int mt = 0; mt < MT; ++mt)
#pragma unroll
      for (int nt = 0; nt < 4; ++nt)
        acc[mt][nt] = prod6(fah[mt], fam[mt], fal[mt], fbh[nt], fbm[nt],
                            fbl[nt], acc[mt][nt]);
  }

  // ---- epilogue (C frag: col = lane&15, row = 4*(lane>>4)+i) ----
  float bv[4];
  if constexpr (EPI == E_BIAS || EPI == E_RES || EPI == E_GELU3 ||
                EPI == E_QKV3) {
#pragma unroll
    for (int nt = 0; nt < 4; ++nt) bv[nt] = bias[bn + wx * 64 + nt * 16 + lr];
  }
#pragma unroll
  for (int mt = 0; mt < MT; ++mt)
#pragma unroll
    for (int nt = 0; nt < 4; ++nt) {
      const int c = bn + wx * 64 + nt * 16 + lr;
#pragma unroll
      for (int i = 0; i < 4; ++i) {
        const int m = bm + wy * (BM / 2) + mt * 16 + 4 * lg + i;
        const size_t idx = (size_t)m * N + c;
        float v = acc[mt][nt][i];
        if constexpr (EPI == E_BIAS) {
          Cf[idx] = v + bv[nt];
        } else if constexpr (EPI == E_RES) {
          Cf[idx] = v + bv[nt] + res[idx];
        } else if constexpr (EPI == E_ACC) {
          Cf[idx] += v;
        } else if constexpr (EPI == E_POS) {
          Cf[idx] = v + res[(size_t)(m & 1023) * N + c];
        } else if constexpr (EPI == E_GUM3) {
          float t = 4.0f * v + 2.0f * res[idx];
          u16 h2, m2, l2;
          split3(t, h2, m2, l2);
          Ch[idx] = h2;
          Cm[idx] = m2;
          Cl[idx] = l2;
        } else if constexpr (EPI == E_GELU3) {
          float t = v + bv[nt];
          float g = 0.5f * t * (1.0f + erff(t * 0.7071067811865476f));
          u16 h2, m2, l2;
          split3(g, h2, m2, l2);
          Ch[idx] = h2;
          Cm[idx] = m2;
          Cl[idx] = l2;
        } else if constexpr (EPI == E_QKV3) {
          float t = v + bv[nt];
          u16 h2, m2, l2;
          split3(t, h2, m2, l2);
          size_t o;
          if (c < 512) {
            o = (size_t)m * 512 + c;                       // Q [B,T,512]
          } else if (c < 1024) {
            o = 4194304 + (size_t)m * 512 + (c - 512);     // K [B,T,512]
          } else {
            int cc = c - 1024, hh2 = cc >> 6, dd = cc & 63;
            int bb2 = m >> 10, tt = m & 1023;
            o = 8388608 +
                (((size_t)(bb2 * 8 + hh2) * 64 + dd) << 10) + tt;  // Vt
          }
          Ch[o] = h2;
          Cm[o] = m2;
          Cl[o] = l2;
        }
      }
    }
}

// ---------------- MFMA flash attention (triple-split, fp32-grade) ------------
// grid (16, 64): qt 0..15 (64 q-rows/block), bh = b*8+hh. 4 waves, each owns
// 16 q-rows. K rows-major [B,T,512]; V pre-transposed [B,8,64,T].
// K/V staging via global_load_lds (pre-swizzled source).
__global__ __launch_bounds__(256) void flash_mfma(
    const u16* __restrict__ QKVh, const u16* __restrict__ QKVm,
    const u16* __restrict__ QKVl, u16* __restrict__ Oh, u16* __restrict__ Om,
    u16* __restrict__ Ol) {
  __shared__ __align__(16) u16 Ks[3][64][8][8];
  __shared__ __align__(16) u16 Vs[3][64][8][8];
  __shared__ __align__(16) u16 Ps[3][64][8][8];
  const int tid = threadIdx.x;
  const int w = tid >> 6, lane = tid & 63;
  const int lr = lane & 15, lg = lane >> 4;
  const int qt = blockIdx.x, bh = blockIdx.y;
  const int b = bh >> 3, hh = bh & 7;

  const u16* Qh = QKVh;
  const u16* Qm = QKVm;
  const u16* Ql = QKVl;
  const u16* Kh = QKVh + 4194304;
  const u16* Km = QKVm + 4194304;
  const u16* Kl = QKVl + 4194304;
  const u16* Vh = QKVh + 8388608;
  const u16* Vm = QKVm + 8388608;
  const u16* Vl = QKVl + 8388608;

  // Q fragments (A-op: m = lr, k-packet = lg), hoisted for all kt
  bf8_t qf[2][3];
  {
    size_t g =
        ((size_t)(b * 1024 + qt * 64 + w * 16 + lr)) * 512 + hh * 64 + lg * 8;
    qf[0][0] = *(const bf8_t*)&Qh[g];
    qf[0][1] = *(const bf8_t*)&Qm[g];
    qf[0][2] = *(const bf8_t*)&Ql[g];
    qf[1][0] = *(const bf8_t*)&Qh[g + 32];
    qf[1][1] = *(const bf8_t*)&Qm[g + 32];
    qf[1][2] = *(const bf8_t*)&Ql[g + 32];
  }

  f4_t oacc[4];
#pragma unroll
  for (int nt = 0; nt < 4; ++nt) oacc[nt] = (f4_t){0.f, 0.f, 0.f, 0.f};
  float mrun[4], lrun[4];
#pragma unroll
  for (int i = 0; i < 4; ++i) {
    mrun[i] = -__builtin_huge_valf();
    lrun[i] = 0.0f;
  }

  const int rowl8 = lane >> 3, slot8 = lane & 7;  // stage coords (8 rows/chunk)

  for (int kt = 0; kt < 16; ++kt) {
    __syncthreads();
    // ---- stage K tile + Vt tile via global_load_lds: 48 x 1KB chunks ----
#pragma unroll
    for (int it = 0; it < 6; ++it) {
      const int f = w + 4 * it;
      const int plane = f >> 3, ch = f & 7;
      const int row = ch * 8 + rowl8;
      const int kp = slot8 ^ (row & 7);
      const size_t gk =
          ((size_t)(b * 1024 + kt * 64 + row)) * 512 + hh * 64 + kp * 8;
      if (plane == 0)
        gload16(&Kh[gk], &Ks[0][0][0][0] + ch * 512);
      else if (plane == 1)
        gload16(&Km[gk], &Ks[1][0][0][0] + ch * 512);
      else
        gload16(&Kl[gk], &Ks[2][0][0][0] + ch * 512);
    }
#pragma unroll
    for (int it = 0; it < 6; ++it) {
      const int f = w + 4 * it;
      const int plane = f >> 3, ch = f & 7;
      const int row = ch * 8 + rowl8;
      const int kp = slot8 ^ (row & 7);
      const size_t gv =
          ((size_t)((b * 8 + hh) * 64 + row)) * 1024 + kt * 64 + kp * 8;
      if (plane == 0)
        gload16(&Vh[gv], &Vs[0][0][0][0] + ch * 512);
      else if (plane == 1)
        gload16(&Vm[gv], &Vs[1][0][0][0] + ch * 512);
      else
        gload16(&Vl[gv], &Vs[2][0][0][0] + ch * 512);
    }
    __syncthreads();

    // ---- S = Q K^T : 4 n-tiles x 2 k-slices x 6 products ----
    f4_t s[4];
#pragma unroll
    for (int nt = 0; nt < 4; ++nt) {
      s[nt] = (f4_t){0.f, 0.f, 0.f, 0.f};
      const int col = nt * 16 + lr;
#pragma unroll
      for (int ks = 0; ks < 2; ++ks) {
        int slot = (ks * 4 + lg) ^ (col & 7);
        bf8_t kh = *(const bf8_t*)&Ks[0][col][slot][0];
        bf8_t km = *(const bf8_t*)&Ks[1][col][slot][0];
        bf8_t kl = *(const bf8_t*)&Ks[2][col][slot][0];
        s[nt] = prod6(qf[ks][0], qf[ks][1], qf[ks][2], kh, km, kl, s[nt]);
      }
    }

    // ---- online softmax (row = 4*lg+i; reduce over lr via shfl) ----
#pragma unroll
    for (int i = 0; i < 4; ++i) {
      float rm = -__builtin_huge_valf();
#pragma unroll
      for (int nt = 0; nt < 4; ++nt) {
        s[nt][i] *= 0.125f;
        rm = fmaxf(rm, s[nt][i]);
      }
      rm = fmaxf(rm, __shfl_xor(rm, 1));
      rm = fmaxf(rm, __shfl_xor(rm, 2));
      rm = fmaxf(rm, __shfl_xor(rm, 4));
      rm = fmaxf(rm, __shfl_xor(rm, 8));
      float mnew = fmaxf(mrun[i], rm);
      float alpha = expf(mrun[i] - mnew);
      float rs = 0.0f;
#pragma unroll
      for (int nt = 0; nt < 4; ++nt) {
        float p = expf(s[nt][i] - mnew);
        s[nt][i] = p;
        rs += p;
      }
      rs += __shfl_xor(rs, 1);
      rs += __shfl_xor(rs, 2);
      rs += __shfl_xor(rs, 4);
      rs += __shfl_xor(rs, 8);
      lrun[i] = lrun[i] * alpha + rs;
      mrun[i] = mnew;
#pragma unroll
      for (int nt = 0; nt < 4; ++nt) oacc[nt][i] *= alpha;
    }

    // ---- P -> wave-private LDS slice (3 planes, swizzled) ----
#pragma unroll
    for (int nt = 0; nt < 4; ++nt)
#pragma unroll
      for (int i = 0; i < 4; ++i) {
        int qrow = w * 16 + 4 * lg + i;
        int kv = nt * 16 + lr;
        int kp = kv >> 3, j = kv & 7;
        int slot = kp ^ (qrow & 7);
        u16 h2, m2, l2;
        split3(s[nt][i], h2, m2, l2);
        Ps[0][qrow][slot][j] = h2;
        Ps[1][qrow][slot][j] = m2;
        Ps[2][qrow][slot][j] = l2;
      }

    // ---- O += P V (A = own P rows, B = Vt cols) ----
    bf8_t pf[2][3];
#pragma unroll
    for (int ks = 0; ks < 2; ++ks) {
      int row = w * 16 + lr;
      int slot = (ks * 4 + lg) ^ (row & 7);
      pf[ks][0] = *(const bf8_t*)&Ps[0][row][slot][0];
      pf[ks][1] = *(const bf8_t*)&Ps[1][row][slot][0];
      pf[ks][2] = *(const bf8_t*)&Ps[2][row][slot][0];
    }
#pragma unroll
    for (int ntd = 0; ntd < 4; ++ntd) {
      const int col = ntd * 16 + lr;
#pragma unroll
      for (int ks = 0; ks < 2; ++ks) {
        int slot = (ks * 4 + lg) ^ (col & 7);
        bf8_t vh = *(const bf8_t*)&Vs[0][col][slot][0];
        bf8_t vm = *(const bf8_t*)&Vs[1][col][slot][0];
        bf8_t vl = *(const bf8_t*)&Vs[2][col][slot][0];
        oacc[ntd] =
            prod6(pf[ks][0], pf[ks][1], pf[ks][2], vh, vm, vl, oacc[ntd]);
      }
    }
  }

  // ---- epilogue: normalize, split3, store planes [B,T,512] ----
#pragma unroll
  for (int i = 0; i < 4; ++i) {
    float inv = 1.0f / lrun[i];
    int t = qt * 64 + w * 16 + 4 * lg + i;
#pragma unroll
    for (int ntd = 0; ntd < 4; ++ntd) {
      int d = hh * 64 + ntd * 16 + lr;
      size_t idx = ((size_t)(b * 1024 + t)) * 512 + d;
      u16 h2, m2, l2;
      split3(oacc[ntd][i] * inv, h2, m2, l2);
      Oh[idx] = h2;
      Om[idx] = m2;
      Ol[idx] = l2;
    }
  }
}

// ---------------- fp32 vector GEMM (VQ-head precision anchor) ----------------
template <int BM, int BN, int WR, int EPI>
__global__ __launch_bounds__((BM / WR) * (BN / 64) * 64) void gemm_f32(
    const float* __restrict__ A, const float* __restrict__ Bmat,
    const float* __restrict__ bias, float* __restrict__ C, int M, int N, int K,
    const int* __restrict__ ep, const int* __restrict__ tot) {
  constexpr int BK = 16;
  constexpr int WN = BN / 64;
  constexpr int NW = (BM / WR) * WN;
  constexpr int NT = NW * 64;
  constexpr int RM = WR / 8;
  __shared__ __align__(16) float As[BK][BM + 4];
  __shared__ __align__(16) float Bs[BK][BN + 4];
  const int tid = threadIdx.x;
  const int w = tid >> 6, lane = tid & 63;
  const int wy = w / WN, wx = w % WN;
  const int ly = lane >> 3, lx = lane & 7;
  const int bm = blockIdx.y * BM;
  const int bn = blockIdx.x * BN;
  const int rbase = wy * WR + ly * RM;

  float acc[RM][8];
#pragma unroll
  for (int i = 0; i < RM; ++i)
#pragma unroll
    for (int j = 0; j < 8; ++j) acc[i][j] = 0.0f;

  for (int k0 = 0; k0 < K; k0 += BK) {
#pragma unroll
    for (int i = 0; i < (BM * BK / 4) / NT; ++i) {
      int idx = tid + i * NT;
      int r = idx >> 2, c4 = (idx & 3) << 2;
      const float4 v = *(const float4*)(A + (size_t)(bm + r) * K + k0 + c4);
      As[c4 + 0][r] = v.x;
      As[c4 + 1][r] = v.y;
      As[c4 + 2][r] = v.z;
      As[c4 + 3][r] = v.w;
    }
#pragma unroll
    for (int i = 0; i < (BN * BK / 4) / NT; ++i) {
      int idx = tid + i * NT;
      int r = idx >> 2, c4 = (idx & 3) << 2;
      const float4 v = *(const float4*)(Bmat + (size_t)(bn + r) * K + k0 + c4);
      Bs[c4 + 0][r] = v.x;
      Bs[c4 + 1][r] = v.y;
      Bs[c4 + 2][r] = v.z;
      Bs[c4 + 3][r] = v.w;
    }
    __syncthreads();
#pragma unroll
    for (int k = 0; k < BK; ++k) {
      float a[RM], b[8];
#pragma unroll
      for (int r4 = 0; r4 < RM; r4 += 4)
        *(float4*)&a[r4] = *(const float4*)&As[k][rbase + r4];
      *(float4*)&b[0] = *(const float4*)&Bs[k][wx * 64 + lx * 8];
      *(float4*)&b[4] = *(const float4*)&Bs[k][wx * 64 + lx * 8 + 4];
#pragma unroll
      for (int i = 0; i < RM; ++i)
#pragma unroll
        for (int j = 0; j < 8; ++j) acc[i][j] = fmaf(a[i], b[j], acc[i][j]);
    }
    __syncthreads();
  }

  const int ncol = bn + wx * 64 + lx * 8;
  float bb[8];
  if constexpr (EPI == E_BIAS) {
    *(float4*)&bb[0] = *(const float4*)(bias + ncol);
    *(float4*)&bb[4] = *(const float4*)(bias + ncol + 4);
  }
  float invt = 1.0f;
  if constexpr (EPI == E_VQ) {
    float t = 1.0f - 0.5f * (float)ep[0] / (float)tot[0];
    invt = 1.0f / fmaxf(0.5f, t);
  }
#pragma unroll
  for (int i = 0; i < RM; ++i) {
    const int m = bm + rbase + i;
    float o[8];
#pragma unroll
    for (int j = 0; j < 8; ++j) o[j] = acc[i][j];
    if constexpr (EPI == E_BIAS) {
#pragma unroll
      for (int j = 0; j < 8; ++j) o[j] += bb[j];
    } else if constexpr (EPI == E_VQ) {
#pragma unroll
      for (int j = 0; j < 8; ++j) o[j] *= invt;
    }
    *(float4*)(C + (size_t)m * N + ncol) = *(float4*)&o[0];
    *(float4*)(C + (size_t)m * N + ncol + 4) = *(float4*)&o[4];
  }
}

// ---------------- row kernels ----------------
DEV float wave_sum(float v) {
#pragma unroll
  for (int off = 1; off < 64; off <<= 1) v += __shfl_xor(v, off);
  return v;
}

DEV void store8_split3(u16* H, u16* M, u16* L, size_t base, const float* t) {
  u16 vh[8], vm[8], vl[8];
#pragma unroll
  for (int j = 0; j < 8; ++j) split3(t[j], vh[j], vm[j], vl[j]);
  *(ushort4*)&H[base] = make_ushort4(vh[0], vh[1], vh[2], vh[3]);
  *(ushort4*)&H[base + 4] = make_ushort4(vh[4], vh[5], vh[6], vh[7]);
  *(ushort4*)&M[base] = make_ushort4(vm[0], vm[1], vm[2], vm[3]);
  *(ushort4*)&M[base + 4] = make_ushort4(vm[4], vm[5], vm[6], vm[7]);
  *(ushort4*)&L[base] = make_ushort4(vl[0], vl[1], vl[2], vl[3]);
  *(ushort4*)&L[base + 4] = make_ushort4(vl[4], vl[5], vl[6], vl[7]);
}

__global__ __launch_bounds__(256) void ln_split3(const float* __restrict__ x,
                                                 const float* __restrict__ g,
                                                 const float* __restrict__ b,
                                                 u16* __restrict__ yh,
                                                 u16* __restrict__ ym,
                                                 u16* __restrict__ yl) {
  const int row = blockIdx.x * 4 + (threadIdx.x >> 6);
  const int lane = threadIdx.x & 63;
  const float* xr = x + (size_t)row * DMODEL;
  float v[8];
  *(float4*)&v[0] = *(const float4*)(xr + lane * 8);
  *(float4*)&v[4] = *(const float4*)(xr + lane * 8 + 4);
  float s = 0.0f;
#pragma unroll
  for (int j = 0; j < 8; ++j) s += v[j];
  s = wave_sum(s);
  float mean = s * (1.0f / 512.0f);
  float s2 = 0.0f;
#pragma unroll
  for (int j = 0; j < 8; ++j) {
    float d = v[j] - mean;
    s2 += d * d;
  }
  s2 = wave_sum(s2);
  float rstd = 1.0f / sqrtf(s2 * (1.0f / 512.0f) + 1e-5f);
  float gg[8], bv[8];
  *(float4*)&gg[0] = *(const float4*)(g + lane * 8);
  *(float4*)&gg[4] = *(const float4*)(g + lane * 8 + 4);
  *(float4*)&bv[0] = *(const float4*)(b + lane * 8);
  *(float4*)&bv[4] = *(const float4*)(b + lane * 8 + 4);
  float t[8];
#pragma unroll
  for (int j = 0; j < 8; ++j) t[j] = (v[j] - mean) * rstd * gg[j] + bv[j];
  store8_split3(yh, ym, yl, (size_t)row * DMODEL + lane * 8, t);
}

__global__ __launch_bounds__(256) void ln_l2_f32(const float* __restrict__ x,
                                                 const float* __restrict__ g,
                                                 const float* __restrict__ b,
                                                 float* __restrict__ y) {
  const int row = blockIdx.x * 4 + (threadIdx.x >> 6);
  const int lane = threadIdx.x & 63;
  const float* xr = x + (size_t)row * DMODEL;
  float v[8];
  *(float4*)&v[0] = *(const float4*)(xr + lane * 8);
  *(float4*)&v[4] = *(const float4*)(xr + lane * 8 + 4);
  float s = 0.0f;
#pragma unroll
  for (int j = 0; j < 8; ++j) s += v[j];
  s = wave_sum(s);
  float mean = s * (1.0f / 512.0f);
  float s2 = 0.0f;
#pragma unroll
  for (int j = 0; j < 8; ++j) {
    float d = v[j] - mean;
    s2 += d * d;
  }
  s2 = wave_sum(s2);
  float rstd = 1.0f / sqrtf(s2 * (1.0f / 512.0f) + 1e-5f);
  float gg[8], bv[8];
  *(float4*)&gg[0] = *(const float4*)(g + lane * 8);
  *(float4*)&gg[4] = *(const float4*)(g + lane * 8 + 4);
  *(float4*)&bv[0] = *(const float4*)(b + lane * 8);
  *(float4*)&bv[4] = *(const float4*)(b + lane * 8 + 4);
  float t[8];
#pragma unroll
  for (int j = 0; j < 8; ++j) t[j] = (v[j] - mean) * rstd * gg[j] + bv[j];
  float n2 = 0.0f;
#pragma unroll
  for (int j = 0; j < 8; ++j) n2 += t[j] * t[j];
  n2 = wave_sum(n2);
  float den = fmaxf(sqrtf(n2), 1e-12f);
#pragma unroll
  for (int j = 0; j < 8; ++j) t[j] /= den;
  float* yr = y + (size_t)row * DMODEL;
  *(float4*)(yr + lane * 8) = *(float4*)&t[0];
  *(float4*)(yr + lane * 8 + 4) = *(float4*)&t[4];
}

__global__ __launch_bounds__(256) void l2_split3(const float* __restrict__ x,
                                                 u16* __restrict__ yh,
                                                 u16* __restrict__ ym,
                                                 u16* __restrict__ yl) {
  const int row = blockIdx.x * 4 + (threadIdx.x >> 6);
  const int lane = threadIdx.x & 63;
  const float* xr = x + (size_t)row * DMODEL;
  float v[8];
  *(float4*)&v[0] = *(const float4*)(xr + lane * 8);
  *(float4*)&v[4] = *(const float4*)(xr + lane * 8 + 4);
  float n2 = 0.0f;
#pragma unroll
  for (int j = 0; j < 8; ++j) n2 += v[j] * v[j];
  n2 = wave_sum(n2);
  float den = fmaxf(sqrtf(n2), 1e-12f);
#pragma unroll
  for (int j = 0; j < 8; ++j) v[j] /= den;
  store8_split3(yh, ym, yl, (size_t)row * DMODEL + lane * 8, v);
}

__global__ __launch_bounds__(256) void l2_f32(const float* __restrict__ x,
                                              float* __restrict__ y) {
  const int row = blockIdx.x * 4 + (threadIdx.x >> 6);
  const int lane = threadIdx.x & 63;
  const float* xr = x + (size_t)row * DMODEL;
  float v[8];
  *(float4*)&v[0] = *(const float4*)(xr + lane * 8);
  *(float4*)&v[4] = *(const float4*)(xr + lane * 8 + 4);
  float n2 = 0.0f;
#pragma unroll
  for (int j = 0; j < 8; ++j) n2 += v[j] * v[j];
  n2 = wave_sum(n2);
  float den = fmaxf(sqrtf(n2), 1e-12f);
#pragma unroll
  for (int j = 0; j < 8; ++j) v[j] /= den;
  float* yr = y + (size_t)row * DMODEL;
  *(float4*)(yr + lane * 8) = *(float4*)&v[0];
  *(float4*)(yr + lane * 8 + 4) = *(float4*)&v[4];
}

__global__ __launch_bounds__(256) void softmax3(u16* __restrict__ H,
                                                u16* __restrict__ M,
                                                u16* __restrict__ L) {
  const int row = blockIdx.x;
  const int tid = threadIdx.x;
  const size_t base = (size_t)row * 1024 + tid * 4;
  ushort4 qh = *(const ushort4*)&H[base];
  ushort4 qm = *(const ushort4*)&M[base];
  ushort4 ql = *(const ushort4*)&L[base];
  float v0 = bf2f(qh.x) + bf2f(qm.x) + bf2f(ql.x);
  float v1 = bf2f(qh.y) + bf2f(qm.y) + bf2f(ql.y);
  float v2 = bf2f(qh.z) + bf2f(qm.z) + bf2f(ql.z);
  float v3 = bf2f(qh.w) + bf2f(qm.w) + bf2f(ql.w);
  float mx = fmaxf(fmaxf(v0, v1), fmaxf(v2, v3));
#pragma unroll
  for (int off = 1; off < 64; off <<= 1) mx = fmaxf(mx, __shfl_xor(mx, off));
  __shared__ float red[4];
  const int wv = tid >> 6;
  if ((tid & 63) == 0) red[wv] = mx;
  __syncthreads();
  mx = fmaxf(fmaxf(red[0], red[1]), fmaxf(red[2], red[3]));
  float e0 = expf(v0 - mx), e1 = expf(v1 - mx), e2 = expf(v2 - mx),
        e3 = expf(v3 - mx);
  float s = e0 + e1 + e2 + e3;
#pragma unroll
  for (int off = 1; off < 64; off <<= 1) s += __shfl_xor(s, off);
  __syncthreads();
  if ((tid & 63) == 0) red[wv] = s;
  __syncthreads();
  s = red[0] + red[1] + red[2] + red[3];
  float inv = 1.0f / s;
  u16 ah[4], am[4], al[4];
  split3(e0 * inv, ah[0], am[0], al[0]);
  split3(e1 * inv, ah[1], am[1], al[1]);
  split3(e2 * inv, ah[2], am[2], al[2]);
  split3(e3 * inv, ah[3], am[3], al[3]);
  *(ushort4*)&H[base] = make_ushort4(ah[0], ah[1], ah[2], ah[3]);
  *(ushort4*)&M[base] = make_ushort4(am[0], am[1], am[2], am[3]);
  *(ushort4*)&L[base] = make_ushort4(al[0], al[1], al[2], al[3]);
}

__global__ __launch_bounds__(256) void split3_k(const float* __restrict__ src,
                                                u16* __restrict__ H,
                                                u16* __restrict__ M,
                                                u16* __restrict__ L, int n4) {
  for (int e = blockIdx.x * 256 + threadIdx.x; e < n4; e += gridDim.x * 256) {
    float4 v = *(const float4*)(src + (size_t)e * 4);
    u16 ah[4], am[4], al[4];
    split3(v.x, ah[0], am[0], al[0]);
    split3(v.y, ah[1], am[1], al[1]);
    split3(v.z, ah[2], am[2], al[2]);
    split3(v.w, ah[3], am[3], al[3]);
    *(ushort4*)&H[(size_t)e * 4] = make_ushort4(ah[0], ah[1], ah[2], ah[3]);
    *(ushort4*)&M[(size_t)e * 4] = make_ushort4(am[0], am[1], am[2], am[3]);
    *(ushort4*)&L[(size_t)e * 4] = make_ushort4(al[0], al[1], al[2], al[3]);
  }
}

__global__ __launch_bounds__(256) void tsplit_cb(const float* __restrict__ cb,
                                                 u16* __restrict__ th,
                                                 u16* __restrict__ tm,
                                                 u16* __restrict__ tl) {
  const int c = blockIdx.x;
  const int t = threadIdx.x;
  u16 ah[4], am[4], al[4];
#pragma unroll
  for (int j = 0; j < 4; ++j) {
    float v = cb[(size_t)(4 * t + j) * 512 + c];
    split3(v, ah[j], am[j], al[j]);
  }
  const size_t base = (size_t)c * 1024 + 4 * t;
  *(ushort4*)&th[base] = make_ushort4(ah[0], ah[1], ah[2], ah[3]);
  *(ushort4*)&tm[base] = make_ushort4(am[0], am[1], am[2], am[3]);
  *(ushort4*)&tl[base] = make_ushort4(al[0], al[1], al[2], al[3]);
}

__global__ __launch_bounds__(256) void vq_finalize(
    const float* __restrict__ logits, const float* __restrict__ patterns,
    float* __restrict__ emb, float* __restrict__ assign,
    float* __restrict__ idxf) {
  const int row = blockIdx.x * 4 + (threadIdx.x >> 6);
  const int lane = threadIdx.x & 63;
  const float* lr = logits + (size_t)row * NPAT;
  float best = -__builtin_huge_valf();
  int bi = 0;
#pragma unroll
  for (int jj = 0; jj < 8; ++jj) {
    int j = lane + jj * 64;
    float v = lr[j];
    if (v > best) {
      best = v;
      bi = j;
    }
  }
#pragma unroll
  for (int off = 1; off < 64; off <<= 1) {
    float ob = __shfl_xor(best, off);
    int oi = __shfl_xor(bi, off);
    if (ob > best || (ob == best && oi < bi)) {
      best = ob;
      bi = oi;
    }
  }
  const float* pr = patterns + (size_t)bi * DMODEL;
#pragma unroll
  for (int g = 0; g < 2; ++g) {
    int c = lane * 8 + g * 4;
    float4 pv = *(const float4*)(pr + c);
    *(float4*)(emb + (size_t)row * DMODEL + c) = pv;
    float4 av;
    av.x = (c + 0 == bi) ? 1.0f : 0.0f;
    av.y = (c + 1 == bi) ? 1.0f : 0.0f;
    av.z = (c + 2 == bi) ? 1.0f : 0.0f;
    av.w = (c + 3 == bi) ? 1.0f : 0.0f;
    *(float4*)(assign + (size_t)row * NPAT + c) = av;
  }
  if (lane == 0) idxf[row] = (float)bi;
}

// ---------------- host launch ----------------
extern "C" void kernel_launch(void* const* d_in, const int* in_sizes, int n_in,
                              void* d_out, int out_size, void* d_ws,
                              size_t ws_size, hipStream_t stream) {
  (void)in_sizes;
  (void)n_in;
  (void)out_size;
  (void)ws_size;
  const float* x = (const float*)d_in[0];
  const float* gumbel = (const float*)d_in[1];
  const float* sym_w = (const float*)d_in[2];
  const float* sym_b = (const float*)d_in[3];
  const float* codebook = (const float*)d_in[4];
  const float* pos_enc = (const float*)d_in[5];
  const float* attn_in_w = (const float*)d_in[6];
  const float* attn_in_b = (const float*)d_in[7];
  const float* attn_out_w = (const float*)d_in[8];
  const float* attn_out_b = (const float*)d_in[9];
  const float* n1_g = (const float*)d_in[10];
  const float* n1_b = (const float*)d_in[11];
  const float* n2_g = (const float*)d_in[12];
  const float* n2_b = (const float*)d_in[13];
  const float* ffn_w1 = (const float*)d_in[14];
  const float* ffn_b1 = (const float*)d_in[15];
  const float* ffn_w2 = (const float*)d_in[16];
  const float* ffn_b2 = (const float*)d_in[17];
  const float* q_w = (const float*)d_in[18];
  const float* q_b = (const float*)d_in[19];
  const float* qln_g = (const float*)d_in[20];
  const float* qln_b = (const float*)d_in[21];
  const float* patterns = (const float*)d_in[22];
  const int* epoch = (const int*)d_in[23];
  const int* tot = (const int*)d_in[24];

  float* out = (float*)d_out;
  float* emb = out;               // [8192,512]
  float* assign = out + 4194304;  // [8192,512]
  float* logits = out + 8388608;  // [8192,512]
  float* h = out + 12582912;      // [8192,512]
  float* idxf = out + 16777216;   // [8192]

  float* ws_f = (float*)d_ws;
  // A region @0 (18.87M floats = 37.75M u16)
  u16* a16 = (u16*)ws_f;
  // B region @18.87M floats (6.29M floats = 12.58M u16)
  float* bF = ws_f + 18874368;
  u16* b16 = (u16*)bF;
  u16 *hnH = b16, *hnM = b16 + 4194304, *hnL = b16 + 8388608;
  // W region @25.17M floats (1.18M floats = 2.36M u16)
  float* wF = ws_f + 25165824;
  u16* w16 = (u16*)wF;

  // ---- symbolization ----
  u16 *xH = a16, *xM = a16 + 8388608, *xL = a16 + 16777216;
  split3_k<<<2048, 256, 0, stream>>>(x, xH, xM, xL, 2097152);
  split3_k<<<512, 256, 0, stream>>>(sym_w, w16, w16 + 524288, w16 + 1048576,
                                    131072);
  gemm_mf<64, E_BIAS><<<512, 256, 0, stream>>>(
      xH, xM, xL, w16, w16 + 524288, w16 + 1048576, sym_b, nullptr, bF,
      nullptr, nullptr, nullptr, 512, 1024, 1024, 1024, 4);
  l2_split3<<<256, 256, 0, stream>>>(codebook, w16, w16 + 524288,
                                     w16 + 1048576);
  u16 *hpH = a16, *hpM = a16 + 4194304, *hpL = a16 + 8388608;
  l2_split3<<<2048, 256, 0, stream>>>(bF, hpH, hpM, hpL);
  u16 *sH = a16 + 12582912, *sM = a16 + 20971520, *sL = a16 + 29360128;
  gemm_mf<64, E_GUM3><<<1024, 256, 0, stream>>>(
      hpH, hpM, hpL, w16, w16 + 524288, w16 + 1048576, nullptr, gumbel,
      nullptr, sH, sM, sL, 1024, 512, 512, 512, 8);
  softmax3<<<8192, 256, 0, stream>>>(sH, sM, sL);
  tsplit_cb<<<512, 256, 0, stream>>>(codebook, w16, w16 + 524288,
                                     w16 + 1048576);
  gemm_mf<64, E_POS><<<512, 256, 0, stream>>>(
      sH, sM, sL, w16, w16 + 524288, w16 + 1048576, nullptr, pos_enc, h,
      nullptr, nullptr, nullptr, 512, 1024, 1024, 1024, 4);

  // ---- transformer layers ----
  u16 *qkvH = a16, *qkvM = a16 + 12582912, *qkvL = a16 + 25165824;
  u16* w1p = (u16*)(ws_f + 12582912);
  u16* w2p = (u16*)(ws_f + 14155776);
  u16 *pH = a16, *pM = a16 + 8388608, *pL = a16 + 16777216;

  for (int l = 0; l < 4; ++l) {
    const float* inw = attn_in_w + (size_t)l * 1536 * 512;
    const float* inb = attn_in_b + (size_t)l * 1536;
    const float* outw = attn_out_w + (size_t)l * 512 * 512;
    const float* outb = attn_out_b + (size_t)l * 512;
    const float* w1 = ffn_w1 + (size_t)l * 2048 * 512;
    const float* b1 = ffn_b1 + (size_t)l * 2048;
    const float* w2 = ffn_w2 + (size_t)l * 512 * 2048;
    const float* b2 = ffn_b2 + (size_t)l * 512;

    ln_split3<<<2048, 256, 0, stream>>>(h, n1_g + l * 512, n1_b + l * 512,
                                        hnH, hnM, hnL);
    split3_k<<<1024, 256, 0, stream>>>(inw, w16, w16 + 786432, w16 + 1572864,
                                       196608);
    gemm_mf<128, E_QKV3><<<768, 256, 0, stream>>>(
        hnH, hnM, hnL, w16, w16 + 786432, w16 + 1572864, inb, nullptr,
        nullptr, qkvH, qkvM, qkvL, 1536, 512, 512, 512, 12);
    flash_mfma<<<dim3(16, 64), 256, 0, stream>>>(qkvH, qkvM, qkvL, hnH, hnM,
                                                 hnL);
    split3_k<<<256, 256, 0, stream>>>(outw, w16, w16 + 262144, w16 + 524288,
                                      65536);
    gemm_mf<64, E_RES><<<512, 256, 0, stream>>>(
        hnH, hnM, hnL, w16, w16 + 262144, w16 + 524288, outb, h, h, nullptr,
        nullptr, nullptr, 512, 512, 512, 512, 4);
    ln_split3<<<2048, 256, 0, stream>>>(h, n2_g + l * 512, n2_b + l * 512,
                                        hnH, hnM, hnL);
    split3_k<<<1024, 256, 0, stream>>>(w1, w1p, w1p + 1048576, w1p + 2097152,
                                       262144);
    split3_k<<<1024, 256, 0, stream>>>(w2, w2p, w2p + 1048576, w2p + 2097152,
                                       262144);
    for (int c = 0; c < 2; ++c) {
      gemm_mf<128, E_GELU3><<<512, 256, 0, stream>>>(
          hnH, hnM, hnL, w1p + c * 524288, w1p + 1048576 + c * 524288,
          w1p + 2097152 + c * 524288, b1 + c * 1024, nullptr, nullptr, pH, pM,
          pL, 1024, 512, 512, 512, 8);
      if (c == 0) {
        gemm_mf<64, E_RES><<<512, 256, 0, stream>>>(
            pH, pM, pL, w2p + 0, w2p + 1048576, w2p + 2097152, b2, h, h,
            nullptr, nullptr, nullptr, 512, 1024, 1024, 2048, 4);
      } else {
        gemm_mf<64, E_ACC><<<512, 256, 0, stream>>>(
            pH, pM, pL, w2p + 1024, w2p + 1048576 + 1024, w2p + 2097152 + 1024,
            nullptr, nullptr, h, nullptr, nullptr, nullptr, 512, 1024, 1024,
            2048, 4);
      }
    }
  }

  // ---- VQ head (fp32-vector precision anchor) ----
  gemm_f32<64, 128, 32, E_BIAS><<<dim3(4, 128), 256, 0, stream>>>(
      h, q_w, q_b, bF, 8192, 512, 512, nullptr, nullptr);
  ln_l2_f32<<<2048, 256, 0, stream>>>(bF, qln_g, qln_b, bF);
  l2_f32<<<128, 256, 0, stream>>>(patterns, wF);
  gemm_f32<64, 128, 32, E_VQ><<<dim3(4, 128), 256, 0, stream>>>(
      bF, wF, nullptr, logits, 8192, 512, 512, epoch, tot);
  vq_finalize<<<2048, 256, 0, stream>>>(logits, patterns, emb, assign, idxf);
}

// Round 9
// 2713.092 us; speedup vs baseline: 11.4876x; 1.0168x over previous
//
#include <hip/hip_runtime.h>

#define DEV __device__ __forceinline__

typedef unsigned short u16;
typedef unsigned int u32;
typedef __attribute__((ext_vector_type(8))) short bf8_t;   // 8 bf16 (4 VGPR)
typedef __attribute__((ext_vector_type(4))) float f4_t;

constexpr int T_SEQ = 1024;
constexpr int DMODEL = 512;
constexpr int NPAT = 512;

// ---------------- epilogue modes ----------------
enum {
  E_BIAS = 0,
  E_VQ = 5,
  E_RES = 6,
  E_ACC = 7,
  E_POS = 8,
  E_GUM3 = 9,
  E_GELU3 = 10,
  E_QKV3 = 11
};

// ---------------- bf16 triple-split helpers ----------------
DEV u16 f2bf(float x) {
  u32 u = __float_as_uint(x);
  u32 r = u + 0x7FFFu + ((u >> 16) & 1u);
  return (u16)(r >> 16);
}
DEV float bf2f(u16 h) { return __uint_as_float((u32)h << 16); }
DEV void split3(float x, u16& h, u16& m, u16& l) {
  h = f2bf(x);
  float r1 = x - bf2f(h);
  m = f2bf(r1);
  float r2 = r1 - bf2f(m);
  l = f2bf(r2);
}

DEV f4_t mf16(bf8_t a, bf8_t b, f4_t c) {
  return __builtin_amdgcn_mfma_f32_16x16x32_bf16(a, b, c, 0, 0, 0);
}
// 6-product triple-split accumulate (err ~2^-24)
DEV f4_t prod6(bf8_t ah, bf8_t am, bf8_t al, bf8_t bh, bf8_t bm, bf8_t bl,
               f4_t c) {
  c = mf16(ah, bh, c);
  c = mf16(ah, bm, c);
  c = mf16(am, bh, c);
  c = mf16(ah, bl, c);
  c = mf16(am, bm, c);
  c = mf16(al, bh, c);
  return c;
}

// async global->LDS, 16B per lane; LDS dest = base + lane*16 (wave-uniform base)
typedef const __attribute__((address_space(1))) unsigned char* gas_t;
typedef __attribute__((address_space(3))) unsigned char* las_t;
DEV void gload16(const u16* g, u16* l) {
  __builtin_amdgcn_global_load_lds((gas_t)(const void*)g, (las_t)(void*)l, 16,
                                   0, 0);
}

// ---------------- MFMA GEMM, triple-bf16 split (fp32-accurate) ---------------
// C[M,N] = A[M,K]*B[N,K]^T via 6 bf16 products. Verified R6/R7.
// Staging via global_load_lds (pre-swizzled source, linear LDS dest).
// 1-D grid + bijective XCD swizzle (consecutive logical blocks share A panel).
template <int BM, int EPI>
__global__ __launch_bounds__(256, 2) void gemm_mf(
    const u16* __restrict__ Ah, const u16* __restrict__ Am,
    const u16* __restrict__ Al, const u16* __restrict__ Bh,
    const u16* __restrict__ Bm, const u16* __restrict__ Bl,
    const float* __restrict__ bias, const float* __restrict__ res,
    float* __restrict__ Cf, u16* __restrict__ Ch, u16* __restrict__ Cm,
    u16* __restrict__ Cl, int N, int KK, int lda, int ldb, int gx) {
  constexpr int MT = BM / 32;  // m-tiles per wave
  __shared__ __align__(16) u16 AsH[BM][4][8], AsM[BM][4][8], AsL[BM][4][8];
  __shared__ __align__(16) u16 BsH[128][4][8], BsM[128][4][8], BsL[128][4][8];
  const int tid = threadIdx.x;
  const int w = tid >> 6, lane = tid & 63;
  const int wy = w >> 1, wx = w & 1;
  const int lr = lane & 15, lg = lane >> 4;

  // bijective XCD swizzle (all grids divisible by 8)
  const int nwg = gridDim.x;
  const int bid = blockIdx.x;
  const int qq = nwg >> 3;
  const int wg = (bid & 7) * qq + (bid >> 3);
  const int by = wg / gx, bx = wg % gx;
  const int bm = by * BM, bn = bx * 128;

  const int rowl = lane >> 2, slot4 = lane & 3;  // per-lane stage coords

  f4_t acc[MT][4];
#pragma unroll
  for (int mt = 0; mt < MT; ++mt)
#pragma unroll
    for (int nt = 0; nt < 4; ++nt) acc[mt][nt] = (f4_t){0.f, 0.f, 0.f, 0.f};

  for (int k0 = 0; k0 < KK; k0 += 32) {
    if (k0) __syncthreads();
    // ---- A planes: 3*(BM/16) 1KB chunks, round-robin over waves ----
#pragma unroll
    for (int it = 0; it < 3 * (BM / 16) / 4; ++it) {
      const int f = w + 4 * it;
      const int plane = f / (BM / 16);
      const int ch = f % (BM / 16);
      const int row = ch * 16 + rowl;
      const int kp = slot4 ^ ((row >> 1) & 3);
      const size_t g = (size_t)(bm + row) * lda + k0 + kp * 8;
      if (plane == 0)
        gload16(&Ah[g], &AsH[0][0][0] + ch * 512);
      else if (plane == 1)
        gload16(&Am[g], &AsM[0][0][0] + ch * 512);
      else
        gload16(&Al[g], &AsL[0][0][0] + ch * 512);
    }
    // ---- B planes: 24 chunks ----
#pragma unroll
    for (int it = 0; it < 6; ++it) {
      const int f = w + 4 * it;
      const int plane = f >> 3;
      const int ch = f & 7;
      const int row = ch * 16 + rowl;
      const int kp = slot4 ^ ((row >> 1) & 3);
      const size_t g = (size_t)(bn + row) * ldb + k0 + kp * 8;
      if (plane == 0)
        gload16(&Bh[g], &BsH[0][0][0] + ch * 512);
      else if (plane == 1)
        gload16(&Bm[g], &BsM[0][0][0] + ch * 512);
      else
        gload16(&Bl[g], &BsL[0][0][0] + ch * 512);
    }
    __syncthreads();

    bf8_t fah[MT], fam[MT], fal[MT], fbh[4], fbm[4], fbl[4];
#pragma unroll
    for (int mt = 0; mt < MT; ++mt) {
      int row = wy * (BM / 2) + mt * 16 + lr;
      int slot = lg ^ ((row >> 1) & 3);
      fah[mt] = *(const bf8_t*)&AsH[row][slot][0];
      fam[mt] = *(const bf8_t*)&AsM[row][slot][0];
      fal[mt] = *(const bf8_t*)&AsL[row][slot][0];
    }
#pragma unroll
    for (int nt = 0; nt < 4; ++nt) {
      int col = wx * 64 + nt * 16 + lr;
      int slot = lg ^ ((col >> 1) & 3);
      fbh[nt] = *(const bf8_t*)&BsH[col][slot][0];
      fbm[nt] = *(const bf8_t*)&BsM[col][slot][0];
      fbl[nt] = *(const bf8_t*)&BsL[col][slot][0];
    }
#pragma unroll
    for (int mt = 0; mt < MT; ++mt)
#pragma unroll
      for (int nt = 0; nt < 4; ++nt)
        acc[mt][nt] = prod6(fah[mt], fam[mt], fal[mt], fbh[nt], fbm[nt],
                            fbl[nt], acc[mt][nt]);
  }

  // ---- epilogue (C frag: col = lane&15, row = 4*(lane>>4)+i) ----
  float bv[4];
  if constexpr (EPI == E_BIAS || EPI == E_RES || EPI == E_GELU3 ||
                EPI == E_QKV3) {
#pragma unroll
    for (int nt = 0; nt < 4; ++nt) bv[nt] = bias[bn + wx * 64 + nt * 16 + lr];
  }
#pragma unroll
  for (int mt = 0; mt < MT; ++mt)
#pragma unroll
    for (int nt = 0; nt < 4; ++nt) {
      const int c = bn + wx * 64 + nt * 16 + lr;
#pragma unroll
      for (int i = 0; i < 4; ++i) {
        const int m = bm + wy * (BM / 2) + mt * 16 + 4 * lg + i;
        const size_t idx = (size_t)m * N + c;
        float v = acc[mt][nt][i];
        if constexpr (EPI == E_BIAS) {
          Cf[idx] = v + bv[nt];
        } else if constexpr (EPI == E_RES) {
          Cf[idx] = v + bv[nt] + res[idx];
        } else if constexpr (EPI == E_ACC) {
          Cf[idx] += v;
        } else if constexpr (EPI == E_POS) {
          Cf[idx] = v + res[(size_t)(m & 1023) * N + c];
        } else if constexpr (EPI == E_GUM3) {
          float t = 4.0f * v + 2.0f * res[idx];
          u16 h2, m2, l2;
          split3(t, h2, m2, l2);
          Ch[idx] = h2;
          Cm[idx] = m2;
          Cl[idx] = l2;
        } else if constexpr (EPI == E_GELU3) {
          float t = v + bv[nt];
          float g = 0.5f * t * (1.0f + erff(t * 0.7071067811865476f));
          u16 h2, m2, l2;
          split3(g, h2, m2, l2);
          Ch[idx] = h2;
          Cm[idx] = m2;
          Cl[idx] = l2;
        } else if constexpr (EPI == E_QKV3) {
          float t = v + bv[nt];
          u16 h2, m2, l2;
          split3(t, h2, m2, l2);
          size_t o;
          if (c < 512) {
            o = (size_t)m * 512 + c;                       // Q [B,T,512]
          } else if (c < 1024) {
            o = 4194304 + (size_t)m * 512 + (c - 512);     // K [B,T,512]
          } else {
            int cc = c - 1024, hh2 = cc >> 6, dd = cc & 63;
            int bb2 = m >> 10, tt = m & 1023;
            o = 8388608 +
                (((size_t)(bb2 * 8 + hh2) * 64 + dd) << 10) + tt;  // Vt
          }
          Ch[o] = h2;
          Cm[o] = m2;
          Cl[o] = l2;
        }
      }
    }
}

// ---------------- MFMA flash attention (triple-split, fp32-grade) ------------
// grid (16, 64): qt 0..15 (64 q-rows/block), bh = b*8+hh. 4 waves, each owns
// 16 q-rows. K rows-major [B,T,512]; V pre-transposed [B,8,64,T].
// K/V staging via global_load_lds. P ALIASES the K tile (dead after QK^T):
// LDS 48KB -> 3 blocks/CU. P reads are wave-private (own 16 rows), so only
// one extra barrier (after QK^T) is needed before the P overwrite.
__global__ __launch_bounds__(256) void flash_mfma(
    const u16* __restrict__ QKVh, const u16* __restrict__ QKVm,
    const u16* __restrict__ QKVl, u16* __restrict__ Oh, u16* __restrict__ Om,
    u16* __restrict__ Ol) {
  __shared__ __align__(16) u16 KP[3][64][8][8];  // K tile, then P tile
  __shared__ __align__(16) u16 Vs[3][64][8][8];
  const int tid = threadIdx.x;
  const int w = tid >> 6, lane = tid & 63;
  const int lr = lane & 15, lg = lane >> 4;
  const int qt = blockIdx.x, bh = blockIdx.y;
  const int b = bh >> 3, hh = bh & 7;

  const u16* Qh = QKVh;
  const u16* Qm = QKVm;
  const u16* Ql = QKVl;
  const u16* Kh = QKVh + 4194304;
  const u16* Km = QKVm + 4194304;
  const u16* Kl = QKVl + 4194304;
  const u16* Vh = QKVh + 8388608;
  const u16* Vm = QKVm + 8388608;
  const u16* Vl = QKVl + 8388608;

  // Q fragments (A-op: m = lr, k-packet = lg), hoisted for all kt
  bf8_t qf[2][3];
  {
    size_t g =
        ((size_t)(b * 1024 + qt * 64 + w * 16 + lr)) * 512 + hh * 64 + lg * 8;
    qf[0][0] = *(const bf8_t*)&Qh[g];
    qf[0][1] = *(const bf8_t*)&Qm[g];
    qf[0][2] = *(const bf8_t*)&Ql[g];
    qf[1][0] = *(const bf8_t*)&Qh[g + 32];
    qf[1][1] = *(const bf8_t*)&Qm[g + 32];
    qf[1][2] = *(const bf8_t*)&Ql[g + 32];
  }

  f4_t oacc[4];
#pragma unroll
  for (int nt = 0; nt < 4; ++nt) oacc[nt] = (f4_t){0.f, 0.f, 0.f, 0.f};
  float mrun[4], lrun[4];
#pragma unroll
  for (int i = 0; i < 4; ++i) {
    mrun[i] = -__builtin_huge_valf();
    lrun[i] = 0.0f;
  }

  const int rowl8 = lane >> 3, slot8 = lane & 7;  // stage coords (8 rows/chunk)

  for (int kt = 0; kt < 16; ++kt) {
    __syncthreads();  // prior PV done reading Vs + KP(P)
    // ---- stage K tile + Vt tile via global_load_lds: 48 x 1KB chunks ----
#pragma unroll
    for (int it = 0; it < 6; ++it) {
      const int f = w + 4 * it;
      const int plane = f >> 3, ch = f & 7;
      const int row = ch * 8 + rowl8;
      const int kp = slot8 ^ (row & 7);
      const size_t gk =
          ((size_t)(b * 1024 + kt * 64 + row)) * 512 + hh * 64 + kp * 8;
      if (plane == 0)
        gload16(&Kh[gk], &KP[0][0][0][0] + ch * 512);
      else if (plane == 1)
        gload16(&Km[gk], &KP[1][0][0][0] + ch * 512);
      else
        gload16(&Kl[gk], &KP[2][0][0][0] + ch * 512);
    }
#pragma unroll
    for (int it = 0; it < 6; ++it) {
      const int f = w + 4 * it;
      const int plane = f >> 3, ch = f & 7;
      const int row = ch * 8 + rowl8;
      const int kp = slot8 ^ (row & 7);
      const size_t gv =
          ((size_t)((b * 8 + hh) * 64 + row)) * 1024 + kt * 64 + kp * 8;
      if (plane == 0)
        gload16(&Vh[gv], &Vs[0][0][0][0] + ch * 512);
      else if (plane == 1)
        gload16(&Vm[gv], &Vs[1][0][0][0] + ch * 512);
      else
        gload16(&Vl[gv], &Vs[2][0][0][0] + ch * 512);
    }
    __syncthreads();

    // ---- S = Q K^T : 4 n-tiles x 2 k-slices x 6 products ----
    f4_t s[4];
#pragma unroll
    for (int nt = 0; nt < 4; ++nt) {
      s[nt] = (f4_t){0.f, 0.f, 0.f, 0.f};
      const int col = nt * 16 + lr;
#pragma unroll
      for (int ks = 0; ks < 2; ++ks) {
        int slot = (ks * 4 + lg) ^ (col & 7);
        bf8_t kh = *(const bf8_t*)&KP[0][col][slot][0];
        bf8_t km = *(const bf8_t*)&KP[1][col][slot][0];
        bf8_t kl = *(const bf8_t*)&KP[2][col][slot][0];
        s[nt] = prod6(qf[ks][0], qf[ks][1], qf[ks][2], kh, km, kl, s[nt]);
      }
    }

    // ---- online softmax (row = 4*lg+i; reduce over lr via shfl) ----
#pragma unroll
    for (int i = 0; i < 4; ++i) {
      float rm = -__builtin_huge_valf();
#pragma unroll
      for (int nt = 0; nt < 4; ++nt) {
        s[nt][i] *= 0.125f;
        rm = fmaxf(rm, s[nt][i]);
      }
      rm = fmaxf(rm, __shfl_xor(rm, 1));
      rm = fmaxf(rm, __shfl_xor(rm, 2));
      rm = fmaxf(rm, __shfl_xor(rm, 4));
      rm = fmaxf(rm, __shfl_xor(rm, 8));
      float mnew = fmaxf(mrun[i], rm);
      float alpha = __expf(mrun[i] - mnew);
      float rs = 0.0f;
#pragma unroll
      for (int nt = 0; nt < 4; ++nt) {
        float p = __expf(s[nt][i] - mnew);
        s[nt][i] = p;
        rs += p;
      }
      rs += __shfl_xor(rs, 1);
      rs += __shfl_xor(rs, 2);
      rs += __shfl_xor(rs, 4);
      rs += __shfl_xor(rs, 8);
      lrun[i] = lrun[i] * alpha + rs;
      mrun[i] = mnew;
#pragma unroll
      for (int nt = 0; nt < 4; ++nt) oacc[nt][i] *= alpha;
    }

    __syncthreads();  // all waves done reading K tile -> safe to overwrite

    // ---- P -> KP (wave-private rows, 3 planes, swizzled) ----
#pragma unroll
    for (int nt = 0; nt < 4; ++nt)
#pragma unroll
      for (int i = 0; i < 4; ++i) {
        int qrow = w * 16 + 4 * lg + i;
        int kv = nt * 16 + lr;
        int kp = kv >> 3, j = kv & 7;
        int slot = kp ^ (qrow & 7);
        u16 h2, m2, l2;
        split3(s[nt][i], h2, m2, l2);
        KP[0][qrow][slot][j] = h2;
        KP[1][qrow][slot][j] = m2;
        KP[2][qrow][slot][j] = l2;
      }

    // ---- O += P V (A = own P rows, B = Vt cols) ----
    bf8_t pf[2][3];
#pragma unroll
    for (int ks = 0; ks < 2; ++ks) {
      int row = w * 16 + lr;
      int slot = (ks * 4 + lg) ^ (row & 7);
      pf[ks][0] = *(const bf8_t*)&KP[0][row][slot][0];
      pf[ks][1] = *(const bf8_t*)&KP[1][row][slot][0];
      pf[ks][2] = *(const bf8_t*)&KP[2][row][slot][0];
    }
#pragma unroll
    for (int ntd = 0; ntd < 4; ++ntd) {
      const int col = ntd * 16 + lr;
#pragma unroll
      for (int ks = 0; ks < 2; ++ks) {
        int slot = (ks * 4 + lg) ^ (col & 7);
        bf8_t vh = *(const bf8_t*)&Vs[0][col][slot][0];
        bf8_t vm = *(const bf8_t*)&Vs[1][col][slot][0];
        bf8_t vl = *(const bf8_t*)&Vs[2][col][slot][0];
        oacc[ntd] =
            prod6(pf[ks][0], pf[ks][1], pf[ks][2], vh, vm, vl, oacc[ntd]);
      }
    }
  }

  // ---- epilogue: normalize, split3, store planes [B,T,512] ----
#pragma unroll
  for (int i = 0; i < 4; ++i) {
    float inv = 1.0f / lrun[i];
    int t = qt * 64 + w * 16 + 4 * lg + i;
#pragma unroll
    for (int ntd = 0; ntd < 4; ++ntd) {
      int d = hh * 64 + ntd * 16 + lr;
      size_t idx = ((size_t)(b * 1024 + t)) * 512 + d;
      u16 h2, m2, l2;
      split3(oacc[ntd][i] * inv, h2, m2, l2);
      Oh[idx] = h2;
      Om[idx] = m2;
      Ol[idx] = l2;
    }
  }
}

// ---------------- fp32 vector GEMM (VQ-head precision anchor) ----------------
template <int BM, int BN, int WR, int EPI>
__global__ __launch_bounds__((BM / WR) * (BN / 64) * 64) void gemm_f32(
    const float* __restrict__ A, const float* __restrict__ Bmat,
    const float* __restrict__ bias, float* __restrict__ C, int M, int N, int K,
    const int* __restrict__ ep, const int* __restrict__ tot) {
  constexpr int BK = 16;
  constexpr int WN = BN / 64;
  constexpr int NW = (BM / WR) * WN;
  constexpr int NT = NW * 64;
  constexpr int RM = WR / 8;
  __shared__ __align__(16) float As[BK][BM + 4];
  __shared__ __align__(16) float Bs[BK][BN + 4];
  const int tid = threadIdx.x;
  const int w = tid >> 6, lane = tid & 63;
  const int wy = w / WN, wx = w % WN;
  const int ly = lane >> 3, lx = lane & 7;
  const int bm = blockIdx.y * BM;
  const int bn = blockIdx.x * BN;
  const int rbase = wy * WR + ly * RM;

  float acc[RM][8];
#pragma unroll
  for (int i = 0; i < RM; ++i)
#pragma unroll
    for (int j = 0; j < 8; ++j) acc[i][j] = 0.0f;

  for (int k0 = 0; k0 < K; k0 += BK) {
#pragma unroll
    for (int i = 0; i < (BM * BK / 4) / NT; ++i) {
      int idx = tid + i * NT;
      int r = idx >> 2, c4 = (idx & 3) << 2;
      const float4 v = *(const float4*)(A + (size_t)(bm + r) * K + k0 + c4);
      As[c4 + 0][r] = v.x;
      As[c4 + 1][r] = v.y;
      As[c4 + 2][r] = v.z;
      As[c4 + 3][r] = v.w;
    }
#pragma unroll
    for (int i = 0; i < (BN * BK / 4) / NT; ++i) {
      int idx = tid + i * NT;
      int r = idx >> 2, c4 = (idx & 3) << 2;
      const float4 v = *(const float4*)(Bmat + (size_t)(bn + r) * K + k0 + c4);
      Bs[c4 + 0][r] = v.x;
      Bs[c4 + 1][r] = v.y;
      Bs[c4 + 2][r] = v.z;
      Bs[c4 + 3][r] = v.w;
    }
    __syncthreads();
#pragma unroll
    for (int k = 0; k < BK; ++k) {
      float a[RM], b[8];
#pragma unroll
      for (int r4 = 0; r4 < RM; r4 += 4)
        *(float4*)&a[r4] = *(const float4*)&As[k][rbase + r4];
      *(float4*)&b[0] = *(const float4*)&Bs[k][wx * 64 + lx * 8];
      *(float4*)&b[4] = *(const float4*)&Bs[k][wx * 64 + lx * 8 + 4];
#pragma unroll
      for (int i = 0; i < RM; ++i)
#pragma unroll
        for (int j = 0; j < 8; ++j) acc[i][j] = fmaf(a[i], b[j], acc[i][j]);
    }
    __syncthreads();
  }

  const int ncol = bn + wx * 64 + lx * 8;
  float bb[8];
  if constexpr (EPI == E_BIAS) {
    *(float4*)&bb[0] = *(const float4*)(bias + ncol);
    *(float4*)&bb[4] = *(const float4*)(bias + ncol + 4);
  }
  float invt = 1.0f;
  if constexpr (EPI == E_VQ) {
    float t = 1.0f - 0.5f * (float)ep[0] / (float)tot[0];
    invt = 1.0f / fmaxf(0.5f, t);
  }
#pragma unroll
  for (int i = 0; i < RM; ++i) {
    const int m = bm + rbase + i;
    float o[8];
#pragma unroll
    for (int j = 0; j < 8; ++j) o[j] = acc[i][j];
    if constexpr (EPI == E_BIAS) {
#pragma unroll
      for (int j = 0; j < 8; ++j) o[j] += bb[j];
    } else if constexpr (EPI == E_VQ) {
#pragma unroll
      for (int j = 0; j < 8; ++j) o[j] *= invt;
    }
    *(float4*)(C + (size_t)m * N + ncol) = *(float4*)&o[0];
    *(float4*)(C + (size_t)m * N + ncol + 4) = *(float4*)&o[4];
  }
}

// ---------------- row kernels ----------------
DEV float wave_sum(float v) {
#pragma unroll
  for (int off = 1; off < 64; off <<= 1) v += __shfl_xor(v, off);
  return v;
}

DEV void store8_split3(u16* H, u16* M, u16* L, size_t base, const float* t) {
  u16 vh[8], vm[8], vl[8];
#pragma unroll
  for (int j = 0; j < 8; ++j) split3(t[j], vh[j], vm[j], vl[j]);
  *(ushort4*)&H[base] = make_ushort4(vh[0], vh[1], vh[2], vh[3]);
  *(ushort4*)&H[base + 4] = make_ushort4(vh[4], vh[5], vh[6], vh[7]);
  *(ushort4*)&M[base] = make_ushort4(vm[0], vm[1], vm[2], vm[3]);
  *(ushort4*)&M[base + 4] = make_ushort4(vm[4], vm[5], vm[6], vm[7]);
  *(ushort4*)&L[base] = make_ushort4(vl[0], vl[1], vl[2], vl[3]);
  *(ushort4*)&L[base + 4] = make_ushort4(vl[4], vl[5], vl[6], vl[7]);
}

__global__ __launch_bounds__(256) void ln_split3(const float* __restrict__ x,
                                                 const float* __restrict__ g,
                                                 const float* __restrict__ b,
                                                 u16* __restrict__ yh,
                                                 u16* __restrict__ ym,
                                                 u16* __restrict__ yl) {
  const int row = blockIdx.x * 4 + (threadIdx.x >> 6);
  const int lane = threadIdx.x & 63;
  const float* xr = x + (size_t)row * DMODEL;
  float v[8];
  *(float4*)&v[0] = *(const float4*)(xr + lane * 8);
  *(float4*)&v[4] = *(const float4*)(xr + lane * 8 + 4);
  float s = 0.0f;
#pragma unroll
  for (int j = 0; j < 8; ++j) s += v[j];
  s = wave_sum(s);
  float mean = s * (1.0f / 512.0f);
  float s2 = 0.0f;
#pragma unroll
  for (int j = 0; j < 8; ++j) {
    float d = v[j] - mean;
    s2 += d * d;
  }
  s2 = wave_sum(s2);
  float rstd = 1.0f / sqrtf(s2 * (1.0f / 512.0f) + 1e-5f);
  float gg[8], bv[8];
  *(float4*)&gg[0] = *(const float4*)(g + lane * 8);
  *(float4*)&gg[4] = *(const float4*)(g + lane * 8 + 4);
  *(float4*)&bv[0] = *(const float4*)(b + lane * 8);
  *(float4*)&bv[4] = *(const float4*)(b + lane * 8 + 4);
  float t[8];
#pragma unroll
  for (int j = 0; j < 8; ++j) t[j] = (v[j] - mean) * rstd * gg[j] + bv[j];
  store8_split3(yh, ym, yl, (size_t)row * DMODEL + lane * 8, t);
}

__global__ __launch_bounds__(256) void ln_l2_f32(const float* __restrict__ x,
                                                 const float* __restrict__ g,
                                                 const float* __restrict__ b,
                                                 float* __restrict__ y) {
  const int row = blockIdx.x * 4 + (threadIdx.x >> 6);
  const int lane = threadIdx.x & 63;
  const float* xr = x + (size_t)row * DMODEL;
  float v[8];
  *(float4*)&v[0] = *(const float4*)(xr + lane * 8);
  *(float4*)&v[4] = *(const float4*)(xr + lane * 8 + 4);
  float s = 0.0f;
#pragma unroll
  for (int j = 0; j < 8; ++j) s += v[j];
  s = wave_sum(s);
  float mean = s * (1.0f / 512.0f);
  float s2 = 0.0f;
#pragma unroll
  for (int j = 0; j < 8; ++j) {
    float d = v[j] - mean;
    s2 += d * d;
  }
  s2 = wave_sum(s2);
  float rstd = 1.0f / sqrtf(s2 * (1.0f / 512.0f) + 1e-5f);
  float gg[8], bv[8];
  *(float4*)&gg[0] = *(const float4*)(g + lane * 8);
  *(float4*)&gg[4] = *(const float4*)(g + lane * 8 + 4);
  *(float4*)&bv[0] = *(const float4*)(b + lane * 8);
  *(float4*)&bv[4] = *(const float4*)(b + lane * 8 + 4);
  float t[8];
#pragma unroll
  for (int j = 0; j < 8; ++j) t[j] = (v[j] - mean) * rstd * gg[j] + bv[j];
  float n2 = 0.0f;
#pragma unroll
  for (int j = 0; j < 8; ++j) n2 += t[j] * t[j];
  n2 = wave_sum(n2);
  float den = fmaxf(sqrtf(n2), 1e-12f);
#pragma unroll
  for (int j = 0; j < 8; ++j) t[j] /= den;
  float* yr = y + (size_t)row * DMODEL;
  *(float4*)(yr + lane * 8) = *(float4*)&t[0];
  *(float4*)(yr + lane * 8 + 4) = *(float4*)&t[4];
}

__global__ __launch_bounds__(256) void l2_split3(const float* __restrict__ x,
                                                 u16* __restrict__ yh,
                                                 u16* __restrict__ ym,
                                                 u16* __restrict__ yl) {
  const int row = blockIdx.x * 4 + (threadIdx.x >> 6);
  const int lane = threadIdx.x & 63;
  const float* xr = x + (size_t)row * DMODEL;
  float v[8];
  *(float4*)&v[0] = *(const float4*)(xr + lane * 8);
  *(float4*)&v[4] = *(const float4*)(xr + lane * 8 + 4);
  float n2 = 0.0f;
#pragma unroll
  for (int j = 0; j < 8; ++j) n2 += v[j] * v[j];
  n2 = wave_sum(n2);
  float den = fmaxf(sqrtf(n2), 1e-12f);
#pragma unroll
  for (int j = 0; j < 8; ++j) v[j] /= den;
  store8_split3(yh, ym, yl, (size_t)row * DMODEL + lane * 8, v);
}

__global__ __launch_bounds__(256) void l2_f32(const float* __restrict__ x,
                                              float* __restrict__ y) {
  const int row = blockIdx.x * 4 + (threadIdx.x >> 6);
  const int lane = threadIdx.x & 63;
  const float* xr = x + (size_t)row * DMODEL;
  float v[8];
  *(float4*)&v[0] = *(const float4*)(xr + lane * 8);
  *(float4*)&v[4] = *(const float4*)(xr + lane * 8 + 4);
  float n2 = 0.0f;
#pragma unroll
  for (int j = 0; j < 8; ++j) n2 += v[j] * v[j];
  n2 = wave_sum(n2);
  float den = fmaxf(sqrtf(n2), 1e-12f);
#pragma unroll
  for (int j = 0; j < 8; ++j) v[j] /= den;
  float* yr = y + (size_t)row * DMODEL;
  *(float4*)(yr + lane * 8) = *(float4*)&v[0];
  *(float4*)(yr + lane * 8 + 4) = *(float4*)&v[4];
}

__global__ __launch_bounds__(256) void softmax3(u16* __restrict__ H,
                                                u16* __restrict__ M,
                                                u16* __restrict__ L) {
  const int row = blockIdx.x;
  const int tid = threadIdx.x;
  const size_t base = (size_t)row * 1024 + tid * 4;
  ushort4 qh = *(const ushort4*)&H[base];
  ushort4 qm = *(const ushort4*)&M[base];
  ushort4 ql = *(const ushort4*)&L[base];
  float v0 = bf2f(qh.x) + bf2f(qm.x) + bf2f(ql.x);
  float v1 = bf2f(qh.y) + bf2f(qm.y) + bf2f(ql.y);
  float v2 = bf2f(qh.z) + bf2f(qm.z) + bf2f(ql.z);
  float v3 = bf2f(qh.w) + bf2f(qm.w) + bf2f(ql.w);
  float mx = fmaxf(fmaxf(v0, v1), fmaxf(v2, v3));
#pragma unroll
  for (int off = 1; off < 64; off <<= 1) mx = fmaxf(mx, __shfl_xor(mx, off));
  __shared__ float red[4];
  const int wv = tid >> 6;
  if ((tid & 63) == 0) red[wv] = mx;
  __syncthreads();
  mx = fmaxf(fmaxf(red[0], red[1]), fmaxf(red[2], red[3]));
  float e0 = __expf(v0 - mx), e1 = __expf(v1 - mx), e2 = __expf(v2 - mx),
        e3 = __expf(v3 - mx);
  float s = e0 + e1 + e2 + e3;
#pragma unroll
  for (int off = 1; off < 64; off <<= 1) s += __shfl_xor(s, off);
  __syncthreads();
  if ((tid & 63) == 0) red[wv] = s;
  __syncthreads();
  s = red[0] + red[1] + red[2] + red[3];
  float inv = 1.0f / s;
  u16 ah[4], am[4], al[4];
  split3(e0 * inv, ah[0], am[0], al[0]);
  split3(e1 * inv, ah[1], am[1], al[1]);
  split3(e2 * inv, ah[2], am[2], al[2]);
  split3(e3 * inv, ah[3], am[3], al[3]);
  *(ushort4*)&H[base] = make_ushort4(ah[0], ah[1], ah[2], ah[3]);
  *(ushort4*)&M[base] = make_ushort4(am[0], am[1], am[2], am[3]);
  *(ushort4*)&L[base] = make_ushort4(al[0], al[1], al[2], al[3]);
}

__global__ __launch_bounds__(256) void split3_k(const float* __restrict__ src,
                                                u16* __restrict__ H,
                                                u16* __restrict__ M,
                                                u16* __restrict__ L, int n4) {
  for (int e = blockIdx.x * 256 + threadIdx.x; e < n4; e += gridDim.x * 256) {
    float4 v = *(const float4*)(src + (size_t)e * 4);
    u16 ah[4], am[4], al[4];
    split3(v.x, ah[0], am[0], al[0]);
    split3(v.y, ah[1], am[1], al[1]);
    split3(v.z, ah[2], am[2], al[2]);
    split3(v.w, ah[3], am[3], al[3]);
    *(ushort4*)&H[(size_t)e * 4] = make_ushort4(ah[0], ah[1], ah[2], ah[3]);
    *(ushort4*)&M[(size_t)e * 4] = make_ushort4(am[0], am[1], am[2], am[3]);
    *(ushort4*)&L[(size_t)e * 4] = make_ushort4(al[0], al[1], al[2], al[3]);
  }
}

__global__ __launch_bounds__(256) void tsplit_cb(const float* __restrict__ cb,
                                                 u16* __restrict__ th,
                                                 u16* __restrict__ tm,
                                                 u16* __restrict__ tl) {
  const int c = blockIdx.x;
  const int t = threadIdx.x;
  u16 ah[4], am[4], al[4];
#pragma unroll
  for (int j = 0; j < 4; ++j) {
    float v = cb[(size_t)(4 * t + j) * 512 + c];
    split3(v, ah[j], am[j], al[j]);
  }
  const size_t base = (size_t)c * 1024 + 4 * t;
  *(ushort4*)&th[base] = make_ushort4(ah[0], ah[1], ah[2], ah[3]);
  *(ushort4*)&tm[base] = make_ushort4(am[0], am[1], am[2], am[3]);
  *(ushort4*)&tl[base] = make_ushort4(al[0], al[1], al[2], al[3]);
}

__global__ __launch_bounds__(256) void vq_finalize(
    const float* __restrict__ logits, const float* __restrict__ patterns,
    float* __restrict__ emb, float* __restrict__ assign,
    float* __restrict__ idxf) {
  const int row = blockIdx.x * 4 + (threadIdx.x >> 6);
  const int lane = threadIdx.x & 63;
  const float* lr = logits + (size_t)row * NPAT;
  float best = -__builtin_huge_valf();
  int bi = 0;
#pragma unroll
  for (int jj = 0; jj < 8; ++jj) {
    int j = lane + jj * 64;
    float v = lr[j];
    if (v > best) {
      best = v;
      bi = j;
    }
  }
#pragma unroll
  for (int off = 1; off < 64; off <<= 1) {
    float ob = __shfl_xor(best, off);
    int oi = __shfl_xor(bi, off);
    if (ob > best || (ob == best && oi < bi)) {
      best = ob;
      bi = oi;
    }
  }
  const float* pr = patterns + (size_t)bi * DMODEL;
#pragma unroll
  for (int g = 0; g < 2; ++g) {
    int c = lane * 8 + g * 4;
    float4 pv = *(const float4*)(pr + c);
    *(float4*)(emb + (size_t)row * DMODEL + c) = pv;
    float4 av;
    av.x = (c + 0 == bi) ? 1.0f : 0.0f;
    av.y = (c + 1 == bi) ? 1.0f : 0.0f;
    av.z = (c + 2 == bi) ? 1.0f : 0.0f;
    av.w = (c + 3 == bi) ? 1.0f : 0.0f;
    *(float4*)(assign + (size_t)row * NPAT + c) = av;
  }
  if (lane == 0) idxf[row] = (float)bi;
}

// ---------------- host launch ----------------
extern "C" void kernel_launch(void* const* d_in, const int* in_sizes, int n_in,
                              void* d_out, int out_size, void* d_ws,
                              size_t ws_size, hipStream_t stream) {
  (void)in_sizes;
  (void)n_in;
  (void)out_size;
  (void)ws_size;
  const float* x = (const float*)d_in[0];
  const float* gumbel = (const float*)d_in[1];
  const float* sym_w = (const float*)d_in[2];
  const float* sym_b = (const float*)d_in[3];
  const float* codebook = (const float*)d_in[4];
  const float* pos_enc = (const float*)d_in[5];
  const float* attn_in_w = (const float*)d_in[6];
  const float* attn_in_b = (const float*)d_in[7];
  const float* attn_out_w = (const float*)d_in[8];
  const float* attn_out_b = (const float*)d_in[9];
  const float* n1_g = (const float*)d_in[10];
  const float* n1_b = (const float*)d_in[11];
  const float* n2_g = (const float*)d_in[12];
  const float* n2_b = (const float*)d_in[13];
  const float* ffn_w1 = (const float*)d_in[14];
  const float* ffn_b1 = (const float*)d_in[15];
  const float* ffn_w2 = (const float*)d_in[16];
  const float* ffn_b2 = (const float*)d_in[17];
  const float* q_w = (const float*)d_in[18];
  const float* q_b = (const float*)d_in[19];
  const float* qln_g = (const float*)d_in[20];
  const float* qln_b = (const float*)d_in[21];
  const float* patterns = (const float*)d_in[22];
  const int* epoch = (const int*)d_in[23];
  const int* tot = (const int*)d_in[24];

  float* out = (float*)d_out;
  float* emb = out;               // [8192,512]
  float* assign = out + 4194304;  // [8192,512]
  float* logits = out + 8388608;  // [8192,512]
  float* h = out + 12582912;      // [8192,512]
  float* idxf = out + 16777216;   // [8192]

  float* ws_f = (float*)d_ws;
  // A region @0 (18.87M floats = 37.75M u16)
  u16* a16 = (u16*)ws_f;
  // B region @18.87M floats (6.29M floats = 12.58M u16)
  float* bF = ws_f + 18874368;
  u16* b16 = (u16*)bF;
  u16 *hnH = b16, *hnM = b16 + 4194304, *hnL = b16 + 8388608;
  // W region @25.17M floats (1.18M floats = 2.36M u16)
  float* wF = ws_f + 25165824;
  u16* w16 = (u16*)wF;

  // ---- symbolization ----
  u16 *xH = a16, *xM = a16 + 8388608, *xL = a16 + 16777216;
  split3_k<<<2048, 256, 0, stream>>>(x, xH, xM, xL, 2097152);
  split3_k<<<512, 256, 0, stream>>>(sym_w, w16, w16 + 524288, w16 + 1048576,
                                    131072);
  gemm_mf<64, E_BIAS><<<512, 256, 0, stream>>>(
      xH, xM, xL, w16, w16 + 524288, w16 + 1048576, sym_b, nullptr, bF,
      nullptr, nullptr, nullptr, 512, 1024, 1024, 1024, 4);
  l2_split3<<<256, 256, 0, stream>>>(codebook, w16, w16 + 524288,
                                     w16 + 1048576);
  u16 *hpH = a16, *hpM = a16 + 4194304, *hpL = a16 + 8388608;
  l2_split3<<<2048, 256, 0, stream>>>(bF, hpH, hpM, hpL);
  u16 *sH = a16 + 12582912, *sM = a16 + 20971520, *sL = a16 + 29360128;
  gemm_mf<64, E_GUM3><<<1024, 256, 0, stream>>>(
      hpH, hpM, hpL, w16, w16 + 524288, w16 + 1048576, nullptr, gumbel,
      nullptr, sH, sM, sL, 1024, 512, 512, 512, 8);
  softmax3<<<8192, 256, 0, stream>>>(sH, sM, sL);
  tsplit_cb<<<512, 256, 0, stream>>>(codebook, w16, w16 + 524288,
                                     w16 + 1048576);
  gemm_mf<64, E_POS><<<512, 256, 0, stream>>>(
      sH, sM, sL, w16, w16 + 524288, w16 + 1048576, nullptr, pos_enc, h,
      nullptr, nullptr, nullptr, 512, 1024, 1024, 1024, 4);

  // ---- transformer layers ----
  u16 *qkvH = a16, *qkvM = a16 + 12582912, *qkvL = a16 + 25165824;
  u16* w1p = (u16*)(ws_f + 12582912);
  u16* w2p = (u16*)(ws_f + 14155776);
  u16 *pH = a16, *pM = a16 + 8388608, *pL = a16 + 16777216;

  for (int l = 0; l < 4; ++l) {
    const float* inw = attn_in_w + (size_t)l * 1536 * 512;
    const float* inb = attn_in_b + (size_t)l * 1536;
    const float* outw = attn_out_w + (size_t)l * 512 * 512;
    const float* outb = attn_out_b + (size_t)l * 512;
    const float* w1 = ffn_w1 + (size_t)l * 2048 * 512;
    const float* b1 = ffn_b1 + (size_t)l * 2048;
    const float* w2 = ffn_w2 + (size_t)l * 512 * 2048;
    const float* b2 = ffn_b2 + (size_t)l * 512;

    ln_split3<<<2048, 256, 0, stream>>>(h, n1_g + l * 512, n1_b + l * 512,
                                        hnH, hnM, hnL);
    split3_k<<<1024, 256, 0, stream>>>(inw, w16, w16 + 786432, w16 + 1572864,
                                       196608);
    gemm_mf<128, E_QKV3><<<768, 256, 0, stream>>>(
        hnH, hnM, hnL, w16, w16 + 786432, w16 + 1572864, inb, nullptr,
        nullptr, qkvH, qkvM, qkvL, 1536, 512, 512, 512, 12);
    flash_mfma<<<dim3(16, 64), 256, 0, stream>>>(qkvH, qkvM, qkvL, hnH, hnM,
                                                 hnL);
    split3_k<<<256, 256, 0, stream>>>(outw, w16, w16 + 262144, w16 + 524288,
                                      65536);
    gemm_mf<64, E_RES><<<512, 256, 0, stream>>>(
        hnH, hnM, hnL, w16, w16 + 262144, w16 + 524288, outb, h, h, nullptr,
        nullptr, nullptr, 512, 512, 512, 512, 4);
    ln_split3<<<2048, 256, 0, stream>>>(h, n2_g + l * 512, n2_b + l * 512,
                                        hnH, hnM, hnL);
    split3_k<<<1024, 256, 0, stream>>>(w1, w1p, w1p + 1048576, w1p + 2097152,
                                       262144);
    split3_k<<<1024, 256, 0, stream>>>(w2, w2p, w2p + 1048576, w2p + 2097152,
                                       262144);
    for (int c = 0; c < 2; ++c) {
      gemm_mf<128, E_GELU3><<<512, 256, 0, stream>>>(
          hnH, hnM, hnL, w1p + c * 524288, w1p + 1048576 + c * 524288,
          w1p + 2097152 + c * 524288, b1 + c * 1024, nullptr, nullptr, pH, pM,
          pL, 1024, 512, 512, 512, 8);
      if (c == 0) {
        gemm_mf<64, E_RES><<<512, 256, 0, stream>>>(
            pH, pM, pL, w2p + 0, w2p + 1048576, w2p + 2097152, b2, h, h,
            nullptr, nullptr, nullptr, 512, 1024, 1024, 2048, 4);
      } else {
        gemm_mf<64, E_ACC><<<512, 256, 0, stream>>>(
            pH, pM, pL, w2p + 1024, w2p + 1048576 + 1024, w2p + 2097152 + 1024,
            nullptr, nullptr, h, nullptr, nullptr, nullptr, 512, 1024, 1024,
            2048, 4);
      }
    }
  }

  // ---- VQ head (fp32-vector precision anchor) ----
  gemm_f32<64, 128, 32, E_BIAS><<<dim3(4, 128), 256, 0, stream>>>(
      h, q_w, q_b, bF, 8192, 512, 512, nullptr, nullptr);
  ln_l2_f32<<<2048, 256, 0, stream>>>(bF, qln_g, qln_b, bF);
  l2_f32<<<128, 256, 0, stream>>>(patterns, wF);
  gemm_f32<64, 128, 32, E_VQ><<<dim3(4, 128), 256, 0, stream>>>(
      bF, wF, nullptr, logits, 8192, 512, 512, epoch, tot);
  vq_finalize<<<2048, 256, 0, stream>>>(logits, patterns, emb, assign, idxf);
}

// Round 10
// 2617.588 us; speedup vs baseline: 11.9067x; 1.0365x over previous
//
#include <hip/hip_runtime.h>

#define DEV __device__ __forceinline__

typedef unsigned short u16;
typedef unsigned int u32;
typedef __attribute__((ext_vector_type(8))) short bf8_t;   // 8 bf16 (4 VGPR)
typedef __attribute__((ext_vector_type(4))) float f4_t;

constexpr int T_SEQ = 1024;
constexpr int DMODEL = 512;
constexpr int NPAT = 512;

// ---------------- epilogue modes ----------------
enum {
  E_BIAS = 0,
  E_VQ = 5,
  E_RES = 6,
  E_ACC = 7,
  E_POS = 8,
  E_GUM3 = 9,
  E_GELU3 = 10,
  E_QKV3 = 11
};

// ---------------- bf16 triple-split helpers ----------------
DEV u16 f2bf(float x) {
  u32 u = __float_as_uint(x);
  u32 r = u + 0x7FFFu + ((u >> 16) & 1u);
  return (u16)(r >> 16);
}
DEV float bf2f(u16 h) { return __uint_as_float((u32)h << 16); }
DEV void split3(float x, u16& h, u16& m, u16& l) {
  h = f2bf(x);
  float r1 = x - bf2f(h);
  m = f2bf(r1);
  float r2 = r1 - bf2f(m);
  l = f2bf(r2);
}

DEV f4_t mf16(bf8_t a, bf8_t b, f4_t c) {
  return __builtin_amdgcn_mfma_f32_16x16x32_bf16(a, b, c, 0, 0, 0);
}
// 6-product triple-split accumulate (err ~2^-24)
DEV f4_t prod6(bf8_t ah, bf8_t am, bf8_t al, bf8_t bh, bf8_t bm, bf8_t bl,
               f4_t c) {
  c = mf16(ah, bh, c);
  c = mf16(ah, bm, c);
  c = mf16(am, bh, c);
  c = mf16(ah, bl, c);
  c = mf16(am, bm, c);
  c = mf16(al, bh, c);
  return c;
}

// async global->LDS, 16B per lane; LDS dest = base + lane*16 (wave-uniform base)
typedef const __attribute__((address_space(1))) unsigned char* gas_t;
typedef __attribute__((address_space(3))) unsigned char* las_t;
DEV void gload16(const u16* g, u16* l) {
  __builtin_amdgcn_global_load_lds((gas_t)(const void*)g, (las_t)(void*)l, 16,
                                   0, 0);
}

// ---------------- MFMA GEMM, triple-bf16 split (fp32-accurate) ---------------
// C[M,N] = A[M,K]*B[N,K]^T via 6 bf16 products. Verified R6-R9.
// 2-phase prefetch: STAGE(t+1 -> buf^1) issued BEFORE compute(buf); single
// __syncthreads()/iter (its implicit vmcnt(0) drain is the producer fence:
//  - compute(buf) reads only buf; stage writes only buf^1 (disjoint)
//  - barrier: all waves done reading buf AND all gload writes to buf^1 landed
//  - next iter: stage(t+2 -> buf) overwrites buf only after that barrier).
// BM=64, BN=128, LDS dbuf 72KB -> 2 blocks/CU. 1-D grid + XCD swizzle.
template <int EPI>
__global__ __launch_bounds__(256, 2) void gemm_mf(
    const u16* __restrict__ Ah, const u16* __restrict__ Am,
    const u16* __restrict__ Al, const u16* __restrict__ Bh,
    const u16* __restrict__ Bm, const u16* __restrict__ Bl,
    const float* __restrict__ bias, const float* __restrict__ res,
    float* __restrict__ Cf, u16* __restrict__ Ch, u16* __restrict__ Cm,
    u16* __restrict__ Cl, int N, int KK, int lda, int ldb, int gx) {
  constexpr int BM = 64;
  constexpr int MT = 2;  // m-tiles per wave
  __shared__ __align__(16) u16 AsH[2][BM][4][8], AsM[2][BM][4][8],
      AsL[2][BM][4][8];
  __shared__ __align__(16) u16 BsH[2][128][4][8], BsM[2][128][4][8],
      BsL[2][128][4][8];
  const int tid = threadIdx.x;
  const int w = tid >> 6, lane = tid & 63;
  const int wy = w >> 1, wx = w & 1;
  const int lr = lane & 15, lg = lane >> 4;

  // bijective XCD swizzle (all grids divisible by 8)
  const int nwg = gridDim.x;
  const int bid = blockIdx.x;
  const int qq = nwg >> 3;
  const int wg = (bid & 7) * qq + (bid >> 3);
  const int by = wg / gx, bx = wg % gx;
  const int bm = by * BM, bn = bx * 128;

  const int rowl = lane >> 2, slot4 = lane & 3;  // per-lane stage coords

  // issue one K-step's staging into buffer `buf` (pre-swizzled global source,
  // linear LDS dest; plane/chunk selectors are wave-uniform)
  auto STAGE = [&](int k0, int buf) {
#pragma unroll
    for (int it = 0; it < 3; ++it) {  // A: 12 chunks (3 planes x 4)
      const int f = w + 4 * it;
      const int plane = f >> 2;
      const int ch = f & 3;
      const int row = ch * 16 + rowl;
      const int kp = slot4 ^ ((row >> 1) & 3);
      const size_t g = (size_t)(bm + row) * lda + k0 + kp * 8;
      if (plane == 0)
        gload16(&Ah[g], &AsH[buf][0][0][0] + ch * 512);
      else if (plane == 1)
        gload16(&Am[g], &AsM[buf][0][0][0] + ch * 512);
      else
        gload16(&Al[g], &AsL[buf][0][0][0] + ch * 512);
    }
#pragma unroll
    for (int it = 0; it < 6; ++it) {  // B: 24 chunks (3 planes x 8)
      const int f = w + 4 * it;
      const int plane = f >> 3;
      const int ch = f & 7;
      const int row = ch * 16 + rowl;
      const int kp = slot4 ^ ((row >> 1) & 3);
      const size_t g = (size_t)(bn + row) * ldb + k0 + kp * 8;
      if (plane == 0)
        gload16(&Bh[g], &BsH[buf][0][0][0] + ch * 512);
      else if (plane == 1)
        gload16(&Bm[g], &BsM[buf][0][0][0] + ch * 512);
      else
        gload16(&Bl[g], &BsL[buf][0][0][0] + ch * 512);
    }
  };

  f4_t acc[MT][4];
#pragma unroll
  for (int mt = 0; mt < MT; ++mt)
#pragma unroll
    for (int nt = 0; nt < 4; ++nt) acc[mt][nt] = (f4_t){0.f, 0.f, 0.f, 0.f};

  const int nsteps = KK / 32;
  STAGE(0, 0);
  __syncthreads();
  for (int t = 0; t < nsteps; ++t) {
    const int cur = t & 1;
    if (t + 1 < nsteps) STAGE((t + 1) * 32, cur ^ 1);

    bf8_t fah[MT], fam[MT], fal[MT], fbh[4], fbm[4], fbl[4];
#pragma unroll
    for (int mt = 0; mt < MT; ++mt) {
      int row = wy * 32 + mt * 16 + lr;
      int slot = lg ^ ((row >> 1) & 3);
      fah[mt] = *(const bf8_t*)&AsH[cur][row][slot][0];
      fam[mt] = *(const bf8_t*)&AsM[cur][row][slot][0];
      fal[mt] = *(const bf8_t*)&AsL[cur][row][slot][0];
    }
#pragma unroll
    for (int nt = 0; nt < 4; ++nt) {
      int col = wx * 64 + nt * 16 + lr;
      int slot = lg ^ ((col >> 1) & 3);
      fbh[nt] = *(const bf8_t*)&BsH[cur][col][slot][0];
      fbm[nt] = *(const bf8_t*)&BsM[cur][col][slot][0];
      fbl[nt] = *(const bf8_t*)&BsL[cur][col][slot][0];
    }
#pragma unroll
    for (int mt = 0; mt < MT; ++mt)
#pragma unroll
      for (int nt = 0; nt < 4; ++nt)
        acc[mt][nt] = prod6(fah[mt], fam[mt], fal[mt], fbh[nt], fbm[nt],
                            fbl[nt], acc[mt][nt]);
    __syncthreads();
  }

  // ---- epilogue (C frag: col = lane&15, row = 4*(lane>>4)+i) ----
  float bv[4];
  if constexpr (EPI == E_BIAS || EPI == E_RES || EPI == E_GELU3 ||
                EPI == E_QKV3) {
#pragma unroll
    for (int nt = 0; nt < 4; ++nt) bv[nt] = bias[bn + wx * 64 + nt * 16 + lr];
  }
#pragma unroll
  for (int mt = 0; mt < MT; ++mt)
#pragma unroll
    for (int nt = 0; nt < 4; ++nt) {
      const int c = bn + wx * 64 + nt * 16 + lr;
#pragma unroll
      for (int i = 0; i < 4; ++i) {
        const int m = bm + wy * 32 + mt * 16 + 4 * lg + i;
        const size_t idx = (size_t)m * N + c;
        float v = acc[mt][nt][i];
        if constexpr (EPI == E_BIAS) {
          Cf[idx] = v + bv[nt];
        } else if constexpr (EPI == E_RES) {
          Cf[idx] = v + bv[nt] + res[idx];
        } else if constexpr (EPI == E_ACC) {
          Cf[idx] += v;
        } else if constexpr (EPI == E_POS) {
          Cf[idx] = v + res[(size_t)(m & 1023) * N + c];
        } else if constexpr (EPI == E_GUM3) {
          float t = 4.0f * v + 2.0f * res[idx];
          u16 h2, m2, l2;
          split3(t, h2, m2, l2);
          Ch[idx] = h2;
          Cm[idx] = m2;
          Cl[idx] = l2;
        } else if constexpr (EPI == E_GELU3) {
          float t = v + bv[nt];
          float g = 0.5f * t * (1.0f + erff(t * 0.7071067811865476f));
          u16 h2, m2, l2;
          split3(g, h2, m2, l2);
          Ch[idx] = h2;
          Cm[idx] = m2;
          Cl[idx] = l2;
        } else if constexpr (EPI == E_QKV3) {
          float t = v + bv[nt];
          u16 h2, m2, l2;
          split3(t, h2, m2, l2);
          size_t o;
          if (c < 512) {
            o = (size_t)m * 512 + c;                       // Q [B,T,512]
          } else if (c < 1024) {
            o = 4194304 + (size_t)m * 512 + (c - 512);     // K [B,T,512]
          } else {
            int cc = c - 1024, hh2 = cc >> 6, dd = cc & 63;
            int bb2 = m >> 10, tt = m & 1023;
            o = 8388608 +
                (((size_t)(bb2 * 8 + hh2) * 64 + dd) << 10) + tt;  // Vt
          }
          Ch[o] = h2;
          Cm[o] = m2;
          Cl[o] = l2;
        }
      }
    }
}

// ---------------- MFMA flash attention (triple-split, fp32-grade) ------------
// grid (16, 64): qt 0..15 (64 q-rows/block), bh = b*8+hh. 4 waves, each owns
// 16 q-rows. K rows-major [B,T,512]; V pre-transposed [B,8,64,T].
// K/V staging via global_load_lds. P ALIASES the K tile (dead after QK^T):
// LDS 48KB -> 3 blocks/CU. P reads are wave-private (own 16 rows), so only
// one extra barrier (after QK^T) is needed before the P overwrite.
__global__ __launch_bounds__(256) void flash_mfma(
    const u16* __restrict__ QKVh, const u16* __restrict__ QKVm,
    const u16* __restrict__ QKVl, u16* __restrict__ Oh, u16* __restrict__ Om,
    u16* __restrict__ Ol) {
  __shared__ __align__(16) u16 KP[3][64][8][8];  // K tile, then P tile
  __shared__ __align__(16) u16 Vs[3][64][8][8];
  const int tid = threadIdx.x;
  const int w = tid >> 6, lane = tid & 63;
  const int lr = lane & 15, lg = lane >> 4;
  const int qt = blockIdx.x, bh = blockIdx.y;
  const int b = bh >> 3, hh = bh & 7;

  const u16* Qh = QKVh;
  const u16* Qm = QKVm;
  const u16* Ql = QKVl;
  const u16* Kh = QKVh + 4194304;
  const u16* Km = QKVm + 4194304;
  const u16* Kl = QKVl + 4194304;
  const u16* Vh = QKVh + 8388608;
  const u16* Vm = QKVm + 8388608;
  const u16* Vl = QKVl + 8388608;

  // Q fragments (A-op: m = lr, k-packet = lg), hoisted for all kt
  bf8_t qf[2][3];
  {
    size_t g =
        ((size_t)(b * 1024 + qt * 64 + w * 16 + lr)) * 512 + hh * 64 + lg * 8;
    qf[0][0] = *(const bf8_t*)&Qh[g];
    qf[0][1] = *(const bf8_t*)&Qm[g];
    qf[0][2] = *(const bf8_t*)&Ql[g];
    qf[1][0] = *(const bf8_t*)&Qh[g + 32];
    qf[1][1] = *(const bf8_t*)&Qm[g + 32];
    qf[1][2] = *(const bf8_t*)&Ql[g + 32];
  }

  f4_t oacc[4];
#pragma unroll
  for (int nt = 0; nt < 4; ++nt) oacc[nt] = (f4_t){0.f, 0.f, 0.f, 0.f};
  float mrun[4], lrun[4];
#pragma unroll
  for (int i = 0; i < 4; ++i) {
    mrun[i] = -__builtin_huge_valf();
    lrun[i] = 0.0f;
  }

  const int rowl8 = lane >> 3, slot8 = lane & 7;  // stage coords (8 rows/chunk)

  for (int kt = 0; kt < 16; ++kt) {
    __syncthreads();  // prior PV done reading Vs + KP(P)
    // ---- stage K tile + Vt tile via global_load_lds: 48 x 1KB chunks ----
#pragma unroll
    for (int it = 0; it < 6; ++it) {
      const int f = w + 4 * it;
      const int plane = f >> 3, ch = f & 7;
      const int row = ch * 8 + rowl8;
      const int kp = slot8 ^ (row & 7);
      const size_t gk =
          ((size_t)(b * 1024 + kt * 64 + row)) * 512 + hh * 64 + kp * 8;
      if (plane == 0)
        gload16(&Kh[gk], &KP[0][0][0][0] + ch * 512);
      else if (plane == 1)
        gload16(&Km[gk], &KP[1][0][0][0] + ch * 512);
      else
        gload16(&Kl[gk], &KP[2][0][0][0] + ch * 512);
    }
#pragma unroll
    for (int it = 0; it < 6; ++it) {
      const int f = w + 4 * it;
      const int plane = f >> 3, ch = f & 7;
      const int row = ch * 8 + rowl8;
      const int kp = slot8 ^ (row & 7);
      const size_t gv =
          ((size_t)((b * 8 + hh) * 64 + row)) * 1024 + kt * 64 + kp * 8;
      if (plane == 0)
        gload16(&Vh[gv], &Vs[0][0][0][0] + ch * 512);
      else if (plane == 1)
        gload16(&Vm[gv], &Vs[1][0][0][0] + ch * 512);
      else
        gload16(&Vl[gv], &Vs[2][0][0][0] + ch * 512);
    }
    __syncthreads();

    // ---- S = Q K^T : 4 n-tiles x 2 k-slices x 6 products ----
    f4_t s[4];
#pragma unroll
    for (int nt = 0; nt < 4; ++nt) {
      s[nt] = (f4_t){0.f, 0.f, 0.f, 0.f};
      const int col = nt * 16 + lr;
#pragma unroll
      for (int ks = 0; ks < 2; ++ks) {
        int slot = (ks * 4 + lg) ^ (col & 7);
        bf8_t kh = *(const bf8_t*)&KP[0][col][slot][0];
        bf8_t km = *(const bf8_t*)&KP[1][col][slot][0];
        bf8_t kl = *(const bf8_t*)&KP[2][col][slot][0];
        s[nt] = prod6(qf[ks][0], qf[ks][1], qf[ks][2], kh, km, kl, s[nt]);
      }
    }

    // ---- online softmax (row = 4*lg+i; reduce over lr via shfl) ----
#pragma unroll
    for (int i = 0; i < 4; ++i) {
      float rm = -__builtin_huge_valf();
#pragma unroll
      for (int nt = 0; nt < 4; ++nt) {
        s[nt][i] *= 0.125f;
        rm = fmaxf(rm, s[nt][i]);
      }
      rm = fmaxf(rm, __shfl_xor(rm, 1));
      rm = fmaxf(rm, __shfl_xor(rm, 2));
      rm = fmaxf(rm, __shfl_xor(rm, 4));
      rm = fmaxf(rm, __shfl_xor(rm, 8));
      float mnew = fmaxf(mrun[i], rm);
      float alpha = __expf(mrun[i] - mnew);
      float rs = 0.0f;
#pragma unroll
      for (int nt = 0; nt < 4; ++nt) {
        float p = __expf(s[nt][i] - mnew);
        s[nt][i] = p;
        rs += p;
      }
      rs += __shfl_xor(rs, 1);
      rs += __shfl_xor(rs, 2);
      rs += __shfl_xor(rs, 4);
      rs += __shfl_xor(rs, 8);
      lrun[i] = lrun[i] * alpha + rs;
      mrun[i] = mnew;
#pragma unroll
      for (int nt = 0; nt < 4; ++nt) oacc[nt][i] *= alpha;
    }

    __syncthreads();  // all waves done reading K tile -> safe to overwrite

    // ---- P -> KP (wave-private rows, 3 planes, swizzled) ----
#pragma unroll
    for (int nt = 0; nt < 4; ++nt)
#pragma unroll
      for (int i = 0; i < 4; ++i) {
        int qrow = w * 16 + 4 * lg + i;
        int kv = nt * 16 + lr;
        int kp = kv >> 3, j = kv & 7;
        int slot = kp ^ (qrow & 7);
        u16 h2, m2, l2;
        split3(s[nt][i], h2, m2, l2);
        KP[0][qrow][slot][j] = h2;
        KP[1][qrow][slot][j] = m2;
        KP[2][qrow][slot][j] = l2;
      }

    // ---- O += P V (A = own P rows, B = Vt cols) ----
    bf8_t pf[2][3];
#pragma unroll
    for (int ks = 0; ks < 2; ++ks) {
      int row = w * 16 + lr;
      int slot = (ks * 4 + lg) ^ (row & 7);
      pf[ks][0] = *(const bf8_t*)&KP[0][row][slot][0];
      pf[ks][1] = *(const bf8_t*)&KP[1][row][slot][0];
      pf[ks][2] = *(const bf8_t*)&KP[2][row][slot][0];
    }
#pragma unroll
    for (int ntd = 0; ntd < 4; ++ntd) {
      const int col = ntd * 16 + lr;
#pragma unroll
      for (int ks = 0; ks < 2; ++ks) {
        int slot = (ks * 4 + lg) ^ (col & 7);
        bf8_t vh = *(const bf8_t*)&Vs[0][col][slot][0];
        bf8_t vm = *(const bf8_t*)&Vs[1][col][slot][0];
        bf8_t vl = *(const bf8_t*)&Vs[2][col][slot][0];
        oacc[ntd] =
            prod6(pf[ks][0], pf[ks][1], pf[ks][2], vh, vm, vl, oacc[ntd]);
      }
    }
  }

  // ---- epilogue: normalize, split3, store planes [B,T,512] ----
#pragma unroll
  for (int i = 0; i < 4; ++i) {
    float inv = 1.0f / lrun[i];
    int t = qt * 64 + w * 16 + 4 * lg + i;
#pragma unroll
    for (int ntd = 0; ntd < 4; ++ntd) {
      int d = hh * 64 + ntd * 16 + lr;
      size_t idx = ((size_t)(b * 1024 + t)) * 512 + d;
      u16 h2, m2, l2;
      split3(oacc[ntd][i] * inv, h2, m2, l2);
      Oh[idx] = h2;
      Om[idx] = m2;
      Ol[idx] = l2;
    }
  }
}

// ---------------- fp32 vector GEMM (VQ-head precision anchor) ----------------
template <int BM, int BN, int WR, int EPI>
__global__ __launch_bounds__((BM / WR) * (BN / 64) * 64) void gemm_f32(
    const float* __restrict__ A, const float* __restrict__ Bmat,
    const float* __restrict__ bias, float* __restrict__ C, int M, int N, int K,
    const int* __restrict__ ep, const int* __restrict__ tot) {
  constexpr int BK = 16;
  constexpr int WN = BN / 64;
  constexpr int NW = (BM / WR) * WN;
  constexpr int NT = NW * 64;
  constexpr int RM = WR / 8;
  __shared__ __align__(16) float As[BK][BM + 4];
  __shared__ __align__(16) float Bs[BK][BN + 4];
  const int tid = threadIdx.x;
  const int w = tid >> 6, lane = tid & 63;
  const int wy = w / WN, wx = w % WN;
  const int ly = lane >> 3, lx = lane & 7;
  const int bm = blockIdx.y * BM;
  const int bn = blockIdx.x * BN;
  const int rbase = wy * WR + ly * RM;

  float acc[RM][8];
#pragma unroll
  for (int i = 0; i < RM; ++i)
#pragma unroll
    for (int j = 0; j < 8; ++j) acc[i][j] = 0.0f;

  for (int k0 = 0; k0 < K; k0 += BK) {
#pragma unroll
    for (int i = 0; i < (BM * BK / 4) / NT; ++i) {
      int idx = tid + i * NT;
      int r = idx >> 2, c4 = (idx & 3) << 2;
      const float4 v = *(const float4*)(A + (size_t)(bm + r) * K + k0 + c4);
      As[c4 + 0][r] = v.x;
      As[c4 + 1][r] = v.y;
      As[c4 + 2][r] = v.z;
      As[c4 + 3][r] = v.w;
    }
#pragma unroll
    for (int i = 0; i < (BN * BK / 4) / NT; ++i) {
      int idx = tid + i * NT;
      int r = idx >> 2, c4 = (idx & 3) << 2;
      const float4 v = *(const float4*)(Bmat + (size_t)(bn + r) * K + k0 + c4);
      Bs[c4 + 0][r] = v.x;
      Bs[c4 + 1][r] = v.y;
      Bs[c4 + 2][r] = v.z;
      Bs[c4 + 3][r] = v.w;
    }
    __syncthreads();
#pragma unroll
    for (int k = 0; k < BK; ++k) {
      float a[RM], b[8];
#pragma unroll
      for (int r4 = 0; r4 < RM; r4 += 4)
        *(float4*)&a[r4] = *(const float4*)&As[k][rbase + r4];
      *(float4*)&b[0] = *(const float4*)&Bs[k][wx * 64 + lx * 8];
      *(float4*)&b[4] = *(const float4*)&Bs[k][wx * 64 + lx * 8 + 4];
#pragma unroll
      for (int i = 0; i < RM; ++i)
#pragma unroll
        for (int j = 0; j < 8; ++j) acc[i][j] = fmaf(a[i], b[j], acc[i][j]);
    }
    __syncthreads();
  }

  const int ncol = bn + wx * 64 + lx * 8;
  float bb[8];
  if constexpr (EPI == E_BIAS) {
    *(float4*)&bb[0] = *(const float4*)(bias + ncol);
    *(float4*)&bb[4] = *(const float4*)(bias + ncol + 4);
  }
  float invt = 1.0f;
  if constexpr (EPI == E_VQ) {
    float t = 1.0f - 0.5f * (float)ep[0] / (float)tot[0];
    invt = 1.0f / fmaxf(0.5f, t);
  }
#pragma unroll
  for (int i = 0; i < RM; ++i) {
    const int m = bm + rbase + i;
    float o[8];
#pragma unroll
    for (int j = 0; j < 8; ++j) o[j] = acc[i][j];
    if constexpr (EPI == E_BIAS) {
#pragma unroll
      for (int j = 0; j < 8; ++j) o[j] += bb[j];
    } else if constexpr (EPI == E_VQ) {
#pragma unroll
      for (int j = 0; j < 8; ++j) o[j] *= invt;
    }
    *(float4*)(C + (size_t)m * N + ncol) = *(float4*)&o[0];
    *(float4*)(C + (size_t)m * N + ncol + 4) = *(float4*)&o[4];
  }
}

// ---------------- row kernels ----------------
DEV float wave_sum(float v) {
#pragma unroll
  for (int off = 1; off < 64; off <<= 1) v += __shfl_xor(v, off);
  return v;
}

DEV void store8_split3(u16* H, u16* M, u16* L, size_t base, const float* t) {
  u16 vh[8], vm[8], vl[8];
#pragma unroll
  for (int j = 0; j < 8; ++j) split3(t[j], vh[j], vm[j], vl[j]);
  *(ushort4*)&H[base] = make_ushort4(vh[0], vh[1], vh[2], vh[3]);
  *(ushort4*)&H[base + 4] = make_ushort4(vh[4], vh[5], vh[6], vh[7]);
  *(ushort4*)&M[base] = make_ushort4(vm[0], vm[1], vm[2], vm[3]);
  *(ushort4*)&M[base + 4] = make_ushort4(vm[4], vm[5], vm[6], vm[7]);
  *(ushort4*)&L[base] = make_ushort4(vl[0], vl[1], vl[2], vl[3]);
  *(ushort4*)&L[base + 4] = make_ushort4(vl[4], vl[5], vl[6], vl[7]);
}

__global__ __launch_bounds__(256) void ln_split3(const float* __restrict__ x,
                                                 const float* __restrict__ g,
                                                 const float* __restrict__ b,
                                                 u16* __restrict__ yh,
                                                 u16* __restrict__ ym,
                                                 u16* __restrict__ yl) {
  const int row = blockIdx.x * 4 + (threadIdx.x >> 6);
  const int lane = threadIdx.x & 63;
  const float* xr = x + (size_t)row * DMODEL;
  float v[8];
  *(float4*)&v[0] = *(const float4*)(xr + lane * 8);
  *(float4*)&v[4] = *(const float4*)(xr + lane * 8 + 4);
  float s = 0.0f;
#pragma unroll
  for (int j = 0; j < 8; ++j) s += v[j];
  s = wave_sum(s);
  float mean = s * (1.0f / 512.0f);
  float s2 = 0.0f;
#pragma unroll
  for (int j = 0; j < 8; ++j) {
    float d = v[j] - mean;
    s2 += d * d;
  }
  s2 = wave_sum(s2);
  float rstd = 1.0f / sqrtf(s2 * (1.0f / 512.0f) + 1e-5f);
  float gg[8], bv[8];
  *(float4*)&gg[0] = *(const float4*)(g + lane * 8);
  *(float4*)&gg[4] = *(const float4*)(g + lane * 8 + 4);
  *(float4*)&bv[0] = *(const float4*)(b + lane * 8);
  *(float4*)&bv[4] = *(const float4*)(b + lane * 8 + 4);
  float t[8];
#pragma unroll
  for (int j = 0; j < 8; ++j) t[j] = (v[j] - mean) * rstd * gg[j] + bv[j];
  store8_split3(yh, ym, yl, (size_t)row * DMODEL + lane * 8, t);
}

__global__ __launch_bounds__(256) void ln_l2_f32(const float* __restrict__ x,
                                                 const float* __restrict__ g,
                                                 const float* __restrict__ b,
                                                 float* __restrict__ y) {
  const int row = blockIdx.x * 4 + (threadIdx.x >> 6);
  const int lane = threadIdx.x & 63;
  const float* xr = x + (size_t)row * DMODEL;
  float v[8];
  *(float4*)&v[0] = *(const float4*)(xr + lane * 8);
  *(float4*)&v[4] = *(const float4*)(xr + lane * 8 + 4);
  float s = 0.0f;
#pragma unroll
  for (int j = 0; j < 8; ++j) s += v[j];
  s = wave_sum(s);
  float mean = s * (1.0f / 512.0f);
  float s2 = 0.0f;
#pragma unroll
  for (int j = 0; j < 8; ++j) {
    float d = v[j] - mean;
    s2 += d * d;
  }
  s2 = wave_sum(s2);
  float rstd = 1.0f / sqrtf(s2 * (1.0f / 512.0f) + 1e-5f);
  float gg[8], bv[8];
  *(float4*)&gg[0] = *(const float4*)(g + lane * 8);
  *(float4*)&gg[4] = *(const float4*)(g + lane * 8 + 4);
  *(float4*)&bv[0] = *(const float4*)(b + lane * 8);
  *(float4*)&bv[4] = *(const float4*)(b + lane * 8 + 4);
  float t[8];
#pragma unroll
  for (int j = 0; j < 8; ++j) t[j] = (v[j] - mean) * rstd * gg[j] + bv[j];
  float n2 = 0.0f;
#pragma unroll
  for (int j = 0; j < 8; ++j) n2 += t[j] * t[j];
  n2 = wave_sum(n2);
  float den = fmaxf(sqrtf(n2), 1e-12f);
#pragma unroll
  for (int j = 0; j < 8; ++j) t[j] /= den;
  float* yr = y + (size_t)row * DMODEL;
  *(float4*)(yr + lane * 8) = *(float4*)&t[0];
  *(float4*)(yr + lane * 8 + 4) = *(float4*)&t[4];
}

__global__ __launch_bounds__(256) void l2_split3(const float* __restrict__ x,
                                                 u16* __restrict__ yh,
                                                 u16* __restrict__ ym,
                                                 u16* __restrict__ yl) {
  const int row = blockIdx.x * 4 + (threadIdx.x >> 6);
  const int lane = threadIdx.x & 63;
  const float* xr = x + (size_t)row * DMODEL;
  float v[8];
  *(float4*)&v[0] = *(const float4*)(xr + lane * 8);
  *(float4*)&v[4] = *(const float4*)(xr + lane * 8 + 4);
  float n2 = 0.0f;
#pragma unroll
  for (int j = 0; j < 8; ++j) n2 += v[j] * v[j];
  n2 = wave_sum(n2);
  float den = fmaxf(sqrtf(n2), 1e-12f);
#pragma unroll
  for (int j = 0; j < 8; ++j) v[j] /= den;
  store8_split3(yh, ym, yl, (size_t)row * DMODEL + lane * 8, v);
}

__global__ __launch_bounds__(256) void l2_f32(const float* __restrict__ x,
                                              float* __restrict__ y) {
  const int row = blockIdx.x * 4 + (threadIdx.x >> 6);
  const int lane = threadIdx.x & 63;
  const float* xr = x + (size_t)row * DMODEL;
  float v[8];
  *(float4*)&v[0] = *(const float4*)(xr + lane * 8);
  *(float4*)&v[4] = *(const float4*)(xr + lane * 8 + 4);
  float n2 = 0.0f;
#pragma unroll
  for (int j = 0; j < 8; ++j) n2 += v[j] * v[j];
  n2 = wave_sum(n2);
  float den = fmaxf(sqrtf(n2), 1e-12f);
#pragma unroll
  for (int j = 0; j < 8; ++j) v[j] /= den;
  float* yr = y + (size_t)row * DMODEL;
  *(float4*)(yr + lane * 8) = *(float4*)&v[0];
  *(float4*)(yr + lane * 8 + 4) = *(float4*)&v[4];
}

__global__ __launch_bounds__(256) void softmax3(u16* __restrict__ H,
                                                u16* __restrict__ M,
                                                u16* __restrict__ L) {
  const int row = blockIdx.x;
  const int tid = threadIdx.x;
  const size_t base = (size_t)row * 1024 + tid * 4;
  ushort4 qh = *(const ushort4*)&H[base];
  ushort4 qm = *(const ushort4*)&M[base];
  ushort4 ql = *(const ushort4*)&L[base];
  float v0 = bf2f(qh.x) + bf2f(qm.x) + bf2f(ql.x);
  float v1 = bf2f(qh.y) + bf2f(qm.y) + bf2f(ql.y);
  float v2 = bf2f(qh.z) + bf2f(qm.z) + bf2f(ql.z);
  float v3 = bf2f(qh.w) + bf2f(qm.w) + bf2f(ql.w);
  float mx = fmaxf(fmaxf(v0, v1), fmaxf(v2, v3));
#pragma unroll
  for (int off = 1; off < 64; off <<= 1) mx = fmaxf(mx, __shfl_xor(mx, off));
  __shared__ float red[4];
  const int wv = tid >> 6;
  if ((tid & 63) == 0) red[wv] = mx;
  __syncthreads();
  mx = fmaxf(fmaxf(red[0], red[1]), fmaxf(red[2], red[3]));
  float e0 = __expf(v0 - mx), e1 = __expf(v1 - mx), e2 = __expf(v2 - mx),
        e3 = __expf(v3 - mx);
  float s = e0 + e1 + e2 + e3;
#pragma unroll
  for (int off = 1; off < 64; off <<= 1) s += __shfl_xor(s, off);
  __syncthreads();
  if ((tid & 63) == 0) red[wv] = s;
  __syncthreads();
  s = red[0] + red[1] + red[2] + red[3];
  float inv = 1.0f / s;
  u16 ah[4], am[4], al[4];
  split3(e0 * inv, ah[0], am[0], al[0]);
  split3(e1 * inv, ah[1], am[1], al[1]);
  split3(e2 * inv, ah[2], am[2], al[2]);
  split3(e3 * inv, ah[3], am[3], al[3]);
  *(ushort4*)&H[base] = make_ushort4(ah[0], ah[1], ah[2], ah[3]);
  *(ushort4*)&M[base] = make_ushort4(am[0], am[1], am[2], am[3]);
  *(ushort4*)&L[base] = make_ushort4(al[0], al[1], al[2], al[3]);
}

__global__ __launch_bounds__(256) void split3_k(const float* __restrict__ src,
                                                u16* __restrict__ H,
                                                u16* __restrict__ M,
                                                u16* __restrict__ L, int n4) {
  for (int e = blockIdx.x * 256 + threadIdx.x; e < n4; e += gridDim.x * 256) {
    float4 v = *(const float4*)(src + (size_t)e * 4);
    u16 ah[4], am[4], al[4];
    split3(v.x, ah[0], am[0], al[0]);
    split3(v.y, ah[1], am[1], al[1]);
    split3(v.z, ah[2], am[2], al[2]);
    split3(v.w, ah[3], am[3], al[3]);
    *(ushort4*)&H[(size_t)e * 4] = make_ushort4(ah[0], ah[1], ah[2], ah[3]);
    *(ushort4*)&M[(size_t)e * 4] = make_ushort4(am[0], am[1], am[2], am[3]);
    *(ushort4*)&L[(size_t)e * 4] = make_ushort4(al[0], al[1], al[2], al[3]);
  }
}

__global__ __launch_bounds__(256) void tsplit_cb(const float* __restrict__ cb,
                                                 u16* __restrict__ th,
                                                 u16* __restrict__ tm,
                                                 u16* __restrict__ tl) {
  const int c = blockIdx.x;
  const int t = threadIdx.x;
  u16 ah[4], am[4], al[4];
#pragma unroll
  for (int j = 0; j < 4; ++j) {
    float v = cb[(size_t)(4 * t + j) * 512 + c];
    split3(v, ah[j], am[j], al[j]);
  }
  const size_t base = (size_t)c * 1024 + 4 * t;
  *(ushort4*)&th[base] = make_ushort4(ah[0], ah[1], ah[2], ah[3]);
  *(ushort4*)&tm[base] = make_ushort4(am[0], am[1], am[2], am[3]);
  *(ushort4*)&tl[base] = make_ushort4(al[0], al[1], al[2], al[3]);
}

__global__ __launch_bounds__(256) void vq_finalize(
    const float* __restrict__ logits, const float* __restrict__ patterns,
    float* __restrict__ emb, float* __restrict__ assign,
    float* __restrict__ idxf) {
  const int row = blockIdx.x * 4 + (threadIdx.x >> 6);
  const int lane = threadIdx.x & 63;
  const float* lr = logits + (size_t)row * NPAT;
  float best = -__builtin_huge_valf();
  int bi = 0;
#pragma unroll
  for (int jj = 0; jj < 8; ++jj) {
    int j = lane + jj * 64;
    float v = lr[j];
    if (v > best) {
      best = v;
      bi = j;
    }
  }
#pragma unroll
  for (int off = 1; off < 64; off <<= 1) {
    float ob = __shfl_xor(best, off);
    int oi = __shfl_xor(bi, off);
    if (ob > best || (ob == best && oi < bi)) {
      best = ob;
      bi = oi;
    }
  }
  const float* pr = patterns + (size_t)bi * DMODEL;
#pragma unroll
  for (int g = 0; g < 2; ++g) {
    int c = lane * 8 + g * 4;
    float4 pv = *(const float4*)(pr + c);
    *(float4*)(emb + (size_t)row * DMODEL + c) = pv;
    float4 av;
    av.x = (c + 0 == bi) ? 1.0f : 0.0f;
    av.y = (c + 1 == bi) ? 1.0f : 0.0f;
    av.z = (c + 2 == bi) ? 1.0f : 0.0f;
    av.w = (c + 3 == bi) ? 1.0f : 0.0f;
    *(float4*)(assign + (size_t)row * NPAT + c) = av;
  }
  if (lane == 0) idxf[row] = (float)bi;
}

// ---------------- host launch ----------------
extern "C" void kernel_launch(void* const* d_in, const int* in_sizes, int n_in,
                              void* d_out, int out_size, void* d_ws,
                              size_t ws_size, hipStream_t stream) {
  (void)in_sizes;
  (void)n_in;
  (void)out_size;
  (void)ws_size;
  const float* x = (const float*)d_in[0];
  const float* gumbel = (const float*)d_in[1];
  const float* sym_w = (const float*)d_in[2];
  const float* sym_b = (const float*)d_in[3];
  const float* codebook = (const float*)d_in[4];
  const float* pos_enc = (const float*)d_in[5];
  const float* attn_in_w = (const float*)d_in[6];
  const float* attn_in_b = (const float*)d_in[7];
  const float* attn_out_w = (const float*)d_in[8];
  const float* attn_out_b = (const float*)d_in[9];
  const float* n1_g = (const float*)d_in[10];
  const float* n1_b = (const float*)d_in[11];
  const float* n2_g = (const float*)d_in[12];
  const float* n2_b = (const float*)d_in[13];
  const float* ffn_w1 = (const float*)d_in[14];
  const float* ffn_b1 = (const float*)d_in[15];
  const float* ffn_w2 = (const float*)d_in[16];
  const float* ffn_b2 = (const float*)d_in[17];
  const float* q_w = (const float*)d_in[18];
  const float* q_b = (const float*)d_in[19];
  const float* qln_g = (const float*)d_in[20];
  const float* qln_b = (const float*)d_in[21];
  const float* patterns = (const float*)d_in[22];
  const int* epoch = (const int*)d_in[23];
  const int* tot = (const int*)d_in[24];

  float* out = (float*)d_out;
  float* emb = out;               // [8192,512]
  float* assign = out + 4194304;  // [8192,512]
  float* logits = out + 8388608;  // [8192,512]
  float* h = out + 12582912;      // [8192,512]
  float* idxf = out + 16777216;   // [8192]

  float* ws_f = (float*)d_ws;
  // A region @0 (18.87M floats = 37.75M u16)
  u16* a16 = (u16*)ws_f;
  // B region @18.87M floats (6.29M floats = 12.58M u16)
  float* bF = ws_f + 18874368;
  u16* b16 = (u16*)bF;
  u16 *hnH = b16, *hnM = b16 + 4194304, *hnL = b16 + 8388608;
  // W region @25.17M floats (1.18M floats = 2.36M u16)
  float* wF = ws_f + 25165824;
  u16* w16 = (u16*)wF;

  // ---- symbolization ----
  u16 *xH = a16, *xM = a16 + 8388608, *xL = a16 + 16777216;
  split3_k<<<2048, 256, 0, stream>>>(x, xH, xM, xL, 2097152);
  split3_k<<<512, 256, 0, stream>>>(sym_w, w16, w16 + 524288, w16 + 1048576,
                                    131072);
  gemm_mf<E_BIAS><<<512, 256, 0, stream>>>(
      xH, xM, xL, w16, w16 + 524288, w16 + 1048576, sym_b, nullptr, bF,
      nullptr, nullptr, nullptr, 512, 1024, 1024, 1024, 4);
  l2_split3<<<256, 256, 0, stream>>>(codebook, w16, w16 + 524288,
                                     w16 + 1048576);
  u16 *hpH = a16, *hpM = a16 + 4194304, *hpL = a16 + 8388608;
  l2_split3<<<2048, 256, 0, stream>>>(bF, hpH, hpM, hpL);
  u16 *sH = a16 + 12582912, *sM = a16 + 20971520, *sL = a16 + 29360128;
  gemm_mf<E_GUM3><<<1024, 256, 0, stream>>>(
      hpH, hpM, hpL, w16, w16 + 524288, w16 + 1048576, nullptr, gumbel,
      nullptr, sH, sM, sL, 1024, 512, 512, 512, 8);
  softmax3<<<8192, 256, 0, stream>>>(sH, sM, sL);
  tsplit_cb<<<512, 256, 0, stream>>>(codebook, w16, w16 + 524288,
                                     w16 + 1048576);
  gemm_mf<E_POS><<<512, 256, 0, stream>>>(
      sH, sM, sL, w16, w16 + 524288, w16 + 1048576, nullptr, pos_enc, h,
      nullptr, nullptr, nullptr, 512, 1024, 1024, 1024, 4);

  // ---- transformer layers ----
  u16 *qkvH = a16, *qkvM = a16 + 12582912, *qkvL = a16 + 25165824;
  u16* w1p = (u16*)(ws_f + 12582912);
  u16* w2p = (u16*)(ws_f + 14155776);
  u16 *pH = a16, *pM = a16 + 8388608, *pL = a16 + 16777216;

  for (int l = 0; l < 4; ++l) {
    const float* inw = attn_in_w + (size_t)l * 1536 * 512;
    const float* inb = attn_in_b + (size_t)l * 1536;
    const float* outw = attn_out_w + (size_t)l * 512 * 512;
    const float* outb = attn_out_b + (size_t)l * 512;
    const float* w1 = ffn_w1 + (size_t)l * 2048 * 512;
    const float* b1 = ffn_b1 + (size_t)l * 2048;
    const float* w2 = ffn_w2 + (size_t)l * 512 * 2048;
    const float* b2 = ffn_b2 + (size_t)l * 512;

    ln_split3<<<2048, 256, 0, stream>>>(h, n1_g + l * 512, n1_b + l * 512,
                                        hnH, hnM, hnL);
    split3_k<<<1024, 256, 0, stream>>>(inw, w16, w16 + 786432, w16 + 1572864,
                                       196608);
    gemm_mf<E_QKV3><<<1536, 256, 0, stream>>>(
        hnH, hnM, hnL, w16, w16 + 786432, w16 + 1572864, inb, nullptr,
        nullptr, qkvH, qkvM, qkvL, 1536, 512, 512, 512, 12);
    flash_mfma<<<dim3(16, 64), 256, 0, stream>>>(qkvH, qkvM, qkvL, hnH, hnM,
                                                 hnL);
    split3_k<<<256, 256, 0, stream>>>(outw, w16, w16 + 262144, w16 + 524288,
                                      65536);
    gemm_mf<E_RES><<<512, 256, 0, stream>>>(
        hnH, hnM, hnL, w16, w16 + 262144, w16 + 524288, outb, h, h, nullptr,
        nullptr, nullptr, 512, 512, 512, 512, 4);
    ln_split3<<<2048, 256, 0, stream>>>(h, n2_g + l * 512, n2_b + l * 512,
                                        hnH, hnM, hnL);
    split3_k<<<1024, 256, 0, stream>>>(w1, w1p, w1p + 1048576, w1p + 2097152,
                                       262144);
    split3_k<<<1024, 256, 0, stream>>>(w2, w2p, w2p + 1048576, w2p + 2097152,
                                       262144);
    for (int c = 0; c < 2; ++c) {
      gemm_mf<E_GELU3><<<1024, 256, 0, stream>>>(
          hnH, hnM, hnL, w1p + c * 524288, w1p + 1048576 + c * 524288,
          w1p + 2097152 + c * 524288, b1 + c * 1024, nullptr, nullptr, pH, pM,
          pL, 1024, 512, 512, 512, 8);
      if (c == 0) {
        gemm_mf<E_RES><<<512, 256, 0, stream>>>(
            pH, pM, pL, w2p + 0, w2p + 1048576, w2p + 2097152, b2, h, h,
            nullptr, nullptr, nullptr, 512, 1024, 1024, 2048, 4);
      } else {
        gemm_mf<E_ACC><<<512, 256, 0, stream>>>(
            pH, pM, pL, w2p + 1024, w2p + 1048576 + 1024, w2p + 2097152 + 1024,
            nullptr, nullptr, h, nullptr, nullptr, nullptr, 512, 1024, 1024,
            2048, 4);
      }
    }
  }

  // ---- VQ head (fp32-vector precision anchor) ----
  gemm_f32<64, 128, 32, E_BIAS><<<dim3(4, 128), 256, 0, stream>>>(
      h, q_w, q_b, bF, 8192, 512, 512, nullptr, nullptr);
  ln_l2_f32<<<2048, 256, 0, stream>>>(bF, qln_g, qln_b, bF);
  l2_f32<<<128, 256, 0, stream>>>(patterns, wF);
  gemm_f32<64, 128, 32, E_VQ><<<dim3(4, 128), 256, 0, stream>>>(
      bF, wF, nullptr, logits, 8192, 512, 512, epoch, tot);
  vq_finalize<<<2048, 256, 0, stream>>>(logits, patterns, emb, assign, idxf);
}